// Round 1
// baseline (5048.164 us; speedup 1.0000x reference)
//
#include <hip/hip_runtime.h>
#include <cstdint>
#include <cstddef>

#define N_NODES 50000
#define N_EDGES 800000

__device__ __forceinline__ unsigned fenc(float f) {
    unsigned u = __float_as_uint(f);
    return (u & 0x80000000u) ? ~u : (u | 0x80000000u);
}
__device__ __forceinline__ float fdec(unsigned u) {
    return __uint_as_float((u & 0x80000000u) ? (u & 0x7FFFFFFFu) : ~u);
}

// ---------------- GEMM (n x 128) @ (128 x C) + fused attn-dot epilogue ----------------
// feat = A @ W  [n, C]; el[n,h] = dot(feat[n, h*64:], al[h]); er likewise.
template <int C, int H>
__launch_bounds__(256)
__global__ void gemm_feat(const float* __restrict__ A, const float* __restrict__ W,
                          const float* __restrict__ al, const float* __restrict__ ar,
                          float* __restrict__ feat, float* __restrict__ el,
                          float* __restrict__ er, int n)
{
    constexpr int K = 128;
    constexpr int BM = 32;
    constexpr int AS = K + 4;          // 132: 16B-aligned rows, bank-conflict-free
    constexpr int F4 = C / 32;         // float4s per thread (4 for C=128, 2 for C=64)
    __shared__ float Al[BM * AS];
    __shared__ float Wl[32 * C];

    const int tid = threadIdx.x;
    const int brow = blockIdx.x * BM;

    // load A tile (BM x 128)
    {
        constexpr int nf4 = BM * K / 4;    // 1024
        #pragma unroll
        for (int i = tid; i < nf4; i += 256) {
            int f = i * 4;
            int r = f >> 7;
            int c = f & 127;
            float4 v = make_float4(0.f, 0.f, 0.f, 0.f);
            int gr = brow + r;
            if (gr < n) v = *reinterpret_cast<const float4*>(A + (size_t)gr * K + c);
            *reinterpret_cast<float4*>(&Al[r * AS + c]) = v;
        }
    }

    const int r = tid >> 3;   // 0..31
    const int g = tid & 7;    // 0..7
    float4 acc[F4];
    #pragma unroll
    for (int j = 0; j < F4; ++j) acc[j] = make_float4(0.f, 0.f, 0.f, 0.f);

    #pragma unroll
    for (int kc = 0; kc < 4; ++kc) {
        // stage W rows kc*32 .. kc*32+31 (contiguous 32*C floats)
        constexpr int nf4 = 32 * C / 4;
        for (int i = tid; i < nf4; i += 256) {
            *reinterpret_cast<float4*>(&Wl[i * 4]) =
                *reinterpret_cast<const float4*>(W + (size_t)kc * 32 * C + i * 4);
        }
        __syncthreads();
        #pragma unroll
        for (int kk = 0; kk < 32; ++kk) {
            float a = Al[r * AS + kc * 32 + kk];
            const float* wr = &Wl[kk * C];
            #pragma unroll
            for (int j = 0; j < F4; ++j) {
                float4 w = *reinterpret_cast<const float4*>(wr + g * 4 + 32 * j);
                acc[j].x += a * w.x; acc[j].y += a * w.y;
                acc[j].z += a * w.z; acc[j].w += a * w.w;
            }
        }
        __syncthreads();
    }

    const int gr = brow + r;
    if (gr < n) {
        float pel[H], per_[H];
        #pragma unroll
        for (int h = 0; h < H; ++h) { pel[h] = 0.f; per_[h] = 0.f; }
        #pragma unroll
        for (int j = 0; j < F4; ++j) {
            int cbase = g * 4 + 32 * j;
            *reinterpret_cast<float4*>(feat + (size_t)gr * C + cbase) = acc[j];
            float av[4] = {acc[j].x, acc[j].y, acc[j].z, acc[j].w};
            #pragma unroll
            for (int u = 0; u < 4; ++u) {
                int col = cbase + u;
                int head = (H == 2) ? (col >> 6) : 0;
                int lc = col & 63;
                pel[head] += av[u] * al[head * 64 + lc];
                per_[head] += av[u] * ar[head * 64 + lc];
            }
        }
        // reduce across the 8 column-group lanes of this row
        #pragma unroll
        for (int off = 1; off < 8; off <<= 1) {
            #pragma unroll
            for (int h = 0; h < H; ++h) {
                pel[h] += __shfl_xor(pel[h], off, 64);
                per_[h] += __shfl_xor(per_[h], off, 64);
            }
        }
        if (g == 0) {
            #pragma unroll
            for (int h = 0; h < H; ++h) {
                el[(size_t)gr * H + h] = pel[h];
                er[(size_t)gr * H + h] = per_[h];
            }
        }
    }
}

// ---------------- per-layer init: segment-max encodings + denom ----------------
__global__ void init_md(unsigned* __restrict__ menc, float* __restrict__ den, int n)
{
    int i = blockIdx.x * blockDim.x + threadIdx.x;
    if (i < n) { menc[i] = 0x007FFFFFu; den[i] = 0.f; }  // enc(-inf)
}

// ---------------- edge pass 1: scores + segment max ----------------
template <int H>
__global__ void edge_max(const int* __restrict__ src, const int* __restrict__ dst,
                         const float* __restrict__ el, const float* __restrict__ er,
                         float* __restrict__ sbuf, unsigned* __restrict__ menc, int E)
{
    int e = blockIdx.x * blockDim.x + threadIdx.x;
    if (e >= E) return;
    int s = src[e], d = dst[e];
    if constexpr (H == 2) {
        float2 l = *reinterpret_cast<const float2*>(el + (size_t)s * 2);
        float2 rr = *reinterpret_cast<const float2*>(er + (size_t)d * 2);
        float v0 = l.x + rr.x; v0 = v0 >= 0.f ? v0 : 0.2f * v0;
        float v1 = l.y + rr.y; v1 = v1 >= 0.f ? v1 : 0.2f * v1;
        sbuf[(size_t)e * 2] = v0;
        sbuf[(size_t)e * 2 + 1] = v1;
        atomicMax(&menc[(size_t)d * 2], fenc(v0));
        atomicMax(&menc[(size_t)d * 2 + 1], fenc(v1));
    } else {
        float v = el[s] + er[d];
        v = v >= 0.f ? v : 0.2f * v;
        sbuf[e] = v;
        atomicMax(&menc[d], fenc(v));
    }
}

// ---------------- edge pass 2: exp(e - m) + segment sum ----------------
template <int H>
__global__ void edge_exp(const int* __restrict__ dst, float* __restrict__ sbuf,
                         const unsigned* __restrict__ menc, float* __restrict__ den, int E)
{
    int e = blockIdx.x * blockDim.x + threadIdx.x;
    if (e >= E) return;
    int d = dst[e];
    #pragma unroll
    for (int h = 0; h < H; ++h) {
        float m = fdec(menc[(size_t)d * H + h]);
        float ee = expf(sbuf[(size_t)e * H + h] - m);
        sbuf[(size_t)e * H + h] = ee;
        atomicAdd(&den[(size_t)d * H + h], ee);
    }
}

__global__ void recip_den(float* __restrict__ den, int n)
{
    int i = blockIdx.x * blockDim.x + threadIdx.x;
    if (i < n) den[i] = 1.f / fmaxf(den[i], 1e-9f);
}

// ---------------- edge pass 3: agg[dst] += alpha * feat[src] ----------------
template <int C, int H, int LOG2C>
__global__ void aggregate(const int* __restrict__ src, const int* __restrict__ dst,
                          const float* __restrict__ sbuf, const float* __restrict__ rden,
                          const float* __restrict__ feat, float* __restrict__ agg,
                          long long total)
{
    long long idx = (long long)blockIdx.x * blockDim.x + threadIdx.x;
    long long stride = (long long)gridDim.x * blockDim.x;
    for (; idx < total; idx += stride) {
        int e = (int)(idx >> LOG2C);
        int c = (int)(idx & (C - 1));
        int h = (H == 2) ? (c >> 6) : 0;
        int s = src[e], d = dst[e];
        float alpha = sbuf[(size_t)e * H + h] * rden[(size_t)d * H + h];
        atomicAdd(&agg[(size_t)d * C + c], alpha * feat[(size_t)s * C + c]);
    }
}

// ---------------- BatchNorm stats (C=128): sums[0:128]=sum, sums[128:256]=sumsq ----------------
__global__ void bn_stats(const float* __restrict__ h, float* __restrict__ sums, int n)
{
    __shared__ float s1[256], s2[256];
    int c = threadIdx.x & 127, half = threadIdx.x >> 7;
    float ls = 0.f, lq = 0.f;
    for (int r = blockIdx.x * 2 + half; r < n; r += gridDim.x * 2) {
        float v = h[(size_t)r * 128 + c];
        ls += v; lq += v * v;
    }
    s1[threadIdx.x] = ls; s2[threadIdx.x] = lq;
    __syncthreads();
    if (threadIdx.x < 128) {
        atomicAdd(&sums[c], s1[threadIdx.x] + s1[threadIdx.x + 128]);
        atomicAdd(&sums[128 + c], s2[threadIdx.x] + s2[threadIdx.x + 128]);
    }
}

// ---------------- BN apply + ReLU, in place (GAT bias cancels inside BN) ----------------
__global__ void bn_apply(float* __restrict__ h, const float* __restrict__ sums,
                         const float* __restrict__ g, const float* __restrict__ b,
                         long long total)
{
    long long i = (long long)blockIdx.x * blockDim.x + threadIdx.x;
    if (i >= total) return;
    int c = (int)(i & 127);
    const float invN = 1.f / (float)N_NODES;
    float mean = sums[c] * invN;
    float var = sums[128 + c] * invN - mean * mean;
    float v = (h[i] - mean) * rsqrtf(var + 1e-5f) * g[c] + b[c];
    h[i] = fmaxf(v, 0.f);
}

__global__ void add_bias64(float* __restrict__ h, const float* __restrict__ b, long long total)
{
    long long i = (long long)blockIdx.x * blockDim.x + threadIdx.x;
    if (i < total) h[i] += b[(int)(i & 63)];
}

// ---------------- predictor: wave per pair ----------------
__launch_bounds__(256)
__global__ void predictor(const float* __restrict__ h,
                          const int* __restrict__ ps, const int* __restrict__ pd,
                          const int* __restrict__ ns, const int* __restrict__ nd,
                          const float* __restrict__ W1, const float* __restrict__ b1,
                          const float* __restrict__ W2, const float* __restrict__ b2,
                          const float* __restrict__ W3, const float* __restrict__ b3,
                          float* __restrict__ out, int P)
{
    __shared__ float w1[64 * 64], w2[64 * 64], w3[64], bb1[64], bb2[64];
    int tid = threadIdx.x;
    for (int i = tid; i < 1024; i += 256) {
        *reinterpret_cast<float4*>(&w1[i * 4]) = *reinterpret_cast<const float4*>(W1 + i * 4);
        *reinterpret_cast<float4*>(&w2[i * 4]) = *reinterpret_cast<const float4*>(W2 + i * 4);
    }
    if (tid < 64) { w3[tid] = W3[tid]; bb1[tid] = b1[tid]; bb2[tid] = b2[tid]; }
    __syncthreads();
    float b3v = b3[0];
    int lane = tid & 63;
    int wave = tid >> 6;
    int gw = blockIdx.x * 4 + wave;
    int nw = gridDim.x * 4;
    for (int p = gw; p < 2 * P; p += nw) {
        int s, d;
        if (p < P) { s = ps[p]; d = pd[p]; }
        else       { s = ns[p - P]; d = nd[p - P]; }
        float z = h[(size_t)s * 64 + lane] * h[(size_t)d * 64 + lane];
        float a1 = bb1[lane];
        #pragma unroll
        for (int k = 0; k < 64; ++k) a1 += __shfl(z, k, 64) * w1[k * 64 + lane];
        a1 = fmaxf(a1, 0.f);
        float a2 = bb2[lane];
        #pragma unroll
        for (int k = 0; k < 64; ++k) a2 += __shfl(a1, k, 64) * w2[k * 64 + lane];
        a2 = fmaxf(a2, 0.f);
        float part = a2 * w3[lane];
        #pragma unroll
        for (int off = 32; off; off >>= 1) part += __shfl_xor(part, off, 64);
        if (lane == 0) out[p] = part + b3v;
    }
}

extern "C" void kernel_launch(void* const* d_in, const int* in_sizes, int n_in,
                              void* d_out, int out_size, void* d_ws, size_t ws_size,
                              hipStream_t stream)
{
    const float* x    = (const float*)d_in[0];
    const int* es     = (const int*)d_in[1];
    const int* ed     = (const int*)d_in[2];
    const int* ps     = (const int*)d_in[3];
    const int* pdst   = (const int*)d_in[4];
    const int* ns     = (const int*)d_in[5];
    const int* nd     = (const int*)d_in[6];
    const float* W0   = (const float*)d_in[7];
    const float* al0  = (const float*)d_in[8];
    const float* ar0  = (const float*)d_in[9];
    const float* W1   = (const float*)d_in[11];
    const float* al1  = (const float*)d_in[12];
    const float* ar1  = (const float*)d_in[13];
    const float* W2   = (const float*)d_in[15];
    const float* al2  = (const float*)d_in[16];
    const float* ar2  = (const float*)d_in[17];
    const float* b2   = (const float*)d_in[18];
    const float* bn0g = (const float*)d_in[19];
    const float* bn0b = (const float*)d_in[20];
    const float* bn1g = (const float*)d_in[21];
    const float* bn1b = (const float*)d_in[22];
    const float* pW1  = (const float*)d_in[23];
    const float* pb1  = (const float*)d_in[24];
    const float* pW2  = (const float*)d_in[25];
    const float* pb2  = (const float*)d_in[26];
    const float* pW3  = (const float*)d_in[27];
    const float* pb3  = (const float*)d_in[28];
    float* out = (float*)d_out;

    float* ws = (float*)d_ws;
    size_t off = 0;
    auto alloc = [&](size_t nelem) {
        float* p = ws + off;
        off += (nelem + 63) & ~(size_t)63;
        return p;
    };
    float* featb = alloc((size_t)N_NODES * 128);
    float* hb    = alloc((size_t)N_NODES * 128);
    float* el    = alloc((size_t)N_NODES * 2);
    float* er    = alloc((size_t)N_NODES * 2);
    unsigned* menc = (unsigned*)alloc((size_t)N_NODES * 2);
    float* den   = alloc((size_t)N_NODES * 2);
    float* sbuf  = alloc((size_t)N_EDGES * 2);
    float* bns   = alloc(256);

    dim3 blk(256);
    const int gemmGrid = (N_NODES + 31) / 32;
    const int edgeGrid = (N_EDGES + 255) / 256;

    // ================= layer 0 (C=128, H=2) =================
    gemm_feat<128, 2><<<gemmGrid, blk, 0, stream>>>(x, W0, al0, ar0, featb, el, er, N_NODES);
    init_md<<<(N_NODES * 2 + 255) / 256, blk, 0, stream>>>(menc, den, N_NODES * 2);
    hipMemsetAsync(hb, 0, (size_t)N_NODES * 128 * sizeof(float), stream);
    edge_max<2><<<edgeGrid, blk, 0, stream>>>(es, ed, el, er, sbuf, menc, N_EDGES);
    edge_exp<2><<<edgeGrid, blk, 0, stream>>>(ed, sbuf, menc, den, N_EDGES);
    recip_den<<<(N_NODES * 2 + 255) / 256, blk, 0, stream>>>(den, N_NODES * 2);
    aggregate<128, 2, 7><<<16384, blk, 0, stream>>>(es, ed, sbuf, den, featb, hb,
                                                    (long long)N_EDGES * 128);
    hipMemsetAsync(bns, 0, 256 * sizeof(float), stream);
    bn_stats<<<256, blk, 0, stream>>>(hb, bns, N_NODES);
    bn_apply<<<(N_NODES * 128 + 255) / 256, blk, 0, stream>>>(hb, bns, bn0g, bn0b,
                                                              (long long)N_NODES * 128);

    // ================= layer 1 (C=128, H=2) =================
    gemm_feat<128, 2><<<gemmGrid, blk, 0, stream>>>(hb, W1, al1, ar1, featb, el, er, N_NODES);
    init_md<<<(N_NODES * 2 + 255) / 256, blk, 0, stream>>>(menc, den, N_NODES * 2);
    hipMemsetAsync(hb, 0, (size_t)N_NODES * 128 * sizeof(float), stream);
    edge_max<2><<<edgeGrid, blk, 0, stream>>>(es, ed, el, er, sbuf, menc, N_EDGES);
    edge_exp<2><<<edgeGrid, blk, 0, stream>>>(ed, sbuf, menc, den, N_EDGES);
    recip_den<<<(N_NODES * 2 + 255) / 256, blk, 0, stream>>>(den, N_NODES * 2);
    aggregate<128, 2, 7><<<16384, blk, 0, stream>>>(es, ed, sbuf, den, featb, hb,
                                                    (long long)N_EDGES * 128);
    hipMemsetAsync(bns, 0, 256 * sizeof(float), stream);
    bn_stats<<<256, blk, 0, stream>>>(hb, bns, N_NODES);
    bn_apply<<<(N_NODES * 128 + 255) / 256, blk, 0, stream>>>(hb, bns, bn1g, bn1b,
                                                              (long long)N_NODES * 128);

    // ================= layer 2 (C=64, H=1) =================
    gemm_feat<64, 1><<<gemmGrid, blk, 0, stream>>>(hb, W2, al2, ar2, featb, el, er, N_NODES);
    init_md<<<(N_NODES + 255) / 256, blk, 0, stream>>>(menc, den, N_NODES);
    hipMemsetAsync(hb, 0, (size_t)N_NODES * 64 * sizeof(float), stream);
    edge_max<1><<<edgeGrid, blk, 0, stream>>>(es, ed, el, er, sbuf, menc, N_EDGES);
    edge_exp<1><<<edgeGrid, blk, 0, stream>>>(ed, sbuf, menc, den, N_EDGES);
    recip_den<<<(N_NODES + 255) / 256, blk, 0, stream>>>(den, N_NODES);
    aggregate<64, 1, 6><<<16384, blk, 0, stream>>>(es, ed, sbuf, den, featb, hb,
                                                   (long long)N_EDGES * 64);
    add_bias64<<<(N_NODES * 64 + 255) / 256, blk, 0, stream>>>(hb, b2, (long long)N_NODES * 64);

    // ================= predictor =================
    predictor<<<2048, blk, 0, stream>>>(hb, ps, pdst, ns, nd,
                                        pW1, pb1, pW2, pb2, pW3, pb3, out, 100000);
}

// Round 2
// 1898.542 us; speedup vs baseline: 2.6590x; 2.6590x over previous
//
#include <hip/hip_runtime.h>
#include <cstdint>
#include <cstddef>

#define N_NODES 50000
#define N_EDGES 800000

__device__ __forceinline__ unsigned fenc(float f) {
    unsigned u = __float_as_uint(f);
    return (u & 0x80000000u) ? ~u : (u | 0x80000000u);
}
__device__ __forceinline__ float fdec(unsigned u) {
    return __uint_as_float((u & 0x80000000u) ? (u & 0x7FFFFFFFu) : ~u);
}

// ---------------- GEMM (n x 128) @ (128 x C) + fused attn-dot epilogue ----------------
// feat = A @ W  [n, C]; el[n,h] = dot(feat[n, h*64:], al[h]); er likewise.
// 2 rows/thread, BM=64; W staged in 32-row chunks; unroll limited to avoid spill.
template <int C, int H>
__launch_bounds__(256, 2)
__global__ void gemm_feat(const float* __restrict__ A, const float* __restrict__ W,
                          const float* __restrict__ al, const float* __restrict__ ar,
                          float* __restrict__ feat, float* __restrict__ el,
                          float* __restrict__ er, int n)
{
    constexpr int K = 128;
    constexpr int BM = 64;
    constexpr int AS = K + 4;          // 132: 16B-aligned rows, bank-conflict-free
    constexpr int F4 = C / 32;         // float4s per thread per row
    __shared__ float Al[BM * AS];      // 33.8 KB
    __shared__ float Wl[32 * C];       // 16 KB (C=128)

    const int tid = threadIdx.x;
    const int brow = blockIdx.x * BM;

    // load A tile (BM x 128)
    for (int i = tid; i < BM * K / 4; i += 256) {
        int f = i * 4;
        int r = f >> 7;
        int c = f & 127;
        float4 v = make_float4(0.f, 0.f, 0.f, 0.f);
        int gr = brow + r;
        if (gr < n) v = *reinterpret_cast<const float4*>(A + (size_t)gr * K + c);
        *reinterpret_cast<float4*>(&Al[r * AS + c]) = v;
    }

    const int r0 = tid >> 3;   // 0..31 (second row = r0+32)
    const int g = tid & 7;     // 0..7
    float4 acc0[F4], acc1[F4];
    #pragma unroll
    for (int j = 0; j < F4; ++j) {
        acc0[j] = make_float4(0.f, 0.f, 0.f, 0.f);
        acc1[j] = make_float4(0.f, 0.f, 0.f, 0.f);
    }

    for (int kc = 0; kc < 4; ++kc) {
        // stage W rows kc*32 .. kc*32+31 (contiguous 32*C floats)
        for (int i = tid; i < 32 * C / 4; i += 256) {
            *reinterpret_cast<float4*>(&Wl[i * 4]) =
                *reinterpret_cast<const float4*>(W + (size_t)kc * 32 * C + i * 4);
        }
        __syncthreads();
        #pragma unroll 4
        for (int kk = 0; kk < 32; ++kk) {
            float a0 = Al[r0 * AS + kc * 32 + kk];
            float a1 = Al[(r0 + 32) * AS + kc * 32 + kk];
            const float* wr = &Wl[kk * C + g * 4];
            #pragma unroll
            for (int j = 0; j < F4; ++j) {
                float4 w = *reinterpret_cast<const float4*>(wr + 32 * j);
                acc0[j].x = fmaf(a0, w.x, acc0[j].x);
                acc0[j].y = fmaf(a0, w.y, acc0[j].y);
                acc0[j].z = fmaf(a0, w.z, acc0[j].z);
                acc0[j].w = fmaf(a0, w.w, acc0[j].w);
                acc1[j].x = fmaf(a1, w.x, acc1[j].x);
                acc1[j].y = fmaf(a1, w.y, acc1[j].y);
                acc1[j].z = fmaf(a1, w.z, acc1[j].z);
                acc1[j].w = fmaf(a1, w.w, acc1[j].w);
            }
        }
        __syncthreads();
    }

    #pragma unroll
    for (int half = 0; half < 2; ++half) {
        const int gr = brow + r0 + half * 32;
        float4* acc = half ? acc1 : acc0;
        if (gr < n) {
            float pel[H], per_[H];
            #pragma unroll
            for (int h = 0; h < H; ++h) { pel[h] = 0.f; per_[h] = 0.f; }
            #pragma unroll
            for (int j = 0; j < F4; ++j) {
                int cbase = g * 4 + 32 * j;
                *reinterpret_cast<float4*>(feat + (size_t)gr * C + cbase) = acc[j];
                float av[4] = {acc[j].x, acc[j].y, acc[j].z, acc[j].w};
                #pragma unroll
                for (int u = 0; u < 4; ++u) {
                    int col = cbase + u;
                    int head = (H == 2) ? (col >> 6) : 0;
                    int lc = col & 63;
                    pel[head] += av[u] * al[head * 64 + lc];
                    per_[head] += av[u] * ar[head * 64 + lc];
                }
            }
            // reduce across the 8 column-group lanes of this row
            #pragma unroll
            for (int off = 1; off < 8; off <<= 1) {
                #pragma unroll
                for (int h = 0; h < H; ++h) {
                    pel[h] += __shfl_xor(pel[h], off, 64);
                    per_[h] += __shfl_xor(per_[h], off, 64);
                }
            }
            if (g == 0) {
                #pragma unroll
                for (int h = 0; h < H; ++h) {
                    el[(size_t)gr * H + h] = pel[h];
                    er[(size_t)gr * H + h] = per_[h];
                }
            }
        }
    }
}

// ---------------- per-layer init: segment-max encodings + denom ----------------
__global__ void init_md(unsigned* __restrict__ menc, float* __restrict__ den, int n)
{
    int i = blockIdx.x * blockDim.x + threadIdx.x;
    if (i < n) { menc[i] = 0x007FFFFFu; den[i] = 0.f; }  // enc(-inf)
}

// ---------------- edge pass 1: scores + segment max ----------------
template <int H>
__global__ void edge_max(const int* __restrict__ src, const int* __restrict__ dst,
                         const float* __restrict__ el, const float* __restrict__ er,
                         float* __restrict__ sbuf, unsigned* __restrict__ menc, int E)
{
    int e = blockIdx.x * blockDim.x + threadIdx.x;
    if (e >= E) return;
    int s = src[e], d = dst[e];
    if constexpr (H == 2) {
        float2 l = *reinterpret_cast<const float2*>(el + (size_t)s * 2);
        float2 rr = *reinterpret_cast<const float2*>(er + (size_t)d * 2);
        float v0 = l.x + rr.x; v0 = v0 >= 0.f ? v0 : 0.2f * v0;
        float v1 = l.y + rr.y; v1 = v1 >= 0.f ? v1 : 0.2f * v1;
        sbuf[(size_t)e * 2] = v0;
        sbuf[(size_t)e * 2 + 1] = v1;
        atomicMax(&menc[(size_t)d * 2], fenc(v0));
        atomicMax(&menc[(size_t)d * 2 + 1], fenc(v1));
    } else {
        float v = el[s] + er[d];
        v = v >= 0.f ? v : 0.2f * v;
        sbuf[e] = v;
        atomicMax(&menc[d], fenc(v));
    }
}

// ---------------- edge pass 2: exp(e - m) + segment sum ----------------
template <int H>
__global__ void edge_exp(const int* __restrict__ dst, float* __restrict__ sbuf,
                         const unsigned* __restrict__ menc, float* __restrict__ den, int E)
{
    int e = blockIdx.x * blockDim.x + threadIdx.x;
    if (e >= E) return;
    int d = dst[e];
    #pragma unroll
    for (int h = 0; h < H; ++h) {
        float m = fdec(menc[(size_t)d * H + h]);
        float ee = expf(sbuf[(size_t)e * H + h] - m);
        sbuf[(size_t)e * H + h] = ee;
        atomicAdd(&den[(size_t)d * H + h], ee);
    }
}

__global__ void recip_den(float* __restrict__ den, int n)
{
    int i = blockIdx.x * blockDim.x + threadIdx.x;
    if (i < n) den[i] = 1.f / fmaxf(den[i], 1e-9f);
}

// ---------------- edge pass 3: agg[dst] += alpha * feat[src] ----------------
template <int C, int H, int LOG2C>
__global__ void aggregate(const int* __restrict__ src, const int* __restrict__ dst,
                          const float* __restrict__ sbuf, const float* __restrict__ rden,
                          const float* __restrict__ feat, float* __restrict__ agg,
                          long long total)
{
    long long idx = (long long)blockIdx.x * blockDim.x + threadIdx.x;
    long long stride = (long long)gridDim.x * blockDim.x;
    for (; idx < total; idx += stride) {
        int e = (int)(idx >> LOG2C);
        int c = (int)(idx & (C - 1));
        int h = (H == 2) ? (c >> 6) : 0;
        int s = src[e], d = dst[e];
        float alpha = sbuf[(size_t)e * H + h] * rden[(size_t)d * H + h];
        atomicAdd(&agg[(size_t)d * C + c], alpha * feat[(size_t)s * C + c]);
    }
}

// ---------------- BatchNorm stats (C=128): sums[0:128]=sum, sums[128:256]=sumsq ----------------
__global__ void bn_stats(const float* __restrict__ h, float* __restrict__ sums, int n)
{
    __shared__ float s1[256], s2[256];
    int c = threadIdx.x & 127, half = threadIdx.x >> 7;
    float ls = 0.f, lq = 0.f;
    for (int r = blockIdx.x * 2 + half; r < n; r += gridDim.x * 2) {
        float v = h[(size_t)r * 128 + c];
        ls += v; lq += v * v;
    }
    s1[threadIdx.x] = ls; s2[threadIdx.x] = lq;
    __syncthreads();
    if (threadIdx.x < 128) {
        atomicAdd(&sums[c], s1[threadIdx.x] + s1[threadIdx.x + 128]);
        atomicAdd(&sums[128 + c], s2[threadIdx.x] + s2[threadIdx.x + 128]);
    }
}

// ---------------- BN apply + ReLU, in place (GAT bias cancels inside BN) ----------------
__global__ void bn_apply(float* __restrict__ h, const float* __restrict__ sums,
                         const float* __restrict__ g, const float* __restrict__ b,
                         long long total)
{
    long long i = (long long)blockIdx.x * blockDim.x + threadIdx.x;
    if (i >= total) return;
    int c = (int)(i & 127);
    const float invN = 1.f / (float)N_NODES;
    float mean = sums[c] * invN;
    float var = sums[128 + c] * invN - mean * mean;
    float v = (h[i] - mean) * rsqrtf(var + 1e-5f) * g[c] + b[c];
    h[i] = fmaxf(v, 0.f);
}

__global__ void add_bias64(float* __restrict__ h, const float* __restrict__ b, long long total)
{
    long long i = (long long)blockIdx.x * blockDim.x + threadIdx.x;
    if (i < total) h[i] += b[(int)(i & 63)];
}

// ---------------- predictor: wave per pair ----------------
__launch_bounds__(256)
__global__ void predictor(const float* __restrict__ h,
                          const int* __restrict__ ps, const int* __restrict__ pd,
                          const int* __restrict__ ns, const int* __restrict__ nd,
                          const float* __restrict__ W1, const float* __restrict__ b1,
                          const float* __restrict__ W2, const float* __restrict__ b2,
                          const float* __restrict__ W3, const float* __restrict__ b3,
                          float* __restrict__ out, int P)
{
    __shared__ float w1[64 * 64], w2[64 * 64], w3[64], bb1[64], bb2[64];
    int tid = threadIdx.x;
    for (int i = tid; i < 1024; i += 256) {
        *reinterpret_cast<float4*>(&w1[i * 4]) = *reinterpret_cast<const float4*>(W1 + i * 4);
        *reinterpret_cast<float4*>(&w2[i * 4]) = *reinterpret_cast<const float4*>(W2 + i * 4);
    }
    if (tid < 64) { w3[tid] = W3[tid]; bb1[tid] = b1[tid]; bb2[tid] = b2[tid]; }
    __syncthreads();
    float b3v = b3[0];
    int lane = tid & 63;
    int wave = tid >> 6;
    int gw = blockIdx.x * 4 + wave;
    int nw = gridDim.x * 4;
    for (int p = gw; p < 2 * P; p += nw) {
        int s, d;
        if (p < P) { s = ps[p]; d = pd[p]; }
        else       { s = ns[p - P]; d = nd[p - P]; }
        float z = h[(size_t)s * 64 + lane] * h[(size_t)d * 64 + lane];
        float a1 = bb1[lane];
        #pragma unroll
        for (int k = 0; k < 64; ++k) a1 += __shfl(z, k, 64) * w1[k * 64 + lane];
        a1 = fmaxf(a1, 0.f);
        float a2 = bb2[lane];
        #pragma unroll
        for (int k = 0; k < 64; ++k) a2 += __shfl(a1, k, 64) * w2[k * 64 + lane];
        a2 = fmaxf(a2, 0.f);
        float part = a2 * w3[lane];
        #pragma unroll
        for (int off = 32; off; off >>= 1) part += __shfl_xor(part, off, 64);
        if (lane == 0) out[p] = part + b3v;
    }
}

extern "C" void kernel_launch(void* const* d_in, const int* in_sizes, int n_in,
                              void* d_out, int out_size, void* d_ws, size_t ws_size,
                              hipStream_t stream)
{
    const float* x    = (const float*)d_in[0];
    const int* es     = (const int*)d_in[1];
    const int* ed     = (const int*)d_in[2];
    const int* ps     = (const int*)d_in[3];
    const int* pdst   = (const int*)d_in[4];
    const int* ns     = (const int*)d_in[5];
    const int* nd     = (const int*)d_in[6];
    const float* W0   = (const float*)d_in[7];
    const float* al0  = (const float*)d_in[8];
    const float* ar0  = (const float*)d_in[9];
    const float* W1   = (const float*)d_in[11];
    const float* al1  = (const float*)d_in[12];
    const float* ar1  = (const float*)d_in[13];
    const float* W2   = (const float*)d_in[15];
    const float* al2  = (const float*)d_in[16];
    const float* ar2  = (const float*)d_in[17];
    const float* b2   = (const float*)d_in[18];
    const float* bn0g = (const float*)d_in[19];
    const float* bn0b = (const float*)d_in[20];
    const float* bn1g = (const float*)d_in[21];
    const float* bn1b = (const float*)d_in[22];
    const float* pW1  = (const float*)d_in[23];
    const float* pb1  = (const float*)d_in[24];
    const float* pW2  = (const float*)d_in[25];
    const float* pb2  = (const float*)d_in[26];
    const float* pW3  = (const float*)d_in[27];
    const float* pb3  = (const float*)d_in[28];
    float* out = (float*)d_out;

    float* ws = (float*)d_ws;
    size_t off = 0;
    auto alloc = [&](size_t nelem) {
        float* p = ws + off;
        off += (nelem + 63) & ~(size_t)63;
        return p;
    };
    float* featb = alloc((size_t)N_NODES * 128);
    float* hb    = alloc((size_t)N_NODES * 128);
    float* el    = alloc((size_t)N_NODES * 2);
    float* er    = alloc((size_t)N_NODES * 2);
    unsigned* menc = (unsigned*)alloc((size_t)N_NODES * 2);
    float* den   = alloc((size_t)N_NODES * 2);
    float* sbuf  = alloc((size_t)N_EDGES * 2);
    float* bns   = alloc(256);

    dim3 blk(256);
    const int gemmGrid = (N_NODES + 63) / 64;
    const int edgeGrid = (N_EDGES + 255) / 256;

    // ================= layer 0 (C=128, H=2) =================
    gemm_feat<128, 2><<<gemmGrid, blk, 0, stream>>>(x, W0, al0, ar0, featb, el, er, N_NODES);
    init_md<<<(N_NODES * 2 + 255) / 256, blk, 0, stream>>>(menc, den, N_NODES * 2);
    hipMemsetAsync(hb, 0, (size_t)N_NODES * 128 * sizeof(float), stream);
    edge_max<2><<<edgeGrid, blk, 0, stream>>>(es, ed, el, er, sbuf, menc, N_EDGES);
    edge_exp<2><<<edgeGrid, blk, 0, stream>>>(ed, sbuf, menc, den, N_EDGES);
    recip_den<<<(N_NODES * 2 + 255) / 256, blk, 0, stream>>>(den, N_NODES * 2);
    aggregate<128, 2, 7><<<16384, blk, 0, stream>>>(es, ed, sbuf, den, featb, hb,
                                                    (long long)N_EDGES * 128);
    hipMemsetAsync(bns, 0, 256 * sizeof(float), stream);
    bn_stats<<<256, blk, 0, stream>>>(hb, bns, N_NODES);
    bn_apply<<<(N_NODES * 128 + 255) / 256, blk, 0, stream>>>(hb, bns, bn0g, bn0b,
                                                              (long long)N_NODES * 128);

    // ================= layer 1 (C=128, H=2) =================
    gemm_feat<128, 2><<<gemmGrid, blk, 0, stream>>>(hb, W1, al1, ar1, featb, el, er, N_NODES);
    init_md<<<(N_NODES * 2 + 255) / 256, blk, 0, stream>>>(menc, den, N_NODES * 2);
    hipMemsetAsync(hb, 0, (size_t)N_NODES * 128 * sizeof(float), stream);
    edge_max<2><<<edgeGrid, blk, 0, stream>>>(es, ed, el, er, sbuf, menc, N_EDGES);
    edge_exp<2><<<edgeGrid, blk, 0, stream>>>(ed, sbuf, menc, den, N_EDGES);
    recip_den<<<(N_NODES * 2 + 255) / 256, blk, 0, stream>>>(den, N_NODES * 2);
    aggregate<128, 2, 7><<<16384, blk, 0, stream>>>(es, ed, sbuf, den, featb, hb,
                                                    (long long)N_EDGES * 128);
    hipMemsetAsync(bns, 0, 256 * sizeof(float), stream);
    bn_stats<<<256, blk, 0, stream>>>(hb, bns, N_NODES);
    bn_apply<<<(N_NODES * 128 + 255) / 256, blk, 0, stream>>>(hb, bns, bn1g, bn1b,
                                                              (long long)N_NODES * 128);

    // ================= layer 2 (C=64, H=1) =================
    gemm_feat<64, 1><<<gemmGrid, blk, 0, stream>>>(hb, W2, al2, ar2, featb, el, er, N_NODES);
    init_md<<<(N_NODES + 255) / 256, blk, 0, stream>>>(menc, den, N_NODES);
    hipMemsetAsync(hb, 0, (size_t)N_NODES * 64 * sizeof(float), stream);
    edge_max<1><<<edgeGrid, blk, 0, stream>>>(es, ed, el, er, sbuf, menc, N_EDGES);
    edge_exp<1><<<edgeGrid, blk, 0, stream>>>(ed, sbuf, menc, den, N_EDGES);
    recip_den<<<(N_NODES + 255) / 256, blk, 0, stream>>>(den, N_NODES);
    aggregate<64, 1, 6><<<16384, blk, 0, stream>>>(es, ed, sbuf, den, featb, hb,
                                                   (long long)N_EDGES * 64);
    add_bias64<<<(N_NODES * 64 + 255) / 256, blk, 0, stream>>>(hb, b2, (long long)N_NODES * 64);

    // ================= predictor =================
    predictor<<<2048, blk, 0, stream>>>(hb, ps, pdst, ns, nd,
                                        pW1, pb1, pW2, pb2, pW3, pb3, out, 100000);
}

// Round 3
// 976.333 us; speedup vs baseline: 5.1705x; 1.9446x over previous
//
#include <hip/hip_runtime.h>
#include <cstdint>
#include <cstddef>

#define N_NODES 50000
#define N_EDGES 800000

// ---------------- GEMM (n x 128) @ (128 x C) + fused attn-dot epilogue ----------------
template <int C, int H>
__launch_bounds__(256, 2)
__global__ void gemm_feat(const float* __restrict__ A, const float* __restrict__ W,
                          const float* __restrict__ al, const float* __restrict__ ar,
                          float* __restrict__ feat, float* __restrict__ el,
                          float* __restrict__ er, int n)
{
    constexpr int K = 128;
    constexpr int BM = 64;
    constexpr int AS = K + 4;
    constexpr int F4 = C / 32;
    __shared__ float Al[BM * AS];
    __shared__ float Wl[32 * C];

    const int tid = threadIdx.x;
    const int brow = blockIdx.x * BM;

    for (int i = tid; i < BM * K / 4; i += 256) {
        int f = i * 4;
        int r = f >> 7;
        int c = f & 127;
        float4 v = make_float4(0.f, 0.f, 0.f, 0.f);
        int gr = brow + r;
        if (gr < n) v = *reinterpret_cast<const float4*>(A + (size_t)gr * K + c);
        *reinterpret_cast<float4*>(&Al[r * AS + c]) = v;
    }

    const int r0 = tid >> 3;
    const int g = tid & 7;
    float4 acc0[F4], acc1[F4];
    #pragma unroll
    for (int j = 0; j < F4; ++j) {
        acc0[j] = make_float4(0.f, 0.f, 0.f, 0.f);
        acc1[j] = make_float4(0.f, 0.f, 0.f, 0.f);
    }

    for (int kc = 0; kc < 4; ++kc) {
        for (int i = tid; i < 32 * C / 4; i += 256) {
            *reinterpret_cast<float4*>(&Wl[i * 4]) =
                *reinterpret_cast<const float4*>(W + (size_t)kc * 32 * C + i * 4);
        }
        __syncthreads();
        #pragma unroll 4
        for (int kk = 0; kk < 32; ++kk) {
            float a0 = Al[r0 * AS + kc * 32 + kk];
            float a1 = Al[(r0 + 32) * AS + kc * 32 + kk];
            const float* wr = &Wl[kk * C + g * 4];
            #pragma unroll
            for (int j = 0; j < F4; ++j) {
                float4 w = *reinterpret_cast<const float4*>(wr + 32 * j);
                acc0[j].x = fmaf(a0, w.x, acc0[j].x);
                acc0[j].y = fmaf(a0, w.y, acc0[j].y);
                acc0[j].z = fmaf(a0, w.z, acc0[j].z);
                acc0[j].w = fmaf(a0, w.w, acc0[j].w);
                acc1[j].x = fmaf(a1, w.x, acc1[j].x);
                acc1[j].y = fmaf(a1, w.y, acc1[j].y);
                acc1[j].z = fmaf(a1, w.z, acc1[j].z);
                acc1[j].w = fmaf(a1, w.w, acc1[j].w);
            }
        }
        __syncthreads();
    }

    #pragma unroll
    for (int half = 0; half < 2; ++half) {
        const int gr = brow + r0 + half * 32;
        float4* acc = half ? acc1 : acc0;
        if (gr < n) {
            float pel[H], per_[H];
            #pragma unroll
            for (int h = 0; h < H; ++h) { pel[h] = 0.f; per_[h] = 0.f; }
            #pragma unroll
            for (int j = 0; j < F4; ++j) {
                int cbase = g * 4 + 32 * j;
                *reinterpret_cast<float4*>(feat + (size_t)gr * C + cbase) = acc[j];
                float av[4] = {acc[j].x, acc[j].y, acc[j].z, acc[j].w};
                #pragma unroll
                for (int u = 0; u < 4; ++u) {
                    int col = cbase + u;
                    int head = (H == 2) ? (col >> 6) : 0;
                    int lc = col & 63;
                    pel[head] += av[u] * al[head * 64 + lc];
                    per_[head] += av[u] * ar[head * 64 + lc];
                }
            }
            #pragma unroll
            for (int off = 1; off < 8; off <<= 1) {
                #pragma unroll
                for (int h = 0; h < H; ++h) {
                    pel[h] += __shfl_xor(pel[h], off, 64);
                    per_[h] += __shfl_xor(per_[h], off, 64);
                }
            }
            if (g == 0) {
                #pragma unroll
                for (int h = 0; h < H; ++h) {
                    el[(size_t)gr * H + h] = pel[h];
                    er[(size_t)gr * H + h] = per_[h];
                }
            }
        }
    }
}

// ---------------- CSR build (by dst), once per launch ----------------
__global__ void hist_dst(const int* __restrict__ dst, int* __restrict__ cnt, int E)
{
    int e = blockIdx.x * blockDim.x + threadIdx.x;
    if (e < E) atomicAdd(&cnt[dst[e]], 1);
}

__global__ void scan_block_sums(const int* __restrict__ cnt, int* __restrict__ bsum, int n)
{
    __shared__ int sh[256];
    int i = blockIdx.x * 256 + threadIdx.x;
    sh[threadIdx.x] = (i < n) ? cnt[i] : 0;
    __syncthreads();
    for (int off = 128; off; off >>= 1) {
        if (threadIdx.x < off) sh[threadIdx.x] += sh[threadIdx.x + off];
        __syncthreads();
    }
    if (threadIdx.x == 0) bsum[blockIdx.x] = sh[0];
}

__global__ void scan_bsum(int* __restrict__ bsum, int nb)
{
    __shared__ int sh[256];
    int t = threadIdx.x;
    sh[t] = (t < nb) ? bsum[t] : 0;
    __syncthreads();
    for (int off = 1; off < 256; off <<= 1) {
        int u = (t >= off) ? sh[t - off] : 0;
        __syncthreads();
        sh[t] += u;
        __syncthreads();
    }
    if (t < nb) bsum[t] = t ? sh[t - 1] : 0;   // exclusive
}

__global__ void scan_final(const int* __restrict__ cnt, const int* __restrict__ bsum,
                           int* __restrict__ rs, int* __restrict__ cursor, int n)
{
    __shared__ int sh[256];
    int t = threadIdx.x;
    int i = blockIdx.x * 256 + t;
    int v = (i < n) ? cnt[i] : 0;
    sh[t] = v;
    __syncthreads();
    for (int off = 1; off < 256; off <<= 1) {
        int u = (t >= off) ? sh[t - off] : 0;
        __syncthreads();
        sh[t] += u;
        __syncthreads();
    }
    int excl = sh[t] - v + bsum[blockIdx.x];
    if (i < n) { rs[i] = excl; cursor[i] = excl; }
    if (i == n - 1) rs[n] = excl + v;
}

__global__ void scatter_csr(const int* __restrict__ src, const int* __restrict__ dst,
                            int* __restrict__ cursor, int* __restrict__ csr, int E)
{
    int e = blockIdx.x * blockDim.x + threadIdx.x;
    if (e < E) {
        int d = dst[e];
        int pos = atomicAdd(&cursor[d], 1);
        csr[pos] = src[e];
    }
}

// ---------------- fused GAT edge-softmax + aggregate: one wave per dst node ----------------
// Online softmax per head; lane l owns channel l (head0) and 64+l (head1).
template <int C, int H>
__launch_bounds__(256)
__global__ void gat_agg(const int* __restrict__ rs, const int* __restrict__ csr,
                        const float* __restrict__ el, const float* __restrict__ er,
                        const float* __restrict__ feat, const float* __restrict__ bias,
                        float* __restrict__ outp, int n)
{
    int node = blockIdx.x * 4 + (threadIdx.x >> 6);
    if (node >= n) return;
    int lane = threadIdx.x & 63;
    int start = rs[node], end = rs[node + 1];

    float er0, er1;
    if constexpr (H == 2) {
        float2 e2 = *reinterpret_cast<const float2*>(er + (size_t)node * 2);
        er0 = e2.x; er1 = e2.y;
    } else {
        er0 = er[node]; er1 = 0.f;
    }

    float m0 = -INFINITY, s0 = 0.f, acc0 = 0.f;
    float m1 = -INFINITY, s1 = 0.f, acc1 = 0.f;

    for (int j = start; j < end; ++j) {
        int s = csr[j];
        if constexpr (H == 2) {
            float2 l2 = *reinterpret_cast<const float2*>(el + (size_t)s * 2);
            float e0 = l2.x + er0; e0 = e0 >= 0.f ? e0 : 0.2f * e0;
            float e1 = l2.y + er1; e1 = e1 >= 0.f ? e1 : 0.2f * e1;
            float f0 = feat[(size_t)s * C + lane];
            float f1 = feat[(size_t)s * C + 64 + lane];
            float mn0 = fmaxf(m0, e0);
            float c0 = __expf(m0 - mn0);
            float p0 = __expf(e0 - mn0);
            s0 = s0 * c0 + p0; acc0 = acc0 * c0 + p0 * f0; m0 = mn0;
            float mn1 = fmaxf(m1, e1);
            float c1 = __expf(m1 - mn1);
            float p1 = __expf(e1 - mn1);
            s1 = s1 * c1 + p1; acc1 = acc1 * c1 + p1 * f1; m1 = mn1;
        } else {
            float e0 = el[s] + er0; e0 = e0 >= 0.f ? e0 : 0.2f * e0;
            float f0 = feat[(size_t)s * C + lane];
            float mn0 = fmaxf(m0, e0);
            float c0 = __expf(m0 - mn0);
            float p0 = __expf(e0 - mn0);
            s0 = s0 * c0 + p0; acc0 = acc0 * c0 + p0 * f0; m0 = mn0;
        }
    }

    float o0 = acc0 / fmaxf(s0, 1e-9f);
    if (bias) o0 += bias[lane];
    outp[(size_t)node * C + lane] = o0;
    if constexpr (H == 2) {
        float o1 = acc1 / fmaxf(s1, 1e-9f);
        if (bias) o1 += bias[64 + lane];
        outp[(size_t)node * C + 64 + lane] = o1;
    }
}

// ---------------- BatchNorm stats (C=128) ----------------
__global__ void bn_stats(const float* __restrict__ h, float* __restrict__ sums, int n)
{
    __shared__ float s1[256], s2[256];
    int c = threadIdx.x & 127, half = threadIdx.x >> 7;
    float ls = 0.f, lq = 0.f;
    for (int r = blockIdx.x * 2 + half; r < n; r += gridDim.x * 2) {
        float v = h[(size_t)r * 128 + c];
        ls += v; lq += v * v;
    }
    s1[threadIdx.x] = ls; s2[threadIdx.x] = lq;
    __syncthreads();
    if (threadIdx.x < 128) {
        atomicAdd(&sums[c], s1[threadIdx.x] + s1[threadIdx.x + 128]);
        atomicAdd(&sums[128 + c], s2[threadIdx.x] + s2[threadIdx.x + 128]);
    }
}

__global__ void bn_apply(float* __restrict__ h, const float* __restrict__ sums,
                         const float* __restrict__ g, const float* __restrict__ b,
                         long long total)
{
    long long i = (long long)blockIdx.x * blockDim.x + threadIdx.x;
    if (i >= total) return;
    int c = (int)(i & 127);
    const float invN = 1.f / (float)N_NODES;
    float mean = sums[c] * invN;
    float var = sums[128 + c] * invN - mean * mean;
    float v = (h[i] - mean) * rsqrtf(var + 1e-5f) * g[c] + b[c];
    h[i] = fmaxf(v, 0.f);
}

// ---------------- predictor: wave per pair ----------------
__launch_bounds__(256)
__global__ void predictor(const float* __restrict__ h,
                          const int* __restrict__ ps, const int* __restrict__ pd,
                          const int* __restrict__ ns, const int* __restrict__ nd,
                          const float* __restrict__ W1, const float* __restrict__ b1,
                          const float* __restrict__ W2, const float* __restrict__ b2,
                          const float* __restrict__ W3, const float* __restrict__ b3,
                          float* __restrict__ out, int P)
{
    __shared__ float w1[64 * 64], w2[64 * 64], w3[64], bb1[64], bb2[64];
    int tid = threadIdx.x;
    for (int i = tid; i < 1024; i += 256) {
        *reinterpret_cast<float4*>(&w1[i * 4]) = *reinterpret_cast<const float4*>(W1 + i * 4);
        *reinterpret_cast<float4*>(&w2[i * 4]) = *reinterpret_cast<const float4*>(W2 + i * 4);
    }
    if (tid < 64) { w3[tid] = W3[tid]; bb1[tid] = b1[tid]; bb2[tid] = b2[tid]; }
    __syncthreads();
    float b3v = b3[0];
    int lane = tid & 63;
    int wave = tid >> 6;
    int gw = blockIdx.x * 4 + wave;
    int nw = gridDim.x * 4;
    for (int p = gw; p < 2 * P; p += nw) {
        int s, d;
        if (p < P) { s = ps[p]; d = pd[p]; }
        else       { s = ns[p - P]; d = nd[p - P]; }
        float z = h[(size_t)s * 64 + lane] * h[(size_t)d * 64 + lane];
        float a1 = bb1[lane];
        #pragma unroll
        for (int k = 0; k < 64; ++k) a1 += __shfl(z, k, 64) * w1[k * 64 + lane];
        a1 = fmaxf(a1, 0.f);
        float a2 = bb2[lane];
        #pragma unroll
        for (int k = 0; k < 64; ++k) a2 += __shfl(a1, k, 64) * w2[k * 64 + lane];
        a2 = fmaxf(a2, 0.f);
        float part = a2 * w3[lane];
        #pragma unroll
        for (int off = 32; off; off >>= 1) part += __shfl_xor(part, off, 64);
        if (lane == 0) out[p] = part + b3v;
    }
}

extern "C" void kernel_launch(void* const* d_in, const int* in_sizes, int n_in,
                              void* d_out, int out_size, void* d_ws, size_t ws_size,
                              hipStream_t stream)
{
    const float* x    = (const float*)d_in[0];
    const int* es     = (const int*)d_in[1];
    const int* ed     = (const int*)d_in[2];
    const int* ps     = (const int*)d_in[3];
    const int* pdst   = (const int*)d_in[4];
    const int* ns     = (const int*)d_in[5];
    const int* nd     = (const int*)d_in[6];
    const float* W0   = (const float*)d_in[7];
    const float* al0  = (const float*)d_in[8];
    const float* ar0  = (const float*)d_in[9];
    const float* W1   = (const float*)d_in[11];
    const float* al1  = (const float*)d_in[12];
    const float* ar1  = (const float*)d_in[13];
    const float* W2   = (const float*)d_in[15];
    const float* al2  = (const float*)d_in[16];
    const float* ar2  = (const float*)d_in[17];
    const float* b2   = (const float*)d_in[18];
    const float* bn0g = (const float*)d_in[19];
    const float* bn0b = (const float*)d_in[20];
    const float* bn1g = (const float*)d_in[21];
    const float* bn1b = (const float*)d_in[22];
    const float* pW1  = (const float*)d_in[23];
    const float* pb1  = (const float*)d_in[24];
    const float* pW2  = (const float*)d_in[25];
    const float* pb2  = (const float*)d_in[26];
    const float* pW3  = (const float*)d_in[27];
    const float* pb3  = (const float*)d_in[28];
    float* out = (float*)d_out;

    float* ws = (float*)d_ws;
    size_t off = 0;
    auto alloc = [&](size_t nelem) {
        float* p = ws + off;
        off += (nelem + 63) & ~(size_t)63;
        return p;
    };
    float* featb = alloc((size_t)N_NODES * 128);
    float* hb    = alloc((size_t)N_NODES * 128);
    float* el    = alloc((size_t)N_NODES * 2);
    float* er    = alloc((size_t)N_NODES * 2);
    float* bns   = alloc(256);
    int* cnt     = (int*)alloc(N_NODES);
    int* rs      = (int*)alloc(N_NODES + 1);
    int* cursor  = (int*)alloc(N_NODES);
    int* bsum    = (int*)alloc(256);
    int* csr     = (int*)alloc(N_EDGES);

    dim3 blk(256);
    const int gemmGrid = (N_NODES + 63) / 64;
    const int edgeGrid = (N_EDGES + 255) / 256;
    const int nodeBlocks = (N_NODES + 255) / 256;   // 196
    const int aggGrid = (N_NODES + 3) / 4;

    // ================= CSR build (once; graph shared by all layers) =================
    hipMemsetAsync(cnt, 0, (size_t)N_NODES * sizeof(int), stream);
    hist_dst<<<edgeGrid, blk, 0, stream>>>(ed, cnt, N_EDGES);
    scan_block_sums<<<nodeBlocks, blk, 0, stream>>>(cnt, bsum, N_NODES);
    scan_bsum<<<1, blk, 0, stream>>>(bsum, nodeBlocks);
    scan_final<<<nodeBlocks, blk, 0, stream>>>(cnt, bsum, rs, cursor, N_NODES);
    scatter_csr<<<edgeGrid, blk, 0, stream>>>(es, ed, cursor, csr, N_EDGES);

    // ================= layer 0 (C=128, H=2) =================
    gemm_feat<128, 2><<<gemmGrid, blk, 0, stream>>>(x, W0, al0, ar0, featb, el, er, N_NODES);
    gat_agg<128, 2><<<aggGrid, blk, 0, stream>>>(rs, csr, el, er, featb, nullptr, hb, N_NODES);
    hipMemsetAsync(bns, 0, 256 * sizeof(float), stream);
    bn_stats<<<256, blk, 0, stream>>>(hb, bns, N_NODES);
    bn_apply<<<(N_NODES * 128 + 255) / 256, blk, 0, stream>>>(hb, bns, bn0g, bn0b,
                                                              (long long)N_NODES * 128);

    // ================= layer 1 (C=128, H=2) =================
    gemm_feat<128, 2><<<gemmGrid, blk, 0, stream>>>(hb, W1, al1, ar1, featb, el, er, N_NODES);
    gat_agg<128, 2><<<aggGrid, blk, 0, stream>>>(rs, csr, el, er, featb, nullptr, hb, N_NODES);
    hipMemsetAsync(bns, 0, 256 * sizeof(float), stream);
    bn_stats<<<256, blk, 0, stream>>>(hb, bns, N_NODES);
    bn_apply<<<(N_NODES * 128 + 255) / 256, blk, 0, stream>>>(hb, bns, bn1g, bn1b,
                                                              (long long)N_NODES * 128);

    // ================= layer 2 (C=64, H=1) =================
    gemm_feat<64, 1><<<gemmGrid, blk, 0, stream>>>(hb, W2, al2, ar2, featb, el, er, N_NODES);
    gat_agg<64, 1><<<aggGrid, blk, 0, stream>>>(rs, csr, el, er, featb, b2, hb, N_NODES);

    // ================= predictor =================
    predictor<<<2048, blk, 0, stream>>>(hb, ps, pdst, ns, nd,
                                        pW1, pb1, pW2, pb2, pW3, pb3, out, 100000);
}

// Round 4
// 734.175 us; speedup vs baseline: 6.8760x; 1.3298x over previous
//
#include <hip/hip_runtime.h>
#include <cstdint>
#include <cstddef>

#define N_NODES 50000
#define N_EDGES 800000

// ---------------- GEMM (n x 128) @ (128 x C) + fused attn-dot epilogue ----------------
template <int C, int H>
__launch_bounds__(256, 2)
__global__ void gemm_feat(const float* __restrict__ A, const float* __restrict__ W,
                          const float* __restrict__ al, const float* __restrict__ ar,
                          float* __restrict__ feat, float* __restrict__ el,
                          float* __restrict__ er, int n)
{
    constexpr int K = 128;
    constexpr int BM = 64;
    constexpr int AS = K + 4;
    constexpr int F4 = C / 32;
    __shared__ float Al[BM * AS];
    __shared__ float Wl[32 * C];

    const int tid = threadIdx.x;
    const int brow = blockIdx.x * BM;

    for (int i = tid; i < BM * K / 4; i += 256) {
        int f = i * 4;
        int r = f >> 7;
        int c = f & 127;
        float4 v = make_float4(0.f, 0.f, 0.f, 0.f);
        int gr = brow + r;
        if (gr < n) v = *reinterpret_cast<const float4*>(A + (size_t)gr * K + c);
        *reinterpret_cast<float4*>(&Al[r * AS + c]) = v;
    }

    const int r0 = tid >> 3;
    const int g = tid & 7;
    float4 acc0[F4], acc1[F4];
    #pragma unroll
    for (int j = 0; j < F4; ++j) {
        acc0[j] = make_float4(0.f, 0.f, 0.f, 0.f);
        acc1[j] = make_float4(0.f, 0.f, 0.f, 0.f);
    }

    for (int kc = 0; kc < 4; ++kc) {
        for (int i = tid; i < 32 * C / 4; i += 256) {
            *reinterpret_cast<float4*>(&Wl[i * 4]) =
                *reinterpret_cast<const float4*>(W + (size_t)kc * 32 * C + i * 4);
        }
        __syncthreads();
        #pragma unroll 4
        for (int kk = 0; kk < 32; ++kk) {
            float a0 = Al[r0 * AS + kc * 32 + kk];
            float a1 = Al[(r0 + 32) * AS + kc * 32 + kk];
            const float* wr = &Wl[kk * C + g * 4];
            #pragma unroll
            for (int j = 0; j < F4; ++j) {
                float4 w = *reinterpret_cast<const float4*>(wr + 32 * j);
                acc0[j].x = fmaf(a0, w.x, acc0[j].x);
                acc0[j].y = fmaf(a0, w.y, acc0[j].y);
                acc0[j].z = fmaf(a0, w.z, acc0[j].z);
                acc0[j].w = fmaf(a0, w.w, acc0[j].w);
                acc1[j].x = fmaf(a1, w.x, acc1[j].x);
                acc1[j].y = fmaf(a1, w.y, acc1[j].y);
                acc1[j].z = fmaf(a1, w.z, acc1[j].z);
                acc1[j].w = fmaf(a1, w.w, acc1[j].w);
            }
        }
        __syncthreads();
    }

    #pragma unroll
    for (int half = 0; half < 2; ++half) {
        const int gr = brow + r0 + half * 32;
        float4* acc = half ? acc1 : acc0;
        if (gr < n) {
            float pel[H], per_[H];
            #pragma unroll
            for (int h = 0; h < H; ++h) { pel[h] = 0.f; per_[h] = 0.f; }
            #pragma unroll
            for (int j = 0; j < F4; ++j) {
                int cbase = g * 4 + 32 * j;
                *reinterpret_cast<float4*>(feat + (size_t)gr * C + cbase) = acc[j];
                float av[4] = {acc[j].x, acc[j].y, acc[j].z, acc[j].w};
                #pragma unroll
                for (int u = 0; u < 4; ++u) {
                    int col = cbase + u;
                    int head = (H == 2) ? (col >> 6) : 0;
                    int lc = col & 63;
                    pel[head] += av[u] * al[head * 64 + lc];
                    per_[head] += av[u] * ar[head * 64 + lc];
                }
            }
            #pragma unroll
            for (int off = 1; off < 8; off <<= 1) {
                #pragma unroll
                for (int h = 0; h < H; ++h) {
                    pel[h] += __shfl_xor(pel[h], off, 64);
                    per_[h] += __shfl_xor(per_[h], off, 64);
                }
            }
            if (g == 0) {
                #pragma unroll
                for (int h = 0; h < H; ++h) {
                    el[(size_t)gr * H + h] = pel[h];
                    er[(size_t)gr * H + h] = per_[h];
                }
            }
        }
    }
}

// ---------------- CSR build (by dst), once per launch ----------------
__global__ void hist_dst(const int* __restrict__ dst, int* __restrict__ cnt, int E)
{
    int e = blockIdx.x * blockDim.x + threadIdx.x;
    if (e < E) atomicAdd(&cnt[dst[e]], 1);
}

__global__ void scan_block_sums(const int* __restrict__ cnt, int* __restrict__ bsum, int n)
{
    __shared__ int sh[256];
    int i = blockIdx.x * 256 + threadIdx.x;
    sh[threadIdx.x] = (i < n) ? cnt[i] : 0;
    __syncthreads();
    for (int off = 128; off; off >>= 1) {
        if (threadIdx.x < off) sh[threadIdx.x] += sh[threadIdx.x + off];
        __syncthreads();
    }
    if (threadIdx.x == 0) bsum[blockIdx.x] = sh[0];
}

__global__ void scan_bsum(int* __restrict__ bsum, int nb)
{
    __shared__ int sh[256];
    int t = threadIdx.x;
    sh[t] = (t < nb) ? bsum[t] : 0;
    __syncthreads();
    for (int off = 1; off < 256; off <<= 1) {
        int u = (t >= off) ? sh[t - off] : 0;
        __syncthreads();
        sh[t] += u;
        __syncthreads();
    }
    if (t < nb) bsum[t] = t ? sh[t - 1] : 0;   // exclusive
}

__global__ void scan_final(const int* __restrict__ cnt, const int* __restrict__ bsum,
                           int* __restrict__ rs, int* __restrict__ cursor, int n)
{
    __shared__ int sh[256];
    int t = threadIdx.x;
    int i = blockIdx.x * 256 + t;
    int v = (i < n) ? cnt[i] : 0;
    sh[t] = v;
    __syncthreads();
    for (int off = 1; off < 256; off <<= 1) {
        int u = (t >= off) ? sh[t - off] : 0;
        __syncthreads();
        sh[t] += u;
        __syncthreads();
    }
    int excl = sh[t] - v + bsum[blockIdx.x];
    if (i < n) { rs[i] = excl; cursor[i] = excl; }
    if (i == n - 1) rs[n] = excl + v;
}

__global__ void scatter_csr(const int* __restrict__ src, const int* __restrict__ dst,
                            int* __restrict__ cursor, int* __restrict__ csr, int E)
{
    int e = blockIdx.x * blockDim.x + threadIdx.x;
    if (e < E) {
        int d = dst[e];
        int pos = atomicAdd(&cursor[d], 1);
        csr[pos] = src[e];
    }
}

// ---------------- fused GAT edge-softmax + aggregate: one wave per dst node ----------------
template <int C, int H>
__launch_bounds__(256)
__global__ void gat_agg(const int* __restrict__ rs, const int* __restrict__ csr,
                        const float* __restrict__ el, const float* __restrict__ er,
                        const float* __restrict__ feat, const float* __restrict__ bias,
                        float* __restrict__ outp, int n)
{
    int node = blockIdx.x * 4 + (threadIdx.x >> 6);
    if (node >= n) return;
    int lane = threadIdx.x & 63;
    int start = rs[node], end = rs[node + 1];

    float er0, er1;
    if constexpr (H == 2) {
        float2 e2 = *reinterpret_cast<const float2*>(er + (size_t)node * 2);
        er0 = e2.x; er1 = e2.y;
    } else {
        er0 = er[node]; er1 = 0.f;
    }

    float m0 = -INFINITY, s0 = 0.f, acc0 = 0.f;
    float m1 = -INFINITY, s1 = 0.f, acc1 = 0.f;

    for (int j = start; j < end; ++j) {
        int s = csr[j];
        if constexpr (H == 2) {
            float2 l2 = *reinterpret_cast<const float2*>(el + (size_t)s * 2);
            float e0 = l2.x + er0; e0 = e0 >= 0.f ? e0 : 0.2f * e0;
            float e1 = l2.y + er1; e1 = e1 >= 0.f ? e1 : 0.2f * e1;
            float f0 = feat[(size_t)s * C + lane];
            float f1 = feat[(size_t)s * C + 64 + lane];
            float mn0 = fmaxf(m0, e0);
            float c0 = __expf(m0 - mn0);
            float p0 = __expf(e0 - mn0);
            s0 = s0 * c0 + p0; acc0 = acc0 * c0 + p0 * f0; m0 = mn0;
            float mn1 = fmaxf(m1, e1);
            float c1 = __expf(m1 - mn1);
            float p1 = __expf(e1 - mn1);
            s1 = s1 * c1 + p1; acc1 = acc1 * c1 + p1 * f1; m1 = mn1;
        } else {
            float e0 = el[s] + er0; e0 = e0 >= 0.f ? e0 : 0.2f * e0;
            float f0 = feat[(size_t)s * C + lane];
            float mn0 = fmaxf(m0, e0);
            float c0 = __expf(m0 - mn0);
            float p0 = __expf(e0 - mn0);
            s0 = s0 * c0 + p0; acc0 = acc0 * c0 + p0 * f0; m0 = mn0;
        }
    }

    float o0 = acc0 / fmaxf(s0, 1e-9f);
    if (bias) o0 += bias[lane];
    outp[(size_t)node * C + lane] = o0;
    if constexpr (H == 2) {
        float o1 = acc1 / fmaxf(s1, 1e-9f);
        if (bias) o1 += bias[64 + lane];
        outp[(size_t)node * C + 64 + lane] = o1;
    }
}

// ---------------- BatchNorm stats (C=128) ----------------
__global__ void bn_stats(const float* __restrict__ h, float* __restrict__ sums, int n)
{
    __shared__ float s1[256], s2[256];
    int c = threadIdx.x & 127, half = threadIdx.x >> 7;
    float ls = 0.f, lq = 0.f;
    for (int r = blockIdx.x * 2 + half; r < n; r += gridDim.x * 2) {
        float v = h[(size_t)r * 128 + c];
        ls += v; lq += v * v;
    }
    s1[threadIdx.x] = ls; s2[threadIdx.x] = lq;
    __syncthreads();
    if (threadIdx.x < 128) {
        atomicAdd(&sums[c], s1[threadIdx.x] + s1[threadIdx.x + 128]);
        atomicAdd(&sums[128 + c], s2[threadIdx.x] + s2[threadIdx.x + 128]);
    }
}

__global__ void bn_apply(float* __restrict__ h, const float* __restrict__ sums,
                         const float* __restrict__ g, const float* __restrict__ b,
                         long long total)
{
    long long i = (long long)blockIdx.x * blockDim.x + threadIdx.x;
    if (i >= total) return;
    int c = (int)(i & 127);
    const float invN = 1.f / (float)N_NODES;
    float mean = sums[c] * invN;
    float var = sums[128 + c] * invN - mean * mean;
    float v = (h[i] - mean) * rsqrtf(var + 1e-5f) * g[c] + b[c];
    h[i] = fmaxf(v, 0.f);
}

// ---------------- predictor v2: tiled batched GEMM, 64 pairs per block ----------------
// zt/at are [channel][pair] padded (stride 68) so the k-loop reads are float4.
// Each thread computes a 4-pair x 4-channel register tile per layer.
__launch_bounds__(256, 2)
__global__ void predictor(const float* __restrict__ h,
                          const int* __restrict__ ps, const int* __restrict__ pd,
                          const int* __restrict__ ns, const int* __restrict__ nd,
                          const float* __restrict__ W1, const float* __restrict__ b1,
                          const float* __restrict__ W2, const float* __restrict__ b2,
                          const float* __restrict__ W3, const float* __restrict__ b3,
                          float* __restrict__ out, int P)
{
    __shared__ float w1[64 * 64];   // [k][c]
    __shared__ float w2[64 * 64];   // [k][c]
    __shared__ float zt[64 * 68];   // [c][p] padded
    __shared__ float at[64 * 68];   // [c][p] padded
    const int tid = threadIdx.x;

    for (int i = tid; i < 1024; i += 256) {
        *reinterpret_cast<float4*>(&w1[i * 4]) = *reinterpret_cast<const float4*>(W1 + i * 4);
        *reinterpret_cast<float4*>(&w2[i * 4]) = *reinterpret_cast<const float4*>(W2 + i * 4);
    }

    // phase 1: z[p][c] = h[s][c] * h[d][c], stored transposed into zt[c][p]
    {
        int p = tid >> 2, q = tid & 3;
        int gp = blockIdx.x * 64 + p;
        int s, d;
        if (gp < P) { s = ps[gp]; d = pd[gp]; }
        else        { s = ns[gp - P]; d = nd[gp - P]; }
        const float4* hs = reinterpret_cast<const float4*>(h + (size_t)s * 64 + q * 16);
        const float4* hd = reinterpret_cast<const float4*>(h + (size_t)d * 64 + q * 16);
        #pragma unroll
        for (int j = 0; j < 4; ++j) {
            float4 a = hs[j], b = hd[j];
            int c0 = q * 16 + j * 4;
            zt[(c0 + 0) * 68 + p] = a.x * b.x;
            zt[(c0 + 1) * 68 + p] = a.y * b.y;
            zt[(c0 + 2) * 68 + p] = a.z * b.z;
            zt[(c0 + 3) * 68 + p] = a.w * b.w;
        }
    }
    __syncthreads();

    const int pb = tid >> 4;      // 0..15 -> pairs pb*4..pb*4+3
    const int cb = tid & 15;      // 0..15 -> channels cb*4..cb*4+3
    const int p0 = pb * 4, c0 = cb * 4;
    float4 vb1 = *reinterpret_cast<const float4*>(b1 + c0);
    float4 vb2 = *reinterpret_cast<const float4*>(b2 + c0);
    float4 vw3 = *reinterpret_cast<const float4*>(W3 + c0);
    const float b3v = b3[0];

    float acc[4][4];

    // ---- layer 1: a1 = relu(z @ W1 + b1) ----
    #pragma unroll
    for (int i = 0; i < 4; ++i)
        #pragma unroll
        for (int j = 0; j < 4; ++j) acc[i][j] = 0.f;

    #pragma unroll 4
    for (int k = 0; k < 64; ++k) {
        float4 zv = *reinterpret_cast<const float4*>(&zt[k * 68 + p0]);
        float4 wv = *reinterpret_cast<const float4*>(&w1[k * 64 + c0]);
        float zz[4] = {zv.x, zv.y, zv.z, zv.w};
        float ww[4] = {wv.x, wv.y, wv.z, wv.w};
        #pragma unroll
        for (int i = 0; i < 4; ++i)
            #pragma unroll
            for (int j = 0; j < 4; ++j)
                acc[i][j] = fmaf(zz[i], ww[j], acc[i][j]);
    }
    {
        float bb[4] = {vb1.x, vb1.y, vb1.z, vb1.w};
        #pragma unroll
        for (int i = 0; i < 4; ++i)
            #pragma unroll
            for (int j = 0; j < 4; ++j)
                at[(c0 + j) * 68 + p0 + i] = fmaxf(acc[i][j] + bb[j], 0.f);
    }
    __syncthreads();

    // ---- layer 2: a2 = relu(a1 @ W2 + b2); out = a2 @ w3 + b3 ----
    #pragma unroll
    for (int i = 0; i < 4; ++i)
        #pragma unroll
        for (int j = 0; j < 4; ++j) acc[i][j] = 0.f;

    #pragma unroll 4
    for (int k = 0; k < 64; ++k) {
        float4 zv = *reinterpret_cast<const float4*>(&at[k * 68 + p0]);
        float4 wv = *reinterpret_cast<const float4*>(&w2[k * 64 + c0]);
        float zz[4] = {zv.x, zv.y, zv.z, zv.w};
        float ww[4] = {wv.x, wv.y, wv.z, wv.w};
        #pragma unroll
        for (int i = 0; i < 4; ++i)
            #pragma unroll
            for (int j = 0; j < 4; ++j)
                acc[i][j] = fmaf(zz[i], ww[j], acc[i][j]);
    }

    float part[4];
    {
        float bb[4] = {vb2.x, vb2.y, vb2.z, vb2.w};
        float w3v[4] = {vw3.x, vw3.y, vw3.z, vw3.w};
        #pragma unroll
        for (int i = 0; i < 4; ++i) {
            float su = 0.f;
            #pragma unroll
            for (int j = 0; j < 4; ++j)
                su += fmaxf(acc[i][j] + bb[j], 0.f) * w3v[j];
            part[i] = su;
        }
    }
    // reduce over the 16 lanes sharing this pair block (same pb, cb=0..15)
    #pragma unroll
    for (int off = 1; off < 16; off <<= 1) {
        #pragma unroll
        for (int i = 0; i < 4; ++i)
            part[i] += __shfl_xor(part[i], off, 16);
    }
    if (cb == 0) {
        int gp0 = blockIdx.x * 64 + p0;
        #pragma unroll
        for (int i = 0; i < 4; ++i)
            out[gp0 + i] = part[i] + b3v;
    }
}

extern "C" void kernel_launch(void* const* d_in, const int* in_sizes, int n_in,
                              void* d_out, int out_size, void* d_ws, size_t ws_size,
                              hipStream_t stream)
{
    const float* x    = (const float*)d_in[0];
    const int* es     = (const int*)d_in[1];
    const int* ed     = (const int*)d_in[2];
    const int* ps     = (const int*)d_in[3];
    const int* pdst   = (const int*)d_in[4];
    const int* ns     = (const int*)d_in[5];
    const int* nd     = (const int*)d_in[6];
    const float* W0   = (const float*)d_in[7];
    const float* al0  = (const float*)d_in[8];
    const float* ar0  = (const float*)d_in[9];
    const float* W1   = (const float*)d_in[11];
    const float* al1  = (const float*)d_in[12];
    const float* ar1  = (const float*)d_in[13];
    const float* W2   = (const float*)d_in[15];
    const float* al2  = (const float*)d_in[16];
    const float* ar2  = (const float*)d_in[17];
    const float* b2   = (const float*)d_in[18];
    const float* bn0g = (const float*)d_in[19];
    const float* bn0b = (const float*)d_in[20];
    const float* bn1g = (const float*)d_in[21];
    const float* bn1b = (const float*)d_in[22];
    const float* pW1  = (const float*)d_in[23];
    const float* pb1  = (const float*)d_in[24];
    const float* pW2  = (const float*)d_in[25];
    const float* pb2  = (const float*)d_in[26];
    const float* pW3  = (const float*)d_in[27];
    const float* pb3  = (const float*)d_in[28];
    float* out = (float*)d_out;

    float* ws = (float*)d_ws;
    size_t off = 0;
    auto alloc = [&](size_t nelem) {
        float* p = ws + off;
        off += (nelem + 63) & ~(size_t)63;
        return p;
    };
    float* featb = alloc((size_t)N_NODES * 128);
    float* hb    = alloc((size_t)N_NODES * 128);
    float* el    = alloc((size_t)N_NODES * 2);
    float* er    = alloc((size_t)N_NODES * 2);
    float* bns   = alloc(256);
    int* cnt     = (int*)alloc(N_NODES);
    int* rs      = (int*)alloc(N_NODES + 1);
    int* cursor  = (int*)alloc(N_NODES);
    int* bsum    = (int*)alloc(256);
    int* csr     = (int*)alloc(N_EDGES);

    dim3 blk(256);
    const int gemmGrid = (N_NODES + 63) / 64;
    const int edgeGrid = (N_EDGES + 255) / 256;
    const int nodeBlocks = (N_NODES + 255) / 256;
    const int aggGrid = (N_NODES + 3) / 4;

    // ================= CSR build (once; graph shared by all layers) =================
    hipMemsetAsync(cnt, 0, (size_t)N_NODES * sizeof(int), stream);
    hist_dst<<<edgeGrid, blk, 0, stream>>>(ed, cnt, N_EDGES);
    scan_block_sums<<<nodeBlocks, blk, 0, stream>>>(cnt, bsum, N_NODES);
    scan_bsum<<<1, blk, 0, stream>>>(bsum, nodeBlocks);
    scan_final<<<nodeBlocks, blk, 0, stream>>>(cnt, bsum, rs, cursor, N_NODES);
    scatter_csr<<<edgeGrid, blk, 0, stream>>>(es, ed, cursor, csr, N_EDGES);

    // ================= layer 0 (C=128, H=2) =================
    gemm_feat<128, 2><<<gemmGrid, blk, 0, stream>>>(x, W0, al0, ar0, featb, el, er, N_NODES);
    gat_agg<128, 2><<<aggGrid, blk, 0, stream>>>(rs, csr, el, er, featb, nullptr, hb, N_NODES);
    hipMemsetAsync(bns, 0, 256 * sizeof(float), stream);
    bn_stats<<<256, blk, 0, stream>>>(hb, bns, N_NODES);
    bn_apply<<<(N_NODES * 128 + 255) / 256, blk, 0, stream>>>(hb, bns, bn0g, bn0b,
                                                              (long long)N_NODES * 128);

    // ================= layer 1 (C=128, H=2) =================
    gemm_feat<128, 2><<<gemmGrid, blk, 0, stream>>>(hb, W1, al1, ar1, featb, el, er, N_NODES);
    gat_agg<128, 2><<<aggGrid, blk, 0, stream>>>(rs, csr, el, er, featb, nullptr, hb, N_NODES);
    hipMemsetAsync(bns, 0, 256 * sizeof(float), stream);
    bn_stats<<<256, blk, 0, stream>>>(hb, bns, N_NODES);
    bn_apply<<<(N_NODES * 128 + 255) / 256, blk, 0, stream>>>(hb, bns, bn1g, bn1b,
                                                              (long long)N_NODES * 128);

    // ================= layer 2 (C=64, H=1) =================
    gemm_feat<64, 1><<<gemmGrid, blk, 0, stream>>>(hb, W2, al2, ar2, featb, el, er, N_NODES);
    gat_agg<64, 1><<<aggGrid, blk, 0, stream>>>(rs, csr, el, er, featb, b2, hb, N_NODES);

    // ================= predictor (200000 pairs / 64 per block = 3125 blocks) =================
    predictor<<<3125, blk, 0, stream>>>(hb, ps, pdst, ns, nd,
                                        pW1, pb1, pW2, pb2, pW3, pb3, out, 100000);
}

// Round 5
// 622.215 us; speedup vs baseline: 8.1132x; 1.1799x over previous
//
#include <hip/hip_runtime.h>
#include <cstdint>
#include <cstddef>

#define N_NODES 50000
#define N_EDGES 800000

// ---------------- GEMM (n x 128) @ (128 x C) + fused attn-dot epilogue ----------------
template <int C, int H>
__launch_bounds__(256, 2)
__global__ void gemm_feat(const float* __restrict__ A, const float* __restrict__ W,
                          const float* __restrict__ al, const float* __restrict__ ar,
                          float* __restrict__ feat, float* __restrict__ el,
                          float* __restrict__ er, int n)
{
    constexpr int K = 128;
    constexpr int BM = 64;
    constexpr int AS = K + 4;
    constexpr int F4 = C / 32;
    __shared__ float Al[BM * AS];
    __shared__ float Wl[32 * C];

    const int tid = threadIdx.x;
    const int brow = blockIdx.x * BM;

    for (int i = tid; i < BM * K / 4; i += 256) {
        int f = i * 4;
        int r = f >> 7;
        int c = f & 127;
        float4 v = make_float4(0.f, 0.f, 0.f, 0.f);
        int gr = brow + r;
        if (gr < n) v = *reinterpret_cast<const float4*>(A + (size_t)gr * K + c);
        *reinterpret_cast<float4*>(&Al[r * AS + c]) = v;
    }

    const int r0 = tid >> 3;
    const int g = tid & 7;
    float4 acc0[F4], acc1[F4];
    #pragma unroll
    for (int j = 0; j < F4; ++j) {
        acc0[j] = make_float4(0.f, 0.f, 0.f, 0.f);
        acc1[j] = make_float4(0.f, 0.f, 0.f, 0.f);
    }

    for (int kc = 0; kc < 4; ++kc) {
        for (int i = tid; i < 32 * C / 4; i += 256) {
            *reinterpret_cast<float4*>(&Wl[i * 4]) =
                *reinterpret_cast<const float4*>(W + (size_t)kc * 32 * C + i * 4);
        }
        __syncthreads();
        #pragma unroll 4
        for (int kk = 0; kk < 32; ++kk) {
            float a0 = Al[r0 * AS + kc * 32 + kk];
            float a1 = Al[(r0 + 32) * AS + kc * 32 + kk];
            const float* wr = &Wl[kk * C + g * 4];
            #pragma unroll
            for (int j = 0; j < F4; ++j) {
                float4 w = *reinterpret_cast<const float4*>(wr + 32 * j);
                acc0[j].x = fmaf(a0, w.x, acc0[j].x);
                acc0[j].y = fmaf(a0, w.y, acc0[j].y);
                acc0[j].z = fmaf(a0, w.z, acc0[j].z);
                acc0[j].w = fmaf(a0, w.w, acc0[j].w);
                acc1[j].x = fmaf(a1, w.x, acc1[j].x);
                acc1[j].y = fmaf(a1, w.y, acc1[j].y);
                acc1[j].z = fmaf(a1, w.z, acc1[j].z);
                acc1[j].w = fmaf(a1, w.w, acc1[j].w);
            }
        }
        __syncthreads();
    }

    #pragma unroll
    for (int half = 0; half < 2; ++half) {
        const int gr = brow + r0 + half * 32;
        float4* acc = half ? acc1 : acc0;
        if (gr < n) {
            float pel[H], per_[H];
            #pragma unroll
            for (int h = 0; h < H; ++h) { pel[h] = 0.f; per_[h] = 0.f; }
            #pragma unroll
            for (int j = 0; j < F4; ++j) {
                int cbase = g * 4 + 32 * j;
                *reinterpret_cast<float4*>(feat + (size_t)gr * C + cbase) = acc[j];
                float av[4] = {acc[j].x, acc[j].y, acc[j].z, acc[j].w};
                #pragma unroll
                for (int u = 0; u < 4; ++u) {
                    int col = cbase + u;
                    int head = (H == 2) ? (col >> 6) : 0;
                    int lc = col & 63;
                    pel[head] += av[u] * al[head * 64 + lc];
                    per_[head] += av[u] * ar[head * 64 + lc];
                }
            }
            #pragma unroll
            for (int off = 1; off < 8; off <<= 1) {
                #pragma unroll
                for (int h = 0; h < H; ++h) {
                    pel[h] += __shfl_xor(pel[h], off, 64);
                    per_[h] += __shfl_xor(per_[h], off, 64);
                }
            }
            if (g == 0) {
                #pragma unroll
                for (int h = 0; h < H; ++h) {
                    el[(size_t)gr * H + h] = pel[h];
                    er[(size_t)gr * H + h] = per_[h];
                }
            }
        }
    }
}

// ---------------- CSR build (by dst), once per launch ----------------
__global__ void hist_dst(const int* __restrict__ dst, int* __restrict__ cnt, int E)
{
    int e = blockIdx.x * blockDim.x + threadIdx.x;
    if (e < E) atomicAdd(&cnt[dst[e]], 1);
}

__global__ void scan_block_sums(const int* __restrict__ cnt, int* __restrict__ bsum, int n)
{
    __shared__ int sh[256];
    int i = blockIdx.x * 256 + threadIdx.x;
    sh[threadIdx.x] = (i < n) ? cnt[i] : 0;
    __syncthreads();
    for (int off = 128; off; off >>= 1) {
        if (threadIdx.x < off) sh[threadIdx.x] += sh[threadIdx.x + off];
        __syncthreads();
    }
    if (threadIdx.x == 0) bsum[blockIdx.x] = sh[0];
}

__global__ void scan_bsum(int* __restrict__ bsum, int nb)
{
    __shared__ int sh[256];
    int t = threadIdx.x;
    sh[t] = (t < nb) ? bsum[t] : 0;
    __syncthreads();
    for (int off = 1; off < 256; off <<= 1) {
        int u = (t >= off) ? sh[t - off] : 0;
        __syncthreads();
        sh[t] += u;
        __syncthreads();
    }
    if (t < nb) bsum[t] = t ? sh[t - 1] : 0;   // exclusive
}

__global__ void scan_final(const int* __restrict__ cnt, const int* __restrict__ bsum,
                           int* __restrict__ rs, int* __restrict__ cursor, int n)
{
    __shared__ int sh[256];
    int t = threadIdx.x;
    int i = blockIdx.x * 256 + t;
    int v = (i < n) ? cnt[i] : 0;
    sh[t] = v;
    __syncthreads();
    for (int off = 1; off < 256; off <<= 1) {
        int u = (t >= off) ? sh[t - off] : 0;
        __syncthreads();
        sh[t] += u;
        __syncthreads();
    }
    int excl = sh[t] - v + bsum[blockIdx.x];
    if (i < n) { rs[i] = excl; cursor[i] = excl; }
    if (i == n - 1) rs[n] = excl + v;
}

__global__ void scatter_csr(const int* __restrict__ src, const int* __restrict__ dst,
                            int* __restrict__ cursor, int* __restrict__ csr, int E)
{
    int e = blockIdx.x * blockDim.x + threadIdx.x;
    if (e < E) {
        int d = dst[e];
        int pos = atomicAdd(&cursor[d], 1);
        csr[pos] = src[e];
    }
}

// ---------------- fused GAT edge-softmax + aggregate v2 ----------------
// Pass A: lane-parallel segment max (csr+el only, L2-resident).
// Pass B: exact softmax accumulate; lane owns 4 channels (float4 feat loads);
//         wave processes 2 edges (C=128) or 4 edges (C=64) concurrently.
template <int C, int H>
__launch_bounds__(256)
__global__ void gat_agg(const int* __restrict__ rs, const int* __restrict__ csr,
                        const float* __restrict__ el, const float* __restrict__ er,
                        const float* __restrict__ feat, const float* __restrict__ bias,
                        float* __restrict__ outp, int n)
{
    int node = blockIdx.x * 4 + (threadIdx.x >> 6);
    if (node >= n) return;
    int lane = threadIdx.x & 63;
    int start = rs[node], end = rs[node + 1];

    if constexpr (H == 2) {
        float2 e2 = *reinterpret_cast<const float2*>(er + (size_t)node * 2);
        // ---- pass A: per-head max, lane-parallel ----
        float m0 = -INFINITY, m1 = -INFINITY;
        for (int j = start + lane; j < end; j += 64) {
            int s = csr[j];
            float2 l2 = *reinterpret_cast<const float2*>(el + (size_t)s * 2);
            float v0 = l2.x + e2.x; v0 = v0 >= 0.f ? v0 : 0.2f * v0;
            float v1 = l2.y + e2.y; v1 = v1 >= 0.f ? v1 : 0.2f * v1;
            m0 = fmaxf(m0, v0); m1 = fmaxf(m1, v1);
        }
        #pragma unroll
        for (int off = 32; off; off >>= 1) {
            m0 = fmaxf(m0, __shfl_xor(m0, off, 64));
            m1 = fmaxf(m1, __shfl_xor(m1, off, 64));
        }
        // ---- pass B: 2 edges in flight; lane owns channels 4*cl..4*cl+3 ----
        const int half = lane >> 5;     // edge slot 0/1
        const int cl = lane & 31;       // channel group
        const int h = cl >> 4;          // head of my channels
        const float mh = h ? m1 : m0;
        const float erh = h ? e2.y : e2.x;
        float ssum = 0.f;
        float4 acc = make_float4(0.f, 0.f, 0.f, 0.f);
        for (int j = start + half; j < end; j += 2) {
            int s = csr[j];
            float v = el[(size_t)s * 2 + h] + erh;
            v = v >= 0.f ? v : 0.2f * v;
            float p = __expf(v - mh);
            float4 f = *reinterpret_cast<const float4*>(feat + (size_t)s * C + cl * 4);
            ssum += p;
            acc.x = fmaf(p, f.x, acc.x);
            acc.y = fmaf(p, f.y, acc.y);
            acc.z = fmaf(p, f.z, acc.z);
            acc.w = fmaf(p, f.w, acc.w);
        }
        ssum += __shfl_xor(ssum, 32, 64);
        acc.x += __shfl_xor(acc.x, 32, 64);
        acc.y += __shfl_xor(acc.y, 32, 64);
        acc.z += __shfl_xor(acc.z, 32, 64);
        acc.w += __shfl_xor(acc.w, 32, 64);
        if (half == 0) {
            float r = 1.f / fmaxf(ssum, 1e-9f);
            float4 o = make_float4(acc.x * r, acc.y * r, acc.z * r, acc.w * r);
            *reinterpret_cast<float4*>(outp + (size_t)node * C + cl * 4) = o;
        }
    } else {
        float er0 = er[node];
        // ---- pass A ----
        float m0 = -INFINITY;
        for (int j = start + lane; j < end; j += 64) {
            int s = csr[j];
            float v = el[s] + er0;
            v = v >= 0.f ? v : 0.2f * v;
            m0 = fmaxf(m0, v);
        }
        #pragma unroll
        for (int off = 32; off; off >>= 1)
            m0 = fmaxf(m0, __shfl_xor(m0, off, 64));
        // ---- pass B: 4 edges in flight; lane owns channels 4*cl..4*cl+3 ----
        const int q = lane >> 4;        // edge slot 0..3
        const int cl = lane & 15;       // channel group
        float ssum = 0.f;
        float4 acc = make_float4(0.f, 0.f, 0.f, 0.f);
        for (int j = start + q; j < end; j += 4) {
            int s = csr[j];
            float v = el[s] + er0;
            v = v >= 0.f ? v : 0.2f * v;
            float p = __expf(v - m0);
            float4 f = *reinterpret_cast<const float4*>(feat + (size_t)s * C + cl * 4);
            ssum += p;
            acc.x = fmaf(p, f.x, acc.x);
            acc.y = fmaf(p, f.y, acc.y);
            acc.z = fmaf(p, f.z, acc.z);
            acc.w = fmaf(p, f.w, acc.w);
        }
        #pragma unroll
        for (int off = 16; off <= 32; off <<= 1) {
            ssum += __shfl_xor(ssum, off, 64);
            acc.x += __shfl_xor(acc.x, off, 64);
            acc.y += __shfl_xor(acc.y, off, 64);
            acc.z += __shfl_xor(acc.z, off, 64);
            acc.w += __shfl_xor(acc.w, off, 64);
        }
        if (q == 0) {
            float r = 1.f / fmaxf(ssum, 1e-9f);
            float4 o;
            o.x = acc.x * r + bias[cl * 4 + 0];
            o.y = acc.y * r + bias[cl * 4 + 1];
            o.z = acc.z * r + bias[cl * 4 + 2];
            o.w = acc.w * r + bias[cl * 4 + 3];
            *reinterpret_cast<float4*>(outp + (size_t)node * C + cl * 4) = o;
        }
    }
}

// ---------------- BatchNorm stats (C=128) ----------------
__global__ void bn_stats(const float* __restrict__ h, float* __restrict__ sums, int n)
{
    __shared__ float s1[256], s2[256];
    int c = threadIdx.x & 127, half = threadIdx.x >> 7;
    float ls = 0.f, lq = 0.f;
    for (int r = blockIdx.x * 2 + half; r < n; r += gridDim.x * 2) {
        float v = h[(size_t)r * 128 + c];
        ls += v; lq += v * v;
    }
    s1[threadIdx.x] = ls; s2[threadIdx.x] = lq;
    __syncthreads();
    if (threadIdx.x < 128) {
        atomicAdd(&sums[c], s1[threadIdx.x] + s1[threadIdx.x + 128]);
        atomicAdd(&sums[128 + c], s2[threadIdx.x] + s2[threadIdx.x + 128]);
    }
}

__global__ void bn_apply(float* __restrict__ h, const float* __restrict__ sums,
                         const float* __restrict__ g, const float* __restrict__ b,
                         long long total)
{
    long long i = (long long)blockIdx.x * blockDim.x + threadIdx.x;
    if (i >= total) return;
    int c = (int)(i & 127);
    const float invN = 1.f / (float)N_NODES;
    float mean = sums[c] * invN;
    float var = sums[128 + c] * invN - mean * mean;
    float v = (h[i] - mean) * rsqrtf(var + 1e-5f) * g[c] + b[c];
    h[i] = fmaxf(v, 0.f);
}

// ---------------- predictor: tiled batched GEMM, 64 pairs per block ----------------
__launch_bounds__(256, 2)
__global__ void predictor(const float* __restrict__ h,
                          const int* __restrict__ ps, const int* __restrict__ pd,
                          const int* __restrict__ ns, const int* __restrict__ nd,
                          const float* __restrict__ W1, const float* __restrict__ b1,
                          const float* __restrict__ W2, const float* __restrict__ b2,
                          const float* __restrict__ W3, const float* __restrict__ b3,
                          float* __restrict__ out, int P)
{
    __shared__ float w1[64 * 64];   // [k][c]
    __shared__ float w2[64 * 64];   // [k][c]
    __shared__ float zt[64 * 68];   // [c][p] padded
    __shared__ float at[64 * 68];   // [c][p] padded
    const int tid = threadIdx.x;

    for (int i = tid; i < 1024; i += 256) {
        *reinterpret_cast<float4*>(&w1[i * 4]) = *reinterpret_cast<const float4*>(W1 + i * 4);
        *reinterpret_cast<float4*>(&w2[i * 4]) = *reinterpret_cast<const float4*>(W2 + i * 4);
    }

    {
        int p = tid >> 2, q = tid & 3;
        int gp = blockIdx.x * 64 + p;
        int s, d;
        if (gp < P) { s = ps[gp]; d = pd[gp]; }
        else        { s = ns[gp - P]; d = nd[gp - P]; }
        const float4* hs = reinterpret_cast<const float4*>(h + (size_t)s * 64 + q * 16);
        const float4* hd = reinterpret_cast<const float4*>(h + (size_t)d * 64 + q * 16);
        #pragma unroll
        for (int j = 0; j < 4; ++j) {
            float4 a = hs[j], b = hd[j];
            int c0 = q * 16 + j * 4;
            zt[(c0 + 0) * 68 + p] = a.x * b.x;
            zt[(c0 + 1) * 68 + p] = a.y * b.y;
            zt[(c0 + 2) * 68 + p] = a.z * b.z;
            zt[(c0 + 3) * 68 + p] = a.w * b.w;
        }
    }
    __syncthreads();

    const int pb = tid >> 4;
    const int cb = tid & 15;
    const int p0 = pb * 4, c0 = cb * 4;
    float4 vb1 = *reinterpret_cast<const float4*>(b1 + c0);
    float4 vb2 = *reinterpret_cast<const float4*>(b2 + c0);
    float4 vw3 = *reinterpret_cast<const float4*>(W3 + c0);
    const float b3v = b3[0];

    float acc[4][4];

    #pragma unroll
    for (int i = 0; i < 4; ++i)
        #pragma unroll
        for (int j = 0; j < 4; ++j) acc[i][j] = 0.f;

    #pragma unroll 4
    for (int k = 0; k < 64; ++k) {
        float4 zv = *reinterpret_cast<const float4*>(&zt[k * 68 + p0]);
        float4 wv = *reinterpret_cast<const float4*>(&w1[k * 64 + c0]);
        float zz[4] = {zv.x, zv.y, zv.z, zv.w};
        float ww[4] = {wv.x, wv.y, wv.z, wv.w};
        #pragma unroll
        for (int i = 0; i < 4; ++i)
            #pragma unroll
            for (int j = 0; j < 4; ++j)
                acc[i][j] = fmaf(zz[i], ww[j], acc[i][j]);
    }
    {
        float bb[4] = {vb1.x, vb1.y, vb1.z, vb1.w};
        #pragma unroll
        for (int i = 0; i < 4; ++i)
            #pragma unroll
            for (int j = 0; j < 4; ++j)
                at[(c0 + j) * 68 + p0 + i] = fmaxf(acc[i][j] + bb[j], 0.f);
    }
    __syncthreads();

    #pragma unroll
    for (int i = 0; i < 4; ++i)
        #pragma unroll
        for (int j = 0; j < 4; ++j) acc[i][j] = 0.f;

    #pragma unroll 4
    for (int k = 0; k < 64; ++k) {
        float4 zv = *reinterpret_cast<const float4*>(&at[k * 68 + p0]);
        float4 wv = *reinterpret_cast<const float4*>(&w2[k * 64 + c0]);
        float zz[4] = {zv.x, zv.y, zv.z, zv.w};
        float ww[4] = {wv.x, wv.y, wv.z, wv.w};
        #pragma unroll
        for (int i = 0; i < 4; ++i)
            #pragma unroll
            for (int j = 0; j < 4; ++j)
                acc[i][j] = fmaf(zz[i], ww[j], acc[i][j]);
    }

    float part[4];
    {
        float bb[4] = {vb2.x, vb2.y, vb2.z, vb2.w};
        float w3v[4] = {vw3.x, vw3.y, vw3.z, vw3.w};
        #pragma unroll
        for (int i = 0; i < 4; ++i) {
            float su = 0.f;
            #pragma unroll
            for (int j = 0; j < 4; ++j)
                su += fmaxf(acc[i][j] + bb[j], 0.f) * w3v[j];
            part[i] = su;
        }
    }
    #pragma unroll
    for (int off = 1; off < 16; off <<= 1) {
        #pragma unroll
        for (int i = 0; i < 4; ++i)
            part[i] += __shfl_xor(part[i], off, 16);
    }
    if (cb == 0) {
        int gp0 = blockIdx.x * 64 + p0;
        #pragma unroll
        for (int i = 0; i < 4; ++i)
            out[gp0 + i] = part[i] + b3v;
    }
}

extern "C" void kernel_launch(void* const* d_in, const int* in_sizes, int n_in,
                              void* d_out, int out_size, void* d_ws, size_t ws_size,
                              hipStream_t stream)
{
    const float* x    = (const float*)d_in[0];
    const int* es     = (const int*)d_in[1];
    const int* ed     = (const int*)d_in[2];
    const int* ps     = (const int*)d_in[3];
    const int* pdst   = (const int*)d_in[4];
    const int* ns     = (const int*)d_in[5];
    const int* nd     = (const int*)d_in[6];
    const float* W0   = (const float*)d_in[7];
    const float* al0  = (const float*)d_in[8];
    const float* ar0  = (const float*)d_in[9];
    const float* W1   = (const float*)d_in[11];
    const float* al1  = (const float*)d_in[12];
    const float* ar1  = (const float*)d_in[13];
    const float* W2   = (const float*)d_in[15];
    const float* al2  = (const float*)d_in[16];
    const float* ar2  = (const float*)d_in[17];
    const float* b2   = (const float*)d_in[18];
    const float* bn0g = (const float*)d_in[19];
    const float* bn0b = (const float*)d_in[20];
    const float* bn1g = (const float*)d_in[21];
    const float* bn1b = (const float*)d_in[22];
    const float* pW1  = (const float*)d_in[23];
    const float* pb1  = (const float*)d_in[24];
    const float* pW2  = (const float*)d_in[25];
    const float* pb2  = (const float*)d_in[26];
    const float* pW3  = (const float*)d_in[27];
    const float* pb3  = (const float*)d_in[28];
    float* out = (float*)d_out;

    float* ws = (float*)d_ws;
    size_t off = 0;
    auto alloc = [&](size_t nelem) {
        float* p = ws + off;
        off += (nelem + 63) & ~(size_t)63;
        return p;
    };
    float* featb = alloc((size_t)N_NODES * 128);
    float* hb    = alloc((size_t)N_NODES * 128);
    float* el    = alloc((size_t)N_NODES * 2);
    float* er    = alloc((size_t)N_NODES * 2);
    float* bns   = alloc(256);
    int* cnt     = (int*)alloc(N_NODES);
    int* rs      = (int*)alloc(N_NODES + 1);
    int* cursor  = (int*)alloc(N_NODES);
    int* bsum    = (int*)alloc(256);
    int* csr     = (int*)alloc(N_EDGES);

    dim3 blk(256);
    const int gemmGrid = (N_NODES + 63) / 64;
    const int edgeGrid = (N_EDGES + 255) / 256;
    const int nodeBlocks = (N_NODES + 255) / 256;
    const int aggGrid = (N_NODES + 3) / 4;

    // ================= CSR build (once; graph shared by all layers) =================
    hipMemsetAsync(cnt, 0, (size_t)N_NODES * sizeof(int), stream);
    hist_dst<<<edgeGrid, blk, 0, stream>>>(ed, cnt, N_EDGES);
    scan_block_sums<<<nodeBlocks, blk, 0, stream>>>(cnt, bsum, N_NODES);
    scan_bsum<<<1, blk, 0, stream>>>(bsum, nodeBlocks);
    scan_final<<<nodeBlocks, blk, 0, stream>>>(cnt, bsum, rs, cursor, N_NODES);
    scatter_csr<<<edgeGrid, blk, 0, stream>>>(es, ed, cursor, csr, N_EDGES);

    // ================= layer 0 (C=128, H=2) =================
    gemm_feat<128, 2><<<gemmGrid, blk, 0, stream>>>(x, W0, al0, ar0, featb, el, er, N_NODES);
    gat_agg<128, 2><<<aggGrid, blk, 0, stream>>>(rs, csr, el, er, featb, nullptr, hb, N_NODES);
    hipMemsetAsync(bns, 0, 256 * sizeof(float), stream);
    bn_stats<<<256, blk, 0, stream>>>(hb, bns, N_NODES);
    bn_apply<<<(N_NODES * 128 + 255) / 256, blk, 0, stream>>>(hb, bns, bn0g, bn0b,
                                                              (long long)N_NODES * 128);

    // ================= layer 1 (C=128, H=2) =================
    gemm_feat<128, 2><<<gemmGrid, blk, 0, stream>>>(hb, W1, al1, ar1, featb, el, er, N_NODES);
    gat_agg<128, 2><<<aggGrid, blk, 0, stream>>>(rs, csr, el, er, featb, nullptr, hb, N_NODES);
    hipMemsetAsync(bns, 0, 256 * sizeof(float), stream);
    bn_stats<<<256, blk, 0, stream>>>(hb, bns, N_NODES);
    bn_apply<<<(N_NODES * 128 + 255) / 256, blk, 0, stream>>>(hb, bns, bn1g, bn1b,
                                                              (long long)N_NODES * 128);

    // ================= layer 2 (C=64, H=1) =================
    gemm_feat<64, 1><<<gemmGrid, blk, 0, stream>>>(hb, W2, al2, ar2, featb, el, er, N_NODES);
    gat_agg<64, 1><<<aggGrid, blk, 0, stream>>>(rs, csr, el, er, featb, b2, hb, N_NODES);

    // ================= predictor =================
    predictor<<<3125, blk, 0, stream>>>(hb, ps, pdst, ns, nd,
                                        pW1, pb1, pW2, pb2, pW3, pb3, out, 100000);
}

// Round 6
// 569.462 us; speedup vs baseline: 8.8648x; 1.0926x over previous
//
#include <hip/hip_runtime.h>
#include <hip/hip_fp16.h>
#include <cstdint>
#include <cstddef>

#define N_NODES 50000
#define N_EDGES 800000

// ---------------- GEMM (n x 128) @ (128 x C) + fused attn-dot epilogue ----------------
// feat output stored fp16 (halves gather traffic in gat_agg); el/er computed f32.
template <int C, int H>
__launch_bounds__(256, 2)
__global__ void gemm_feat(const float* __restrict__ A, const float* __restrict__ W,
                          const float* __restrict__ al, const float* __restrict__ ar,
                          __half* __restrict__ feat, float* __restrict__ el,
                          float* __restrict__ er, int n)
{
    constexpr int K = 128;
    constexpr int BM = 64;
    constexpr int AS = K + 4;
    constexpr int F4 = C / 32;
    __shared__ float Al[BM * AS];
    __shared__ float Wl[32 * C];

    const int tid = threadIdx.x;
    const int brow = blockIdx.x * BM;

    for (int i = tid; i < BM * K / 4; i += 256) {
        int f = i * 4;
        int r = f >> 7;
        int c = f & 127;
        float4 v = make_float4(0.f, 0.f, 0.f, 0.f);
        int gr = brow + r;
        if (gr < n) v = *reinterpret_cast<const float4*>(A + (size_t)gr * K + c);
        *reinterpret_cast<float4*>(&Al[r * AS + c]) = v;
    }

    const int r0 = tid >> 3;
    const int g = tid & 7;
    float4 acc0[F4], acc1[F4];
    #pragma unroll
    for (int j = 0; j < F4; ++j) {
        acc0[j] = make_float4(0.f, 0.f, 0.f, 0.f);
        acc1[j] = make_float4(0.f, 0.f, 0.f, 0.f);
    }

    for (int kc = 0; kc < 4; ++kc) {
        for (int i = tid; i < 32 * C / 4; i += 256) {
            *reinterpret_cast<float4*>(&Wl[i * 4]) =
                *reinterpret_cast<const float4*>(W + (size_t)kc * 32 * C + i * 4);
        }
        __syncthreads();
        #pragma unroll 4
        for (int kk = 0; kk < 32; ++kk) {
            float a0 = Al[r0 * AS + kc * 32 + kk];
            float a1 = Al[(r0 + 32) * AS + kc * 32 + kk];
            const float* wr = &Wl[kk * C + g * 4];
            #pragma unroll
            for (int j = 0; j < F4; ++j) {
                float4 w = *reinterpret_cast<const float4*>(wr + 32 * j);
                acc0[j].x = fmaf(a0, w.x, acc0[j].x);
                acc0[j].y = fmaf(a0, w.y, acc0[j].y);
                acc0[j].z = fmaf(a0, w.z, acc0[j].z);
                acc0[j].w = fmaf(a0, w.w, acc0[j].w);
                acc1[j].x = fmaf(a1, w.x, acc1[j].x);
                acc1[j].y = fmaf(a1, w.y, acc1[j].y);
                acc1[j].z = fmaf(a1, w.z, acc1[j].z);
                acc1[j].w = fmaf(a1, w.w, acc1[j].w);
            }
        }
        __syncthreads();
    }

    #pragma unroll
    for (int half = 0; half < 2; ++half) {
        const int gr = brow + r0 + half * 32;
        float4* acc = half ? acc1 : acc0;
        if (gr < n) {
            float pel[H], per_[H];
            #pragma unroll
            for (int h = 0; h < H; ++h) { pel[h] = 0.f; per_[h] = 0.f; }
            #pragma unroll
            for (int j = 0; j < F4; ++j) {
                int cbase = g * 4 + 32 * j;
                __half2 h01 = __floats2half2_rn(acc[j].x, acc[j].y);
                __half2 h23 = __floats2half2_rn(acc[j].z, acc[j].w);
                uint2 pk;
                pk.x = *reinterpret_cast<unsigned*>(&h01);
                pk.y = *reinterpret_cast<unsigned*>(&h23);
                *reinterpret_cast<uint2*>(feat + (size_t)gr * C + cbase) = pk;
                float av[4] = {acc[j].x, acc[j].y, acc[j].z, acc[j].w};
                #pragma unroll
                for (int u = 0; u < 4; ++u) {
                    int col = cbase + u;
                    int head = (H == 2) ? (col >> 6) : 0;
                    int lc = col & 63;
                    pel[head] += av[u] * al[head * 64 + lc];
                    per_[head] += av[u] * ar[head * 64 + lc];
                }
            }
            #pragma unroll
            for (int off = 1; off < 8; off <<= 1) {
                #pragma unroll
                for (int h = 0; h < H; ++h) {
                    pel[h] += __shfl_xor(pel[h], off, 64);
                    per_[h] += __shfl_xor(per_[h], off, 64);
                }
            }
            if (g == 0) {
                #pragma unroll
                for (int h = 0; h < H; ++h) {
                    el[(size_t)gr * H + h] = pel[h];
                    er[(size_t)gr * H + h] = per_[h];
                }
            }
        }
    }
}

// ---------------- CSR build (by dst), once per launch ----------------
__global__ void hist_dst(const int* __restrict__ dst, int* __restrict__ cnt, int E)
{
    int e = blockIdx.x * blockDim.x + threadIdx.x;
    if (e < E) atomicAdd(&cnt[dst[e]], 1);
}

__global__ void scan_block_sums(const int* __restrict__ cnt, int* __restrict__ bsum, int n)
{
    __shared__ int sh[256];
    int i = blockIdx.x * 256 + threadIdx.x;
    sh[threadIdx.x] = (i < n) ? cnt[i] : 0;
    __syncthreads();
    for (int off = 128; off; off >>= 1) {
        if (threadIdx.x < off) sh[threadIdx.x] += sh[threadIdx.x + off];
        __syncthreads();
    }
    if (threadIdx.x == 0) bsum[blockIdx.x] = sh[0];
}

__global__ void scan_bsum(int* __restrict__ bsum, int nb)
{
    __shared__ int sh[256];
    int t = threadIdx.x;
    sh[t] = (t < nb) ? bsum[t] : 0;
    __syncthreads();
    for (int off = 1; off < 256; off <<= 1) {
        int u = (t >= off) ? sh[t - off] : 0;
        __syncthreads();
        sh[t] += u;
        __syncthreads();
    }
    if (t < nb) bsum[t] = t ? sh[t - 1] : 0;   // exclusive
}

__global__ void scan_final(const int* __restrict__ cnt, const int* __restrict__ bsum,
                           int* __restrict__ rs, int* __restrict__ cursor, int n)
{
    __shared__ int sh[256];
    int t = threadIdx.x;
    int i = blockIdx.x * 256 + t;
    int v = (i < n) ? cnt[i] : 0;
    sh[t] = v;
    __syncthreads();
    for (int off = 1; off < 256; off <<= 1) {
        int u = (t >= off) ? sh[t - off] : 0;
        __syncthreads();
        sh[t] += u;
        __syncthreads();
    }
    int excl = sh[t] - v + bsum[blockIdx.x];
    if (i < n) { rs[i] = excl; cursor[i] = excl; }
    if (i == n - 1) rs[n] = excl + v;
}

__global__ void scatter_csr(const int* __restrict__ src, const int* __restrict__ dst,
                            int* __restrict__ cursor, int* __restrict__ csr, int E)
{
    int e = blockIdx.x * blockDim.x + threadIdx.x;
    if (e < E) {
        int d = dst[e];
        int pos = atomicAdd(&cursor[d], 1);
        csr[pos] = src[e];
    }
}

// ---------------- fused GAT edge-softmax + aggregate v3 (fp16 feat gather) ----------------
// Pass A: lane-parallel segment max. Pass B: lane owns 8 channels (one 16B fp16 load);
// wave processes 4 edges (C=128) or 8 edges (C=64) concurrently; f32 accumulate.
template <int C, int H>
__launch_bounds__(256)
__global__ void gat_agg(const int* __restrict__ rs, const int* __restrict__ csr,
                        const float* __restrict__ el, const float* __restrict__ er,
                        const __half* __restrict__ feat, const float* __restrict__ bias,
                        float* __restrict__ outp, int n)
{
    int node = blockIdx.x * 4 + (threadIdx.x >> 6);
    if (node >= n) return;
    int lane = threadIdx.x & 63;
    int start = rs[node], end = rs[node + 1];

    if constexpr (H == 2) {
        float2 e2 = *reinterpret_cast<const float2*>(er + (size_t)node * 2);
        // ---- pass A ----
        float m0 = -INFINITY, m1 = -INFINITY;
        for (int j = start + lane; j < end; j += 64) {
            int s = csr[j];
            float2 l2 = *reinterpret_cast<const float2*>(el + (size_t)s * 2);
            float v0 = l2.x + e2.x; v0 = v0 >= 0.f ? v0 : 0.2f * v0;
            float v1 = l2.y + e2.y; v1 = v1 >= 0.f ? v1 : 0.2f * v1;
            m0 = fmaxf(m0, v0); m1 = fmaxf(m1, v1);
        }
        #pragma unroll
        for (int off = 32; off; off >>= 1) {
            m0 = fmaxf(m0, __shfl_xor(m0, off, 64));
            m1 = fmaxf(m1, __shfl_xor(m1, off, 64));
        }
        // ---- pass B: 4 edge slots x 16 lanes; lane owns channels cl*8..cl*8+7 ----
        const int slot = lane >> 4;
        const int cl = lane & 15;
        const int h = cl >> 3;
        const float mh = h ? m1 : m0;
        const float erh = h ? e2.y : e2.x;
        float ssum = 0.f;
        float acc[8];
        #pragma unroll
        for (int u = 0; u < 8; ++u) acc[u] = 0.f;
        for (int j = start + slot; j < end; j += 4) {
            int s = csr[j];
            float v = el[(size_t)s * 2 + h] + erh;
            v = v >= 0.f ? v : 0.2f * v;
            float p = __expf(v - mh);
            ssum += p;
            float4 raw = *reinterpret_cast<const float4*>(feat + (size_t)s * C + cl * 8);
            const __half2* hp = reinterpret_cast<const __half2*>(&raw);
            #pragma unroll
            for (int u = 0; u < 4; ++u) {
                float2 f2 = __half22float2(hp[u]);
                acc[2 * u]     = fmaf(p, f2.x, acc[2 * u]);
                acc[2 * u + 1] = fmaf(p, f2.y, acc[2 * u + 1]);
            }
        }
        #pragma unroll
        for (int off = 16; off <= 32; off <<= 1) {
            ssum += __shfl_xor(ssum, off, 64);
            #pragma unroll
            for (int u = 0; u < 8; ++u) acc[u] += __shfl_xor(acc[u], off, 64);
        }
        if (slot == 0) {
            float r = 1.f / fmaxf(ssum, 1e-9f);
            float4 o0 = make_float4(acc[0] * r, acc[1] * r, acc[2] * r, acc[3] * r);
            float4 o1 = make_float4(acc[4] * r, acc[5] * r, acc[6] * r, acc[7] * r);
            *reinterpret_cast<float4*>(outp + (size_t)node * C + cl * 8) = o0;
            *reinterpret_cast<float4*>(outp + (size_t)node * C + cl * 8 + 4) = o1;
        }
    } else {
        float er0 = er[node];
        // ---- pass A ----
        float m0 = -INFINITY;
        for (int j = start + lane; j < end; j += 64) {
            int s = csr[j];
            float v = el[s] + er0;
            v = v >= 0.f ? v : 0.2f * v;
            m0 = fmaxf(m0, v);
        }
        #pragma unroll
        for (int off = 32; off; off >>= 1)
            m0 = fmaxf(m0, __shfl_xor(m0, off, 64));
        // ---- pass B: 8 edge slots x 8 lanes; lane owns channels cl*8..cl*8+7 ----
        const int slot = lane >> 3;
        const int cl = lane & 7;
        float ssum = 0.f;
        float acc[8];
        #pragma unroll
        for (int u = 0; u < 8; ++u) acc[u] = 0.f;
        for (int j = start + slot; j < end; j += 8) {
            int s = csr[j];
            float v = el[s] + er0;
            v = v >= 0.f ? v : 0.2f * v;
            float p = __expf(v - m0);
            ssum += p;
            float4 raw = *reinterpret_cast<const float4*>(feat + (size_t)s * C + cl * 8);
            const __half2* hp = reinterpret_cast<const __half2*>(&raw);
            #pragma unroll
            for (int u = 0; u < 4; ++u) {
                float2 f2 = __half22float2(hp[u]);
                acc[2 * u]     = fmaf(p, f2.x, acc[2 * u]);
                acc[2 * u + 1] = fmaf(p, f2.y, acc[2 * u + 1]);
            }
        }
        #pragma unroll
        for (int off = 8; off <= 32; off <<= 1) {
            ssum += __shfl_xor(ssum, off, 64);
            #pragma unroll
            for (int u = 0; u < 8; ++u) acc[u] += __shfl_xor(acc[u], off, 64);
        }
        if (slot == 0) {
            float r = 1.f / fmaxf(ssum, 1e-9f);
            float4 o0, o1;
            o0.x = acc[0] * r + bias[cl * 8 + 0];
            o0.y = acc[1] * r + bias[cl * 8 + 1];
            o0.z = acc[2] * r + bias[cl * 8 + 2];
            o0.w = acc[3] * r + bias[cl * 8 + 3];
            o1.x = acc[4] * r + bias[cl * 8 + 4];
            o1.y = acc[5] * r + bias[cl * 8 + 5];
            o1.z = acc[6] * r + bias[cl * 8 + 6];
            o1.w = acc[7] * r + bias[cl * 8 + 7];
            *reinterpret_cast<float4*>(outp + (size_t)node * C + cl * 8) = o0;
            *reinterpret_cast<float4*>(outp + (size_t)node * C + cl * 8 + 4) = o1;
        }
    }
}

// ---------------- BatchNorm stats (C=128) ----------------
__global__ void bn_stats(const float* __restrict__ h, float* __restrict__ sums, int n)
{
    __shared__ float s1[256], s2[256];
    int c = threadIdx.x & 127, half = threadIdx.x >> 7;
    float ls = 0.f, lq = 0.f;
    for (int r = blockIdx.x * 2 + half; r < n; r += gridDim.x * 2) {
        float v = h[(size_t)r * 128 + c];
        ls += v; lq += v * v;
    }
    s1[threadIdx.x] = ls; s2[threadIdx.x] = lq;
    __syncthreads();
    if (threadIdx.x < 128) {
        atomicAdd(&sums[c], s1[threadIdx.x] + s1[threadIdx.x + 128]);
        atomicAdd(&sums[128 + c], s2[threadIdx.x] + s2[threadIdx.x + 128]);
    }
}

__global__ void bn_apply(float* __restrict__ h, const float* __restrict__ sums,
                         const float* __restrict__ g, const float* __restrict__ b,
                         long long total)
{
    long long i = (long long)blockIdx.x * blockDim.x + threadIdx.x;
    if (i >= total) return;
    int c = (int)(i & 127);
    const float invN = 1.f / (float)N_NODES;
    float mean = sums[c] * invN;
    float var = sums[128 + c] * invN - mean * mean;
    float v = (h[i] - mean) * rsqrtf(var + 1e-5f) * g[c] + b[c];
    h[i] = fmaxf(v, 0.f);
}

// ---------------- predictor v3: tiled batched GEMM, 64 pairs per block ----------------
// zt reused for z and a1 (50.2KB LDS -> 3 blocks/CU). Phase 1: pair=lane,
// channel-quarter=wave (2-way write conflicts only). a1 writeback as float4.
__launch_bounds__(256, 3)
__global__ void predictor(const float* __restrict__ h,
                          const int* __restrict__ ps, const int* __restrict__ pd,
                          const int* __restrict__ ns, const int* __restrict__ nd,
                          const float* __restrict__ W1, const float* __restrict__ b1,
                          const float* __restrict__ W2, const float* __restrict__ b2,
                          const float* __restrict__ W3, const float* __restrict__ b3,
                          float* __restrict__ out, int P)
{
    __shared__ float w1[64 * 64];   // [k][c]
    __shared__ float w2[64 * 64];   // [k][c]
    __shared__ float zt[64 * 68];   // [c][p] padded; reused for z then a1
    const int tid = threadIdx.x;

    for (int i = tid; i < 1024; i += 256) {
        *reinterpret_cast<float4*>(&w1[i * 4]) = *reinterpret_cast<const float4*>(W1 + i * 4);
        *reinterpret_cast<float4*>(&w2[i * 4]) = *reinterpret_cast<const float4*>(W2 + i * 4);
    }

    // phase 1: z[p][c] = h[s][c]*h[d][c]; thread handles pair l, channels w*16..w*16+15
    {
        int l = tid & 63, w = tid >> 6;
        int gp = blockIdx.x * 64 + l;
        int s, d;
        if (gp < P) { s = ps[gp]; d = pd[gp]; }
        else        { s = ns[gp - P]; d = nd[gp - P]; }
        const float4* hs = reinterpret_cast<const float4*>(h + (size_t)s * 64 + w * 16);
        const float4* hd = reinterpret_cast<const float4*>(h + (size_t)d * 64 + w * 16);
        #pragma unroll
        for (int j = 0; j < 4; ++j) {
            float4 a = hs[j], b = hd[j];
            int c0 = w * 16 + j * 4;
            zt[(c0 + 0) * 68 + l] = a.x * b.x;
            zt[(c0 + 1) * 68 + l] = a.y * b.y;
            zt[(c0 + 2) * 68 + l] = a.z * b.z;
            zt[(c0 + 3) * 68 + l] = a.w * b.w;
        }
    }
    __syncthreads();

    const int pb = tid >> 4;
    const int cb = tid & 15;
    const int p0 = pb * 4, c0 = cb * 4;
    float4 vb1 = *reinterpret_cast<const float4*>(b1 + c0);
    float4 vb2 = *reinterpret_cast<const float4*>(b2 + c0);
    float4 vw3 = *reinterpret_cast<const float4*>(W3 + c0);
    const float b3v = b3[0];

    float acc[4][4];

    // ---- layer 1: a1 = relu(z @ W1 + b1) ----
    #pragma unroll
    for (int i = 0; i < 4; ++i)
        #pragma unroll
        for (int j = 0; j < 4; ++j) acc[i][j] = 0.f;

    #pragma unroll 4
    for (int k = 0; k < 64; ++k) {
        float4 zv = *reinterpret_cast<const float4*>(&zt[k * 68 + p0]);
        float4 wv = *reinterpret_cast<const float4*>(&w1[k * 64 + c0]);
        float zz[4] = {zv.x, zv.y, zv.z, zv.w};
        float ww[4] = {wv.x, wv.y, wv.z, wv.w};
        #pragma unroll
        for (int i = 0; i < 4; ++i)
            #pragma unroll
            for (int j = 0; j < 4; ++j)
                acc[i][j] = fmaf(zz[i], ww[j], acc[i][j]);
    }
    __syncthreads();   // all reads of z complete before overwrite
    {
        float bb[4] = {vb1.x, vb1.y, vb1.z, vb1.w};
        #pragma unroll
        for (int j = 0; j < 4; ++j) {
            float4 st = make_float4(fmaxf(acc[0][j] + bb[j], 0.f),
                                    fmaxf(acc[1][j] + bb[j], 0.f),
                                    fmaxf(acc[2][j] + bb[j], 0.f),
                                    fmaxf(acc[3][j] + bb[j], 0.f));
            *reinterpret_cast<float4*>(&zt[(c0 + j) * 68 + p0]) = st;
        }
    }
    __syncthreads();

    // ---- layer 2: a2 = relu(a1 @ W2 + b2); out = a2 @ w3 + b3 ----
    #pragma unroll
    for (int i = 0; i < 4; ++i)
        #pragma unroll
        for (int j = 0; j < 4; ++j) acc[i][j] = 0.f;

    #pragma unroll 4
    for (int k = 0; k < 64; ++k) {
        float4 zv = *reinterpret_cast<const float4*>(&zt[k * 68 + p0]);
        float4 wv = *reinterpret_cast<const float4*>(&w2[k * 64 + c0]);
        float zz[4] = {zv.x, zv.y, zv.z, zv.w};
        float ww[4] = {wv.x, wv.y, wv.z, wv.w};
        #pragma unroll
        for (int i = 0; i < 4; ++i)
            #pragma unroll
            for (int j = 0; j < 4; ++j)
                acc[i][j] = fmaf(zz[i], ww[j], acc[i][j]);
    }

    float part[4];
    {
        float bb[4] = {vb2.x, vb2.y, vb2.z, vb2.w};
        float w3v[4] = {vw3.x, vw3.y, vw3.z, vw3.w};
        #pragma unroll
        for (int i = 0; i < 4; ++i) {
            float su = 0.f;
            #pragma unroll
            for (int j = 0; j < 4; ++j)
                su += fmaxf(acc[i][j] + bb[j], 0.f) * w3v[j];
            part[i] = su;
        }
    }
    #pragma unroll
    for (int off = 1; off < 16; off <<= 1) {
        #pragma unroll
        for (int i = 0; i < 4; ++i)
            part[i] += __shfl_xor(part[i], off, 16);
    }
    if (cb == 0) {
        int gp0 = blockIdx.x * 64 + p0;
        #pragma unroll
        for (int i = 0; i < 4; ++i)
            out[gp0 + i] = part[i] + b3v;
    }
}

extern "C" void kernel_launch(void* const* d_in, const int* in_sizes, int n_in,
                              void* d_out, int out_size, void* d_ws, size_t ws_size,
                              hipStream_t stream)
{
    const float* x    = (const float*)d_in[0];
    const int* es     = (const int*)d_in[1];
    const int* ed     = (const int*)d_in[2];
    const int* ps     = (const int*)d_in[3];
    const int* pdst   = (const int*)d_in[4];
    const int* ns     = (const int*)d_in[5];
    const int* nd     = (const int*)d_in[6];
    const float* W0   = (const float*)d_in[7];
    const float* al0  = (const float*)d_in[8];
    const float* ar0  = (const float*)d_in[9];
    const float* W1   = (const float*)d_in[11];
    const float* al1  = (const float*)d_in[12];
    const float* ar1  = (const float*)d_in[13];
    const float* W2   = (const float*)d_in[15];
    const float* al2  = (const float*)d_in[16];
    const float* ar2  = (const float*)d_in[17];
    const float* b2   = (const float*)d_in[18];
    const float* bn0g = (const float*)d_in[19];
    const float* bn0b = (const float*)d_in[20];
    const float* bn1g = (const float*)d_in[21];
    const float* bn1b = (const float*)d_in[22];
    const float* pW1  = (const float*)d_in[23];
    const float* pb1  = (const float*)d_in[24];
    const float* pW2  = (const float*)d_in[25];
    const float* pb2  = (const float*)d_in[26];
    const float* pW3  = (const float*)d_in[27];
    const float* pb3  = (const float*)d_in[28];
    float* out = (float*)d_out;

    float* ws = (float*)d_ws;
    size_t off = 0;
    auto alloc = [&](size_t nelem) {
        float* p = ws + off;
        off += (nelem + 63) & ~(size_t)63;
        return p;
    };
    __half* featb = (__half*)alloc((size_t)N_NODES * 64);   // 50000 x 128 halfs
    float* hb    = alloc((size_t)N_NODES * 128);
    float* el    = alloc((size_t)N_NODES * 2);
    float* er    = alloc((size_t)N_NODES * 2);
    float* bns   = alloc(256);
    int* cnt     = (int*)alloc(N_NODES);
    int* rs      = (int*)alloc(N_NODES + 1);
    int* cursor  = (int*)alloc(N_NODES);
    int* bsum    = (int*)alloc(256);
    int* csr     = (int*)alloc(N_EDGES);

    dim3 blk(256);
    const int gemmGrid = (N_NODES + 63) / 64;
    const int edgeGrid = (N_EDGES + 255) / 256;
    const int nodeBlocks = (N_NODES + 255) / 256;
    const int aggGrid = (N_NODES + 3) / 4;

    // ================= CSR build (once; graph shared by all layers) =================
    hipMemsetAsync(cnt, 0, (size_t)N_NODES * sizeof(int), stream);
    hist_dst<<<edgeGrid, blk, 0, stream>>>(ed, cnt, N_EDGES);
    scan_block_sums<<<nodeBlocks, blk, 0, stream>>>(cnt, bsum, N_NODES);
    scan_bsum<<<1, blk, 0, stream>>>(bsum, nodeBlocks);
    scan_final<<<nodeBlocks, blk, 0, stream>>>(cnt, bsum, rs, cursor, N_NODES);
    scatter_csr<<<edgeGrid, blk, 0, stream>>>(es, ed, cursor, csr, N_EDGES);

    // ================= layer 0 (C=128, H=2) =================
    gemm_feat<128, 2><<<gemmGrid, blk, 0, stream>>>(x, W0, al0, ar0, featb, el, er, N_NODES);
    gat_agg<128, 2><<<aggGrid, blk, 0, stream>>>(rs, csr, el, er, featb, nullptr, hb, N_NODES);
    hipMemsetAsync(bns, 0, 256 * sizeof(float), stream);
    bn_stats<<<256, blk, 0, stream>>>(hb, bns, N_NODES);
    bn_apply<<<(N_NODES * 128 + 255) / 256, blk, 0, stream>>>(hb, bns, bn0g, bn0b,
                                                              (long long)N_NODES * 128);

    // ================= layer 1 (C=128, H=2) =================
    gemm_feat<128, 2><<<gemmGrid, blk, 0, stream>>>(hb, W1, al1, ar1, featb, el, er, N_NODES);
    gat_agg<128, 2><<<aggGrid, blk, 0, stream>>>(rs, csr, el, er, featb, nullptr, hb, N_NODES);
    hipMemsetAsync(bns, 0, 256 * sizeof(float), stream);
    bn_stats<<<256, blk, 0, stream>>>(hb, bns, N_NODES);
    bn_apply<<<(N_NODES * 128 + 255) / 256, blk, 0, stream>>>(hb, bns, bn1g, bn1b,
                                                              (long long)N_NODES * 128);

    // ================= layer 2 (C=64, H=1) =================
    gemm_feat<64, 1><<<gemmGrid, blk, 0, stream>>>(hb, W2, al2, ar2, featb, el, er, N_NODES);
    gat_agg<64, 1><<<aggGrid, blk, 0, stream>>>(rs, csr, el, er, featb, b2, hb, N_NODES);

    // ================= predictor =================
    predictor<<<3125, blk, 0, stream>>>(hb, ps, pdst, ns, nd,
                                        pW1, pb1, pW2, pb2, pW3, pb3, out, 100000);
}

// Round 7
// 502.666 us; speedup vs baseline: 10.0428x; 1.1329x over previous
//
#include <hip/hip_runtime.h>
#include <hip/hip_fp16.h>
#include <cstdint>
#include <cstddef>

#define N_NODES 50000
#define N_EDGES 800000

typedef _Float16 f16x8 __attribute__((ext_vector_type(8)));
typedef float f32x4 __attribute__((ext_vector_type(4)));

// ---------------- f32 -> f16 convert (for x) ----------------
__global__ void f32_to_f16(const float* __restrict__ in, __half* __restrict__ outp, int n4)
{
    int i = blockIdx.x * blockDim.x + threadIdx.x;
    int stride = gridDim.x * blockDim.x;
    for (; i < n4; i += stride) {
        float4 v = *reinterpret_cast<const float4*>(in + (size_t)i * 4);
        __half2 a = __floats2half2_rn(v.x, v.y);
        __half2 b = __floats2half2_rn(v.z, v.w);
        uint2 pk;
        pk.x = *reinterpret_cast<unsigned*>(&a);
        pk.y = *reinterpret_cast<unsigned*>(&b);
        *reinterpret_cast<uint2*>(outp + (size_t)i * 4) = pk;
    }
}

// ---------------- W -> Wt[c][k] fp16 pre-transpose (all 3 layers) ----------------
__global__ void prep_wt(const float* __restrict__ W0, const float* __restrict__ W1,
                        const float* __restrict__ W2, __half* __restrict__ t0,
                        __half* __restrict__ t1, __half* __restrict__ t2)
{
    int b = blockIdx.x >> 7;          // which W
    int k = blockIdx.x & 127;         // input-dim row
    int c = threadIdx.x;              // output col
    const float* W = (b == 0) ? W0 : (b == 1) ? W1 : W2;
    __half* T = (b == 0) ? t0 : (b == 1) ? t1 : t2;
    int Cb = (b == 2) ? 64 : 128;
    if (c < Cb) T[(size_t)c * 128 + k] = __float2half(W[(size_t)k * Cb + c]);
}

// ---------------- MFMA GEMM (n x 128) @ (128 x C) + fused attn-dot epilogue ----------------
// A fp16 [n][128]; Wt fp16 [C][128] (pre-transposed). Each wave: 16 rows x C cols.
// mfma_f32_16x16x32_f16; C/D layout: col=lane&15, row=(lane>>4)*4+reg [m89].
template <int C, int H>
__launch_bounds__(256, 3)
__global__ void gemm_mfma(const __half* __restrict__ Ah, const __half* __restrict__ Wt,
                          const float* __restrict__ al, const float* __restrict__ ar,
                          __half* __restrict__ feat, float* __restrict__ el,
                          float* __restrict__ er, int n)
{
    constexpr int K = 128;
    constexpr int AS = 136;                  // padded halves/row: 272B, 16B-aligned, banks spread
    constexpr int CT = C / 16;
    __shared__ __half As[64 * AS];           // 17.0 KB
    __shared__ __half Ws[C * AS];            // 34.0 KB (C=128)

    const int tid = threadIdx.x;
    const int brow = blockIdx.x * 64;

    // stage A tile (64 x 128 f16), zero-fill OOB rows
    for (int idx = tid; idx < 64 * 16; idx += 256) {
        int r = idx >> 4, u = idx & 15;
        int gr = brow + r;
        f16x8 v = {0, 0, 0, 0, 0, 0, 0, 0};
        if (gr < n) v = *reinterpret_cast<const f16x8*>(Ah + (size_t)gr * K + u * 8);
        *reinterpret_cast<f16x8*>(&As[r * AS + u * 8]) = v;
    }
    // stage Wt (C x 128 f16)
    for (int idx = tid; idx < C * 16; idx += 256) {
        int c = idx >> 4, u = idx & 15;
        *reinterpret_cast<f16x8*>(&Ws[c * AS + u * 8]) =
            *reinterpret_cast<const f16x8*>(Wt + (size_t)c * K + u * 8);
    }
    __syncthreads();

    const int w = tid >> 6;       // wave -> rows w*16..w*16+15
    const int l = tid & 63;
    const int l15 = l & 15;
    const int kg = l >> 4;

    f32x4 acc[CT];
    #pragma unroll
    for (int ct = 0; ct < CT; ++ct) acc[ct] = (f32x4){0.f, 0.f, 0.f, 0.f};

    #pragma unroll
    for (int kt = 0; kt < 4; ++kt) {
        f16x8 a = *reinterpret_cast<const f16x8*>(&As[(w * 16 + l15) * AS + kt * 32 + kg * 8]);
        #pragma unroll
        for (int ct = 0; ct < CT; ++ct) {
            f16x8 b = *reinterpret_cast<const f16x8*>(&Ws[(ct * 16 + l15) * AS + kt * 32 + kg * 8]);
            acc[ct] = __builtin_amdgcn_mfma_f32_16x16x32_f16(a, b, acc[ct], 0, 0, 0);
        }
    }

    // epilogue: feat store (fp16) + el/er dots
    const int row0 = w * 16 + kg * 4;        // + j (reg)
    float pel[4][H], per_[4][H];
    #pragma unroll
    for (int j = 0; j < 4; ++j)
        #pragma unroll
        for (int h = 0; h < H; ++h) { pel[j][h] = 0.f; per_[j][h] = 0.f; }

    #pragma unroll
    for (int ct = 0; ct < CT; ++ct) {
        int col = ct * 16 + l15;
        int head = (H == 2) ? (col >> 6) : 0;
        int lc = col & 63;
        float av = al[head * 64 + lc];
        float rv = ar[head * 64 + lc];
        #pragma unroll
        for (int j = 0; j < 4; ++j) {
            float fv = acc[ct][j];
            int gr = brow + row0 + j;
            if (gr < n) feat[(size_t)gr * C + col] = __float2half(fv);
            pel[j][head] += fv * av;
            per_[j][head] += fv * rv;
        }
    }
    // reduce across the 16 col-lanes (xor offsets < 16 stay within the group)
    #pragma unroll
    for (int off = 1; off < 16; off <<= 1) {
        #pragma unroll
        for (int j = 0; j < 4; ++j)
            #pragma unroll
            for (int h = 0; h < H; ++h) {
                pel[j][h] += __shfl_xor(pel[j][h], off, 64);
                per_[j][h] += __shfl_xor(per_[j][h], off, 64);
            }
    }
    if (l15 == 0) {
        #pragma unroll
        for (int j = 0; j < 4; ++j) {
            int gr = brow + row0 + j;
            if (gr < n) {
                if constexpr (H == 2) {
                    float2 e0 = make_float2(pel[j][0], pel[j][1]);
                    float2 e1 = make_float2(per_[j][0], per_[j][1]);
                    *reinterpret_cast<float2*>(el + (size_t)gr * 2) = e0;
                    *reinterpret_cast<float2*>(er + (size_t)gr * 2) = e1;
                } else {
                    el[gr] = pel[j][0];
                    er[gr] = per_[j][0];
                }
            }
        }
    }
}

// ---------------- CSR build (by dst), once per launch ----------------
__global__ void hist_dst(const int* __restrict__ dst, int* __restrict__ cnt, int E)
{
    int e = blockIdx.x * blockDim.x + threadIdx.x;
    if (e < E) atomicAdd(&cnt[dst[e]], 1);
}

__global__ void scan_block_sums(const int* __restrict__ cnt, int* __restrict__ bsum, int n)
{
    __shared__ int sh[256];
    int i = blockIdx.x * 256 + threadIdx.x;
    sh[threadIdx.x] = (i < n) ? cnt[i] : 0;
    __syncthreads();
    for (int off = 128; off; off >>= 1) {
        if (threadIdx.x < off) sh[threadIdx.x] += sh[threadIdx.x + off];
        __syncthreads();
    }
    if (threadIdx.x == 0) bsum[blockIdx.x] = sh[0];
}

__global__ void scan_bsum(int* __restrict__ bsum, int nb)
{
    __shared__ int sh[256];
    int t = threadIdx.x;
    sh[t] = (t < nb) ? bsum[t] : 0;
    __syncthreads();
    for (int off = 1; off < 256; off <<= 1) {
        int u = (t >= off) ? sh[t - off] : 0;
        __syncthreads();
        sh[t] += u;
        __syncthreads();
    }
    if (t < nb) bsum[t] = t ? sh[t - 1] : 0;   // exclusive
}

__global__ void scan_final(const int* __restrict__ cnt, const int* __restrict__ bsum,
                           int* __restrict__ rs, int* __restrict__ cursor, int n)
{
    __shared__ int sh[256];
    int t = threadIdx.x;
    int i = blockIdx.x * 256 + t;
    int v = (i < n) ? cnt[i] : 0;
    sh[t] = v;
    __syncthreads();
    for (int off = 1; off < 256; off <<= 1) {
        int u = (t >= off) ? sh[t - off] : 0;
        __syncthreads();
        sh[t] += u;
        __syncthreads();
    }
    int excl = sh[t] - v + bsum[blockIdx.x];
    if (i < n) { rs[i] = excl; cursor[i] = excl; }
    if (i == n - 1) rs[n] = excl + v;
}

__global__ void scatter_csr(const int* __restrict__ src, const int* __restrict__ dst,
                            int* __restrict__ cursor, int* __restrict__ csr, int E)
{
    int e = blockIdx.x * blockDim.x + threadIdx.x;
    if (e < E) {
        int d = dst[e];
        int pos = atomicAdd(&cursor[d], 1);
        csr[pos] = src[e];
    }
}

// ---------------- fused GAT edge-softmax + aggregate (fp16 feat gather) ----------------
template <int C, int H>
__launch_bounds__(256)
__global__ void gat_agg(const int* __restrict__ rs, const int* __restrict__ csr,
                        const float* __restrict__ el, const float* __restrict__ er,
                        const __half* __restrict__ feat, const float* __restrict__ bias,
                        float* __restrict__ outp, int n)
{
    int node = blockIdx.x * 4 + (threadIdx.x >> 6);
    if (node >= n) return;
    int lane = threadIdx.x & 63;
    int start = rs[node], end = rs[node + 1];

    if constexpr (H == 2) {
        float2 e2 = *reinterpret_cast<const float2*>(er + (size_t)node * 2);
        float m0 = -INFINITY, m1 = -INFINITY;
        for (int j = start + lane; j < end; j += 64) {
            int s = csr[j];
            float2 l2 = *reinterpret_cast<const float2*>(el + (size_t)s * 2);
            float v0 = l2.x + e2.x; v0 = v0 >= 0.f ? v0 : 0.2f * v0;
            float v1 = l2.y + e2.y; v1 = v1 >= 0.f ? v1 : 0.2f * v1;
            m0 = fmaxf(m0, v0); m1 = fmaxf(m1, v1);
        }
        #pragma unroll
        for (int off = 32; off; off >>= 1) {
            m0 = fmaxf(m0, __shfl_xor(m0, off, 64));
            m1 = fmaxf(m1, __shfl_xor(m1, off, 64));
        }
        const int slot = lane >> 4;
        const int cl = lane & 15;
        const int h = cl >> 3;
        const float mh = h ? m1 : m0;
        const float erh = h ? e2.y : e2.x;
        float ssum = 0.f;
        float acc[8];
        #pragma unroll
        for (int u = 0; u < 8; ++u) acc[u] = 0.f;
        for (int j = start + slot; j < end; j += 4) {
            int s = csr[j];
            float v = el[(size_t)s * 2 + h] + erh;
            v = v >= 0.f ? v : 0.2f * v;
            float p = __expf(v - mh);
            ssum += p;
            float4 raw = *reinterpret_cast<const float4*>(feat + (size_t)s * C + cl * 8);
            const __half2* hp = reinterpret_cast<const __half2*>(&raw);
            #pragma unroll
            for (int u = 0; u < 4; ++u) {
                float2 f2 = __half22float2(hp[u]);
                acc[2 * u]     = fmaf(p, f2.x, acc[2 * u]);
                acc[2 * u + 1] = fmaf(p, f2.y, acc[2 * u + 1]);
            }
        }
        #pragma unroll
        for (int off = 16; off <= 32; off <<= 1) {
            ssum += __shfl_xor(ssum, off, 64);
            #pragma unroll
            for (int u = 0; u < 8; ++u) acc[u] += __shfl_xor(acc[u], off, 64);
        }
        if (slot == 0) {
            float r = 1.f / fmaxf(ssum, 1e-9f);
            float4 o0 = make_float4(acc[0] * r, acc[1] * r, acc[2] * r, acc[3] * r);
            float4 o1 = make_float4(acc[4] * r, acc[5] * r, acc[6] * r, acc[7] * r);
            *reinterpret_cast<float4*>(outp + (size_t)node * C + cl * 8) = o0;
            *reinterpret_cast<float4*>(outp + (size_t)node * C + cl * 8 + 4) = o1;
        }
    } else {
        float er0 = er[node];
        float m0 = -INFINITY;
        for (int j = start + lane; j < end; j += 64) {
            int s = csr[j];
            float v = el[s] + er0;
            v = v >= 0.f ? v : 0.2f * v;
            m0 = fmaxf(m0, v);
        }
        #pragma unroll
        for (int off = 32; off; off >>= 1)
            m0 = fmaxf(m0, __shfl_xor(m0, off, 64));
        const int slot = lane >> 3;
        const int cl = lane & 7;
        float ssum = 0.f;
        float acc[8];
        #pragma unroll
        for (int u = 0; u < 8; ++u) acc[u] = 0.f;
        for (int j = start + slot; j < end; j += 8) {
            int s = csr[j];
            float v = el[s] + er0;
            v = v >= 0.f ? v : 0.2f * v;
            float p = __expf(v - m0);
            ssum += p;
            float4 raw = *reinterpret_cast<const float4*>(feat + (size_t)s * C + cl * 8);
            const __half2* hp = reinterpret_cast<const __half2*>(&raw);
            #pragma unroll
            for (int u = 0; u < 4; ++u) {
                float2 f2 = __half22float2(hp[u]);
                acc[2 * u]     = fmaf(p, f2.x, acc[2 * u]);
                acc[2 * u + 1] = fmaf(p, f2.y, acc[2 * u + 1]);
            }
        }
        #pragma unroll
        for (int off = 8; off <= 32; off <<= 1) {
            ssum += __shfl_xor(ssum, off, 64);
            #pragma unroll
            for (int u = 0; u < 8; ++u) acc[u] += __shfl_xor(acc[u], off, 64);
        }
        if (slot == 0) {
            float r = 1.f / fmaxf(ssum, 1e-9f);
            float4 o0, o1;
            o0.x = acc[0] * r + bias[cl * 8 + 0];
            o0.y = acc[1] * r + bias[cl * 8 + 1];
            o0.z = acc[2] * r + bias[cl * 8 + 2];
            o0.w = acc[3] * r + bias[cl * 8 + 3];
            o1.x = acc[4] * r + bias[cl * 8 + 4];
            o1.y = acc[5] * r + bias[cl * 8 + 5];
            o1.z = acc[6] * r + bias[cl * 8 + 6];
            o1.w = acc[7] * r + bias[cl * 8 + 7];
            *reinterpret_cast<float4*>(outp + (size_t)node * C + cl * 8) = o0;
            *reinterpret_cast<float4*>(outp + (size_t)node * C + cl * 8 + 4) = o1;
        }
    }
}

// ---------------- BatchNorm stats (C=128) ----------------
__global__ void bn_stats(const float* __restrict__ h, float* __restrict__ sums, int n)
{
    __shared__ float s1[256], s2[256];
    int c = threadIdx.x & 127, half = threadIdx.x >> 7;
    float ls = 0.f, lq = 0.f;
    for (int r = blockIdx.x * 2 + half; r < n; r += gridDim.x * 2) {
        float v = h[(size_t)r * 128 + c];
        ls += v; lq += v * v;
    }
    s1[threadIdx.x] = ls; s2[threadIdx.x] = lq;
    __syncthreads();
    if (threadIdx.x < 128) {
        atomicAdd(&sums[c], s1[threadIdx.x] + s1[threadIdx.x + 128]);
        atomicAdd(&sums[128 + c], s2[threadIdx.x] + s2[threadIdx.x + 128]);
    }
}

// ---------------- BN apply + ReLU -> fp16 (feeds next gemm_mfma) ----------------
__global__ void bn_apply(const float* __restrict__ in, __half* __restrict__ outp,
                         const float* __restrict__ sums,
                         const float* __restrict__ g, const float* __restrict__ b,
                         long long npairs)
{
    long long i = (long long)blockIdx.x * blockDim.x + threadIdx.x;
    if (i >= npairs) return;
    int c0 = (int)((i * 2) & 127);
    const float invN = 1.f / (float)N_NODES;
    float2 v = *reinterpret_cast<const float2*>(in + i * 2);
    float mean0 = sums[c0] * invN, mean1 = sums[c0 + 1] * invN;
    float var0 = sums[128 + c0] * invN - mean0 * mean0;
    float var1 = sums[128 + c0 + 1] * invN - mean1 * mean1;
    float o0 = fmaxf((v.x - mean0) * rsqrtf(var0 + 1e-5f) * g[c0] + b[c0], 0.f);
    float o1 = fmaxf((v.y - mean1) * rsqrtf(var1 + 1e-5f) * g[c0 + 1] + b[c0 + 1], 0.f);
    *reinterpret_cast<__half2*>(outp + i * 2) = __floats2half2_rn(o0, o1);
}

// ---------------- predictor: tiled batched GEMM, 64 pairs per block ----------------
__launch_bounds__(256, 3)
__global__ void predictor(const float* __restrict__ h,
                          const int* __restrict__ ps, const int* __restrict__ pd,
                          const int* __restrict__ ns, const int* __restrict__ nd,
                          const float* __restrict__ W1, const float* __restrict__ b1,
                          const float* __restrict__ W2, const float* __restrict__ b2,
                          const float* __restrict__ W3, const float* __restrict__ b3,
                          float* __restrict__ out, int P)
{
    __shared__ float w1[64 * 64];   // [k][c]
    __shared__ float w2[64 * 64];   // [k][c]
    __shared__ float zt[64 * 68];   // [c][p] padded; reused for z then a1
    const int tid = threadIdx.x;

    for (int i = tid; i < 1024; i += 256) {
        *reinterpret_cast<float4*>(&w1[i * 4]) = *reinterpret_cast<const float4*>(W1 + i * 4);
        *reinterpret_cast<float4*>(&w2[i * 4]) = *reinterpret_cast<const float4*>(W2 + i * 4);
    }

    {
        int l = tid & 63, w = tid >> 6;
        int gp = blockIdx.x * 64 + l;
        int s, d;
        if (gp < P) { s = ps[gp]; d = pd[gp]; }
        else        { s = ns[gp - P]; d = nd[gp - P]; }
        const float4* hs = reinterpret_cast<const float4*>(h + (size_t)s * 64 + w * 16);
        const float4* hd = reinterpret_cast<const float4*>(h + (size_t)d * 64 + w * 16);
        #pragma unroll
        for (int j = 0; j < 4; ++j) {
            float4 a = hs[j], b = hd[j];
            int c0 = w * 16 + j * 4;
            zt[(c0 + 0) * 68 + l] = a.x * b.x;
            zt[(c0 + 1) * 68 + l] = a.y * b.y;
            zt[(c0 + 2) * 68 + l] = a.z * b.z;
            zt[(c0 + 3) * 68 + l] = a.w * b.w;
        }
    }
    __syncthreads();

    const int pb = tid >> 4;
    const int cb = tid & 15;
    const int p0 = pb * 4, c0 = cb * 4;
    float4 vb1 = *reinterpret_cast<const float4*>(b1 + c0);
    float4 vb2 = *reinterpret_cast<const float4*>(b2 + c0);
    float4 vw3 = *reinterpret_cast<const float4*>(W3 + c0);
    const float b3v = b3[0];

    float acc[4][4];

    #pragma unroll
    for (int i = 0; i < 4; ++i)
        #pragma unroll
        for (int j = 0; j < 4; ++j) acc[i][j] = 0.f;

    #pragma unroll 4
    for (int k = 0; k < 64; ++k) {
        float4 zv = *reinterpret_cast<const float4*>(&zt[k * 68 + p0]);
        float4 wv = *reinterpret_cast<const float4*>(&w1[k * 64 + c0]);
        float zz[4] = {zv.x, zv.y, zv.z, zv.w};
        float ww[4] = {wv.x, wv.y, wv.z, wv.w};
        #pragma unroll
        for (int i = 0; i < 4; ++i)
            #pragma unroll
            for (int j = 0; j < 4; ++j)
                acc[i][j] = fmaf(zz[i], ww[j], acc[i][j]);
    }
    __syncthreads();
    {
        float bb[4] = {vb1.x, vb1.y, vb1.z, vb1.w};
        #pragma unroll
        for (int j = 0; j < 4; ++j) {
            float4 st = make_float4(fmaxf(acc[0][j] + bb[j], 0.f),
                                    fmaxf(acc[1][j] + bb[j], 0.f),
                                    fmaxf(acc[2][j] + bb[j], 0.f),
                                    fmaxf(acc[3][j] + bb[j], 0.f));
            *reinterpret_cast<float4*>(&zt[(c0 + j) * 68 + p0]) = st;
        }
    }
    __syncthreads();

    #pragma unroll
    for (int i = 0; i < 4; ++i)
        #pragma unroll
        for (int j = 0; j < 4; ++j) acc[i][j] = 0.f;

    #pragma unroll 4
    for (int k = 0; k < 64; ++k) {
        float4 zv = *reinterpret_cast<const float4*>(&zt[k * 68 + p0]);
        float4 wv = *reinterpret_cast<const float4*>(&w2[k * 64 + c0]);
        float zz[4] = {zv.x, zv.y, zv.z, zv.w};
        float ww[4] = {wv.x, wv.y, wv.z, wv.w};
        #pragma unroll
        for (int i = 0; i < 4; ++i)
            #pragma unroll
            for (int j = 0; j < 4; ++j)
                acc[i][j] = fmaf(zz[i], ww[j], acc[i][j]);
    }

    float part[4];
    {
        float bb[4] = {vb2.x, vb2.y, vb2.z, vb2.w};
        float w3v[4] = {vw3.x, vw3.y, vw3.z, vw3.w};
        #pragma unroll
        for (int i = 0; i < 4; ++i) {
            float su = 0.f;
            #pragma unroll
            for (int j = 0; j < 4; ++j)
                su += fmaxf(acc[i][j] + bb[j], 0.f) * w3v[j];
            part[i] = su;
        }
    }
    #pragma unroll
    for (int off = 1; off < 16; off <<= 1) {
        #pragma unroll
        for (int i = 0; i < 4; ++i)
            part[i] += __shfl_xor(part[i], off, 16);
    }
    if (cb == 0) {
        int gp0 = blockIdx.x * 64 + p0;
        #pragma unroll
        for (int i = 0; i < 4; ++i)
            out[gp0 + i] = part[i] + b3v;
    }
}

extern "C" void kernel_launch(void* const* d_in, const int* in_sizes, int n_in,
                              void* d_out, int out_size, void* d_ws, size_t ws_size,
                              hipStream_t stream)
{
    const float* x    = (const float*)d_in[0];
    const int* es     = (const int*)d_in[1];
    const int* ed     = (const int*)d_in[2];
    const int* ps     = (const int*)d_in[3];
    const int* pdst   = (const int*)d_in[4];
    const int* ns     = (const int*)d_in[5];
    const int* nd     = (const int*)d_in[6];
    const float* W0   = (const float*)d_in[7];
    const float* al0  = (const float*)d_in[8];
    const float* ar0  = (const float*)d_in[9];
    const float* W1   = (const float*)d_in[11];
    const float* al1  = (const float*)d_in[12];
    const float* ar1  = (const float*)d_in[13];
    const float* W2   = (const float*)d_in[15];
    const float* al2  = (const float*)d_in[16];
    const float* ar2  = (const float*)d_in[17];
    const float* b2   = (const float*)d_in[18];
    const float* bn0g = (const float*)d_in[19];
    const float* bn0b = (const float*)d_in[20];
    const float* bn1g = (const float*)d_in[21];
    const float* bn1b = (const float*)d_in[22];
    const float* pW1  = (const float*)d_in[23];
    const float* pb1  = (const float*)d_in[24];
    const float* pW2  = (const float*)d_in[25];
    const float* pb2  = (const float*)d_in[26];
    const float* pW3  = (const float*)d_in[27];
    const float* pb3  = (const float*)d_in[28];
    float* out = (float*)d_out;

    float* ws = (float*)d_ws;
    size_t off = 0;
    auto alloc = [&](size_t nelem) {
        float* p = ws + off;
        off += (nelem + 63) & ~(size_t)63;
        return p;
    };
    __half* featb = (__half*)alloc((size_t)N_NODES * 64);   // N x 128 halfs
    __half* xh    = (__half*)alloc((size_t)N_NODES * 64);   // fp16 activations (x / bn out)
    float* hb    = alloc((size_t)N_NODES * 128);
    __half* wt0  = (__half*)alloc(128 * 64);                // 128x128 halfs
    __half* wt1  = (__half*)alloc(128 * 64);
    __half* wt2  = (__half*)alloc(64 * 64);                 // 64x128 halfs
    float* el    = alloc((size_t)N_NODES * 2);
    float* er    = alloc((size_t)N_NODES * 2);
    float* bns   = alloc(256);
    int* cnt     = (int*)alloc(N_NODES);
    int* rs      = (int*)alloc(N_NODES + 1);
    int* cursor  = (int*)alloc(N_NODES);
    int* bsum    = (int*)alloc(256);
    int* csr     = (int*)alloc(N_EDGES);

    dim3 blk(256);
    const int gemmGrid = (N_NODES + 63) / 64;
    const int edgeGrid = (N_EDGES + 255) / 256;
    const int nodeBlocks = (N_NODES + 255) / 256;
    const int aggGrid = (N_NODES + 3) / 4;
    const long long bnPairs = (long long)N_NODES * 64;

    // ================= CSR build + fp16 prep =================
    hipMemsetAsync(cnt, 0, (size_t)N_NODES * sizeof(int), stream);
    hist_dst<<<edgeGrid, blk, 0, stream>>>(ed, cnt, N_EDGES);
    scan_block_sums<<<nodeBlocks, blk, 0, stream>>>(cnt, bsum, N_NODES);
    scan_bsum<<<1, blk, 0, stream>>>(bsum, nodeBlocks);
    scan_final<<<nodeBlocks, blk, 0, stream>>>(cnt, bsum, rs, cursor, N_NODES);
    scatter_csr<<<edgeGrid, blk, 0, stream>>>(es, ed, cursor, csr, N_EDGES);
    f32_to_f16<<<2048, blk, 0, stream>>>(x, xh, N_NODES * 32);
    prep_wt<<<384, dim3(128), 0, stream>>>(W0, W1, W2, wt0, wt1, wt2);

    // ================= layer 0 (C=128, H=2) =================
    gemm_mfma<128, 2><<<gemmGrid, blk, 0, stream>>>(xh, wt0, al0, ar0, featb, el, er, N_NODES);
    gat_agg<128, 2><<<aggGrid, blk, 0, stream>>>(rs, csr, el, er, featb, nullptr, hb, N_NODES);
    hipMemsetAsync(bns, 0, 256 * sizeof(float), stream);
    bn_stats<<<256, blk, 0, stream>>>(hb, bns, N_NODES);
    bn_apply<<<(int)((bnPairs + 255) / 256), blk, 0, stream>>>(hb, xh, bns, bn0g, bn0b, bnPairs);

    // ================= layer 1 (C=128, H=2) =================
    gemm_mfma<128, 2><<<gemmGrid, blk, 0, stream>>>(xh, wt1, al1, ar1, featb, el, er, N_NODES);
    gat_agg<128, 2><<<aggGrid, blk, 0, stream>>>(rs, csr, el, er, featb, nullptr, hb, N_NODES);
    hipMemsetAsync(bns, 0, 256 * sizeof(float), stream);
    bn_stats<<<256, blk, 0, stream>>>(hb, bns, N_NODES);
    bn_apply<<<(int)((bnPairs + 255) / 256), blk, 0, stream>>>(hb, xh, bns, bn1g, bn1b, bnPairs);

    // ================= layer 2 (C=64, H=1) =================
    gemm_mfma<64, 1><<<gemmGrid, blk, 0, stream>>>(xh, wt2, al2, ar2, featb, el, er, N_NODES);
    gat_agg<64, 1><<<aggGrid, blk, 0, stream>>>(rs, csr, el, er, featb, b2, hb, N_NODES);

    // ================= predictor =================
    predictor<<<3125, blk, 0, stream>>>(hb, ps, pdst, ns, nd,
                                        pW1, pb1, pW2, pb2, pW3, pb3, out, 100000);
}

// Round 8
// 467.586 us; speedup vs baseline: 10.7962x; 1.0750x over previous
//
#include <hip/hip_runtime.h>
#include <hip/hip_fp16.h>
#include <cstdint>
#include <cstddef>

#define N_NODES 50000
#define N_EDGES 800000

typedef _Float16 f16x8 __attribute__((ext_vector_type(8)));
typedef float f32x4 __attribute__((ext_vector_type(4)));

// ---------------- f32 -> f16 convert ----------------
__global__ void f32_to_f16(const float* __restrict__ in, __half* __restrict__ outp, int n4)
{
    int i = blockIdx.x * blockDim.x + threadIdx.x;
    int stride = gridDim.x * blockDim.x;
    for (; i < n4; i += stride) {
        float4 v = *reinterpret_cast<const float4*>(in + (size_t)i * 4);
        __half2 a = __floats2half2_rn(v.x, v.y);
        __half2 b = __floats2half2_rn(v.z, v.w);
        uint2 pk;
        pk.x = *reinterpret_cast<unsigned*>(&a);
        pk.y = *reinterpret_cast<unsigned*>(&b);
        *reinterpret_cast<uint2*>(outp + (size_t)i * 4) = pk;
    }
}

// ---------------- W -> Wt[c][k] fp16 pre-transpose (GAT layers) ----------------
__global__ void prep_wt(const float* __restrict__ W0, const float* __restrict__ W1,
                        const float* __restrict__ W2, __half* __restrict__ t0,
                        __half* __restrict__ t1, __half* __restrict__ t2)
{
    int b = blockIdx.x >> 7;
    int k = blockIdx.x & 127;
    int c = threadIdx.x;
    const float* W = (b == 0) ? W0 : (b == 1) ? W1 : W2;
    __half* T = (b == 0) ? t0 : (b == 1) ? t1 : t2;
    int Cb = (b == 2) ? 64 : 128;
    if (c < Cb) T[(size_t)c * 128 + k] = __float2half(W[(size_t)k * Cb + c]);
}

// ---------------- predictor weights -> [c][k] fp16 (64x64 each) ----------------
__global__ void prep_pwt(const float* __restrict__ W1, const float* __restrict__ W2,
                         __half* __restrict__ t1, __half* __restrict__ t2)
{
    int b = blockIdx.x >> 6;
    int k = blockIdx.x & 63;
    int c = threadIdx.x;          // 64 threads
    const float* W = b ? W2 : W1;
    __half* T = b ? t2 : t1;
    T[(size_t)c * 64 + k] = __float2half(W[(size_t)k * 64 + c]);
}

// ---------------- MFMA GEMM (n x 128) @ (128 x C) + fused attn-dot epilogue ----------------
template <int C, int H>
__launch_bounds__(256, 3)
__global__ void gemm_mfma(const __half* __restrict__ Ah, const __half* __restrict__ Wt,
                          const float* __restrict__ al, const float* __restrict__ ar,
                          __half* __restrict__ feat, float* __restrict__ el,
                          float* __restrict__ er, int n)
{
    constexpr int K = 128;
    constexpr int AS = 136;
    constexpr int CT = C / 16;
    __shared__ __half As[64 * AS];
    __shared__ __half Ws[C * AS];

    const int tid = threadIdx.x;
    const int brow = blockIdx.x * 64;

    for (int idx = tid; idx < 64 * 16; idx += 256) {
        int r = idx >> 4, u = idx & 15;
        int gr = brow + r;
        f16x8 v = {0, 0, 0, 0, 0, 0, 0, 0};
        if (gr < n) v = *reinterpret_cast<const f16x8*>(Ah + (size_t)gr * K + u * 8);
        *reinterpret_cast<f16x8*>(&As[r * AS + u * 8]) = v;
    }
    for (int idx = tid; idx < C * 16; idx += 256) {
        int c = idx >> 4, u = idx & 15;
        *reinterpret_cast<f16x8*>(&Ws[c * AS + u * 8]) =
            *reinterpret_cast<const f16x8*>(Wt + (size_t)c * K + u * 8);
    }
    __syncthreads();

    const int w = tid >> 6;
    const int l = tid & 63;
    const int l15 = l & 15;
    const int kg = l >> 4;

    f32x4 acc[CT];
    #pragma unroll
    for (int ct = 0; ct < CT; ++ct) acc[ct] = (f32x4){0.f, 0.f, 0.f, 0.f};

    #pragma unroll
    for (int kt = 0; kt < 4; ++kt) {
        f16x8 a = *reinterpret_cast<const f16x8*>(&As[(w * 16 + l15) * AS + kt * 32 + kg * 8]);
        #pragma unroll
        for (int ct = 0; ct < CT; ++ct) {
            f16x8 b = *reinterpret_cast<const f16x8*>(&Ws[(ct * 16 + l15) * AS + kt * 32 + kg * 8]);
            acc[ct] = __builtin_amdgcn_mfma_f32_16x16x32_f16(a, b, acc[ct], 0, 0, 0);
        }
    }

    const int row0 = w * 16 + kg * 4;
    float pel[4][H], per_[4][H];
    #pragma unroll
    for (int j = 0; j < 4; ++j)
        #pragma unroll
        for (int h = 0; h < H; ++h) { pel[j][h] = 0.f; per_[j][h] = 0.f; }

    #pragma unroll
    for (int ct = 0; ct < CT; ++ct) {
        int col = ct * 16 + l15;
        int head = (H == 2) ? (col >> 6) : 0;
        int lc = col & 63;
        float av = al[head * 64 + lc];
        float rv = ar[head * 64 + lc];
        #pragma unroll
        for (int j = 0; j < 4; ++j) {
            float fv = acc[ct][j];
            int gr = brow + row0 + j;
            if (gr < n) feat[(size_t)gr * C + col] = __float2half(fv);
            pel[j][head] += fv * av;
            per_[j][head] += fv * rv;
        }
    }
    #pragma unroll
    for (int off = 1; off < 16; off <<= 1) {
        #pragma unroll
        for (int j = 0; j < 4; ++j)
            #pragma unroll
            for (int h = 0; h < H; ++h) {
                pel[j][h] += __shfl_xor(pel[j][h], off, 64);
                per_[j][h] += __shfl_xor(per_[j][h], off, 64);
            }
    }
    if (l15 == 0) {
        #pragma unroll
        for (int j = 0; j < 4; ++j) {
            int gr = brow + row0 + j;
            if (gr < n) {
                if constexpr (H == 2) {
                    float2 e0 = make_float2(pel[j][0], pel[j][1]);
                    float2 e1 = make_float2(per_[j][0], per_[j][1]);
                    *reinterpret_cast<float2*>(el + (size_t)gr * 2) = e0;
                    *reinterpret_cast<float2*>(er + (size_t)gr * 2) = e1;
                } else {
                    el[gr] = pel[j][0];
                    er[gr] = per_[j][0];
                }
            }
        }
    }
}

// ---------------- CSR build (by dst), once per launch ----------------
__global__ void hist_dst(const int* __restrict__ dst, int* __restrict__ cnt, int E)
{
    int e = blockIdx.x * blockDim.x + threadIdx.x;
    if (e < E) atomicAdd(&cnt[dst[e]], 1);
}

__global__ void scan_block_sums(const int* __restrict__ cnt, int* __restrict__ bsum, int n)
{
    __shared__ int sh[256];
    int i = blockIdx.x * 256 + threadIdx.x;
    sh[threadIdx.x] = (i < n) ? cnt[i] : 0;
    __syncthreads();
    for (int off = 128; off; off >>= 1) {
        if (threadIdx.x < off) sh[threadIdx.x] += sh[threadIdx.x + off];
        __syncthreads();
    }
    if (threadIdx.x == 0) bsum[blockIdx.x] = sh[0];
}

__global__ void scan_bsum(int* __restrict__ bsum, int nb)
{
    __shared__ int sh[256];
    int t = threadIdx.x;
    sh[t] = (t < nb) ? bsum[t] : 0;
    __syncthreads();
    for (int off = 1; off < 256; off <<= 1) {
        int u = (t >= off) ? sh[t - off] : 0;
        __syncthreads();
        sh[t] += u;
        __syncthreads();
    }
    if (t < nb) bsum[t] = t ? sh[t - 1] : 0;   // exclusive
}

__global__ void scan_final(const int* __restrict__ cnt, const int* __restrict__ bsum,
                           int* __restrict__ rs, int* __restrict__ cursor, int n)
{
    __shared__ int sh[256];
    int t = threadIdx.x;
    int i = blockIdx.x * 256 + t;
    int v = (i < n) ? cnt[i] : 0;
    sh[t] = v;
    __syncthreads();
    for (int off = 1; off < 256; off <<= 1) {
        int u = (t >= off) ? sh[t - off] : 0;
        __syncthreads();
        sh[t] += u;
        __syncthreads();
    }
    int excl = sh[t] - v + bsum[blockIdx.x];
    if (i < n) { rs[i] = excl; cursor[i] = excl; }
    if (i == n - 1) rs[n] = excl + v;
}

__global__ void scatter_csr(const int* __restrict__ src, const int* __restrict__ dst,
                            int* __restrict__ cursor, int* __restrict__ csr, int E)
{
    int e = blockIdx.x * blockDim.x + threadIdx.x;
    if (e < E) {
        int d = dst[e];
        int pos = atomicAdd(&cursor[d], 1);
        csr[pos] = src[e];
    }
}

// ---------------- fused GAT edge-softmax + aggregate (fp16 feat gather) ----------------
template <int C, int H>
__launch_bounds__(256)
__global__ void gat_agg(const int* __restrict__ rs, const int* __restrict__ csr,
                        const float* __restrict__ el, const float* __restrict__ er,
                        const __half* __restrict__ feat, const float* __restrict__ bias,
                        float* __restrict__ outp, int n)
{
    int node = blockIdx.x * 4 + (threadIdx.x >> 6);
    if (node >= n) return;
    int lane = threadIdx.x & 63;
    int start = rs[node], end = rs[node + 1];

    if constexpr (H == 2) {
        float2 e2 = *reinterpret_cast<const float2*>(er + (size_t)node * 2);
        float m0 = -INFINITY, m1 = -INFINITY;
        for (int j = start + lane; j < end; j += 64) {
            int s = csr[j];
            float2 l2 = *reinterpret_cast<const float2*>(el + (size_t)s * 2);
            float v0 = l2.x + e2.x; v0 = v0 >= 0.f ? v0 : 0.2f * v0;
            float v1 = l2.y + e2.y; v1 = v1 >= 0.f ? v1 : 0.2f * v1;
            m0 = fmaxf(m0, v0); m1 = fmaxf(m1, v1);
        }
        #pragma unroll
        for (int off = 32; off; off >>= 1) {
            m0 = fmaxf(m0, __shfl_xor(m0, off, 64));
            m1 = fmaxf(m1, __shfl_xor(m1, off, 64));
        }
        const int slot = lane >> 4;
        const int cl = lane & 15;
        const int h = cl >> 3;
        const float mh = h ? m1 : m0;
        const float erh = h ? e2.y : e2.x;
        float ssum = 0.f;
        float acc[8];
        #pragma unroll
        for (int u = 0; u < 8; ++u) acc[u] = 0.f;
        for (int j = start + slot; j < end; j += 4) {
            int s = csr[j];
            float v = el[(size_t)s * 2 + h] + erh;
            v = v >= 0.f ? v : 0.2f * v;
            float p = __expf(v - mh);
            ssum += p;
            float4 raw = *reinterpret_cast<const float4*>(feat + (size_t)s * C + cl * 8);
            const __half2* hp = reinterpret_cast<const __half2*>(&raw);
            #pragma unroll
            for (int u = 0; u < 4; ++u) {
                float2 f2 = __half22float2(hp[u]);
                acc[2 * u]     = fmaf(p, f2.x, acc[2 * u]);
                acc[2 * u + 1] = fmaf(p, f2.y, acc[2 * u + 1]);
            }
        }
        #pragma unroll
        for (int off = 16; off <= 32; off <<= 1) {
            ssum += __shfl_xor(ssum, off, 64);
            #pragma unroll
            for (int u = 0; u < 8; ++u) acc[u] += __shfl_xor(acc[u], off, 64);
        }
        if (slot == 0) {
            float r = 1.f / fmaxf(ssum, 1e-9f);
            float4 o0 = make_float4(acc[0] * r, acc[1] * r, acc[2] * r, acc[3] * r);
            float4 o1 = make_float4(acc[4] * r, acc[5] * r, acc[6] * r, acc[7] * r);
            *reinterpret_cast<float4*>(outp + (size_t)node * C + cl * 8) = o0;
            *reinterpret_cast<float4*>(outp + (size_t)node * C + cl * 8 + 4) = o1;
        }
    } else {
        float er0 = er[node];
        float m0 = -INFINITY;
        for (int j = start + lane; j < end; j += 64) {
            int s = csr[j];
            float v = el[s] + er0;
            v = v >= 0.f ? v : 0.2f * v;
            m0 = fmaxf(m0, v);
        }
        #pragma unroll
        for (int off = 32; off; off >>= 1)
            m0 = fmaxf(m0, __shfl_xor(m0, off, 64));
        const int slot = lane >> 3;
        const int cl = lane & 7;
        float ssum = 0.f;
        float acc[8];
        #pragma unroll
        for (int u = 0; u < 8; ++u) acc[u] = 0.f;
        for (int j = start + slot; j < end; j += 8) {
            int s = csr[j];
            float v = el[s] + er0;
            v = v >= 0.f ? v : 0.2f * v;
            float p = __expf(v - m0);
            ssum += p;
            float4 raw = *reinterpret_cast<const float4*>(feat + (size_t)s * C + cl * 8);
            const __half2* hp = reinterpret_cast<const __half2*>(&raw);
            #pragma unroll
            for (int u = 0; u < 4; ++u) {
                float2 f2 = __half22float2(hp[u]);
                acc[2 * u]     = fmaf(p, f2.x, acc[2 * u]);
                acc[2 * u + 1] = fmaf(p, f2.y, acc[2 * u + 1]);
            }
        }
        #pragma unroll
        for (int off = 8; off <= 32; off <<= 1) {
            ssum += __shfl_xor(ssum, off, 64);
            #pragma unroll
            for (int u = 0; u < 8; ++u) acc[u] += __shfl_xor(acc[u], off, 64);
        }
        if (slot == 0) {
            float r = 1.f / fmaxf(ssum, 1e-9f);
            float4 o0, o1;
            o0.x = acc[0] * r + bias[cl * 8 + 0];
            o0.y = acc[1] * r + bias[cl * 8 + 1];
            o0.z = acc[2] * r + bias[cl * 8 + 2];
            o0.w = acc[3] * r + bias[cl * 8 + 3];
            o1.x = acc[4] * r + bias[cl * 8 + 4];
            o1.y = acc[5] * r + bias[cl * 8 + 5];
            o1.z = acc[6] * r + bias[cl * 8 + 6];
            o1.w = acc[7] * r + bias[cl * 8 + 7];
            *reinterpret_cast<float4*>(outp + (size_t)node * C + cl * 8) = o0;
            *reinterpret_cast<float4*>(outp + (size_t)node * C + cl * 8 + 4) = o1;
        }
    }
}

// ---------------- BatchNorm stats (C=128) ----------------
__global__ void bn_stats(const float* __restrict__ h, float* __restrict__ sums, int n)
{
    __shared__ float s1[256], s2[256];
    int c = threadIdx.x & 127, half = threadIdx.x >> 7;
    float ls = 0.f, lq = 0.f;
    for (int r = blockIdx.x * 2 + half; r < n; r += gridDim.x * 2) {
        float v = h[(size_t)r * 128 + c];
        ls += v; lq += v * v;
    }
    s1[threadIdx.x] = ls; s2[threadIdx.x] = lq;
    __syncthreads();
    if (threadIdx.x < 128) {
        atomicAdd(&sums[c], s1[threadIdx.x] + s1[threadIdx.x + 128]);
        atomicAdd(&sums[128 + c], s2[threadIdx.x] + s2[threadIdx.x + 128]);
    }
}

// ---------------- BN apply + ReLU -> fp16 ----------------
__global__ void bn_apply(const float* __restrict__ in, __half* __restrict__ outp,
                         const float* __restrict__ sums,
                         const float* __restrict__ g, const float* __restrict__ b,
                         long long npairs)
{
    long long i = (long long)blockIdx.x * blockDim.x + threadIdx.x;
    if (i >= npairs) return;
    int c0 = (int)((i * 2) & 127);
    const float invN = 1.f / (float)N_NODES;
    float2 v = *reinterpret_cast<const float2*>(in + i * 2);
    float mean0 = sums[c0] * invN, mean1 = sums[c0 + 1] * invN;
    float var0 = sums[128 + c0] * invN - mean0 * mean0;
    float var1 = sums[128 + c0 + 1] * invN - mean1 * mean1;
    float o0 = fmaxf((v.x - mean0) * rsqrtf(var0 + 1e-5f) * g[c0] + b[c0], 0.f);
    float o1 = fmaxf((v.y - mean1) * rsqrtf(var1 + 1e-5f) * g[c0 + 1] + b[c0 + 1], 0.f);
    *reinterpret_cast<__half2*>(outp + i * 2) = __floats2half2_rn(o0, o1);
}

// ---------------- predictor v4: MFMA batched MLP, 64 pairs per block ----------------
// zt[p][72] fp16 holds z then (in place, row-exclusive per wave) a1.
// W1t/W2t fp16 [c][k]. Wave w owns pair-rows w*16..w*16+15; 8 MFMA per layer.
__launch_bounds__(256, 5)
__global__ void predictor(const __half* __restrict__ h16,
                          const int* __restrict__ ps, const int* __restrict__ pd,
                          const int* __restrict__ ns, const int* __restrict__ nd,
                          const __half* __restrict__ W1t, const float* __restrict__ b1,
                          const __half* __restrict__ W2t, const float* __restrict__ b2,
                          const float* __restrict__ W3, const float* __restrict__ b3,
                          float* __restrict__ out, int P)
{
    constexpr int AS = 72;            // halves/row: 144B, 16B-aligned
    __shared__ __half zt[64 * AS];    // 9.2 KB
    __shared__ __half w1s[64 * AS];
    __shared__ __half w2s[64 * AS];
    const int tid = threadIdx.x;

    // stage weights (64 rows x 64 halves each)
    for (int idx = tid; idx < 512; idx += 256) {
        int c = idx >> 3, u = idx & 7;
        *reinterpret_cast<f16x8*>(&w1s[c * AS + u * 8]) =
            *reinterpret_cast<const f16x8*>(W1t + (size_t)c * 64 + u * 8);
        *reinterpret_cast<f16x8*>(&w2s[c * AS + u * 8]) =
            *reinterpret_cast<const f16x8*>(W2t + (size_t)c * 64 + u * 8);
    }

    // phase 1: z[p][c] = h[s][c]*h[d][c] (fp16 packed mul), p = tid>>2, 16 ch per thread
    {
        int p = tid >> 2, q = tid & 3;
        int gp = blockIdx.x * 64 + p;
        int s, d;
        if (gp < P) { s = ps[gp]; d = pd[gp]; }
        else        { s = ns[gp - P]; d = nd[gp - P]; }
        const f16x8* hs = reinterpret_cast<const f16x8*>(h16 + (size_t)s * 64 + q * 16);
        const f16x8* hd = reinterpret_cast<const f16x8*>(h16 + (size_t)d * 64 + q * 16);
        #pragma unroll
        for (int u = 0; u < 2; ++u) {
            f16x8 z = hs[u] * hd[u];
            *reinterpret_cast<f16x8*>(&zt[p * AS + q * 16 + u * 8]) = z;
        }
    }
    __syncthreads();

    const int w = tid >> 6;
    const int l = tid & 63;
    const int l15 = l & 15;
    const int kg = l >> 4;
    const int myrow = (w * 16 + l15) * AS;

    // ---- layer 1 ----
    f32x4 acc[4];
    {
        f16x8 a0 = *reinterpret_cast<const f16x8*>(&zt[myrow + kg * 8]);
        f16x8 a1 = *reinterpret_cast<const f16x8*>(&zt[myrow + 32 + kg * 8]);
        #pragma unroll
        for (int nt = 0; nt < 4; ++nt) {
            f16x8 b0 = *reinterpret_cast<const f16x8*>(&w1s[(nt * 16 + l15) * AS + kg * 8]);
            f16x8 b1v = *reinterpret_cast<const f16x8*>(&w1s[(nt * 16 + l15) * AS + 32 + kg * 8]);
            acc[nt] = __builtin_amdgcn_mfma_f32_16x16x32_f16(a0, b0, (f32x4){0.f, 0.f, 0.f, 0.f}, 0, 0, 0);
            acc[nt] = __builtin_amdgcn_mfma_f32_16x16x32_f16(a1, b1v, acc[nt], 0, 0, 0);
        }
    }
    // relu + bias, write a1 back into zt (own rows only)
    {
        #pragma unroll
        for (int nt = 0; nt < 4; ++nt) {
            float bb = b1[nt * 16 + l15];
            #pragma unroll
            for (int j = 0; j < 4; ++j) {
                float v = fmaxf(acc[nt][j] + bb, 0.f);
                zt[(w * 16 + kg * 4 + j) * AS + nt * 16 + l15] = __float2half(v);
            }
        }
    }
    __syncthreads();

    // ---- layer 2 + w3 dot ----
    {
        f16x8 a0 = *reinterpret_cast<const f16x8*>(&zt[myrow + kg * 8]);
        f16x8 a1 = *reinterpret_cast<const f16x8*>(&zt[myrow + 32 + kg * 8]);
        #pragma unroll
        for (int nt = 0; nt < 4; ++nt) {
            f16x8 b0 = *reinterpret_cast<const f16x8*>(&w2s[(nt * 16 + l15) * AS + kg * 8]);
            f16x8 b1v = *reinterpret_cast<const f16x8*>(&w2s[(nt * 16 + l15) * AS + 32 + kg * 8]);
            acc[nt] = __builtin_amdgcn_mfma_f32_16x16x32_f16(a0, b0, (f32x4){0.f, 0.f, 0.f, 0.f}, 0, 0, 0);
            acc[nt] = __builtin_amdgcn_mfma_f32_16x16x32_f16(a1, b1v, acc[nt], 0, 0, 0);
        }
    }
    float part[4] = {0.f, 0.f, 0.f, 0.f};
    #pragma unroll
    for (int nt = 0; nt < 4; ++nt) {
        float bb = b2[nt * 16 + l15];
        float wv = W3[nt * 16 + l15];
        #pragma unroll
        for (int j = 0; j < 4; ++j)
            part[j] += fmaxf(acc[nt][j] + bb, 0.f) * wv;
    }
    #pragma unroll
    for (int off = 1; off < 16; off <<= 1) {
        #pragma unroll
        for (int j = 0; j < 4; ++j)
            part[j] += __shfl_xor(part[j], off, 16);
    }
    if (l15 == 0) {
        const float b3v = b3[0];
        int gp0 = blockIdx.x * 64 + w * 16 + kg * 4;
        #pragma unroll
        for (int j = 0; j < 4; ++j)
            out[gp0 + j] = part[j] + b3v;
    }
}

extern "C" void kernel_launch(void* const* d_in, const int* in_sizes, int n_in,
                              void* d_out, int out_size, void* d_ws, size_t ws_size,
                              hipStream_t stream)
{
    const float* x    = (const float*)d_in[0];
    const int* es     = (const int*)d_in[1];
    const int* ed     = (const int*)d_in[2];
    const int* ps     = (const int*)d_in[3];
    const int* pdst   = (const int*)d_in[4];
    const int* ns     = (const int*)d_in[5];
    const int* nd     = (const int*)d_in[6];
    const float* W0   = (const float*)d_in[7];
    const float* al0  = (const float*)d_in[8];
    const float* ar0  = (const float*)d_in[9];
    const float* W1   = (const float*)d_in[11];
    const float* al1  = (const float*)d_in[12];
    const float* ar1  = (const float*)d_in[13];
    const float* W2   = (const float*)d_in[15];
    const float* al2  = (const float*)d_in[16];
    const float* ar2  = (const float*)d_in[17];
    const float* b2   = (const float*)d_in[18];
    const float* bn0g = (const float*)d_in[19];
    const float* bn0b = (const float*)d_in[20];
    const float* bn1g = (const float*)d_in[21];
    const float* bn1b = (const float*)d_in[22];
    const float* pW1  = (const float*)d_in[23];
    const float* pb1  = (const float*)d_in[24];
    const float* pW2  = (const float*)d_in[25];
    const float* pb2  = (const float*)d_in[26];
    const float* pW3  = (const float*)d_in[27];
    const float* pb3  = (const float*)d_in[28];
    float* out = (float*)d_out;

    float* ws = (float*)d_ws;
    size_t off = 0;
    auto alloc = [&](size_t nelem) {
        float* p = ws + off;
        off += (nelem + 63) & ~(size_t)63;
        return p;
    };
    __half* featb = (__half*)alloc((size_t)N_NODES * 64);   // N x 128 halfs
    __half* xh    = (__half*)alloc((size_t)N_NODES * 64);   // fp16 activations
    float* hb    = alloc((size_t)N_NODES * 128);
    __half* wt0  = (__half*)alloc(128 * 64);
    __half* wt1  = (__half*)alloc(128 * 64);
    __half* wt2  = (__half*)alloc(64 * 64);
    __half* pwt1 = (__half*)alloc(64 * 32);                 // 64x64 halfs
    __half* pwt2 = (__half*)alloc(64 * 32);
    float* el    = alloc((size_t)N_NODES * 2);
    float* er    = alloc((size_t)N_NODES * 2);
    float* bns   = alloc(256);
    int* cnt     = (int*)alloc(N_NODES);
    int* rs      = (int*)alloc(N_NODES + 1);
    int* cursor  = (int*)alloc(N_NODES);
    int* bsum    = (int*)alloc(256);
    int* csr     = (int*)alloc(N_EDGES);

    dim3 blk(256);
    const int gemmGrid = (N_NODES + 63) / 64;
    const int edgeGrid = (N_EDGES + 255) / 256;
    const int nodeBlocks = (N_NODES + 255) / 256;
    const int aggGrid = (N_NODES + 3) / 4;
    const long long bnPairs = (long long)N_NODES * 64;

    // ================= CSR build + fp16 prep =================
    hipMemsetAsync(cnt, 0, (size_t)N_NODES * sizeof(int), stream);
    hist_dst<<<edgeGrid, blk, 0, stream>>>(ed, cnt, N_EDGES);
    scan_block_sums<<<nodeBlocks, blk, 0, stream>>>(cnt, bsum, N_NODES);
    scan_bsum<<<1, blk, 0, stream>>>(bsum, nodeBlocks);
    scan_final<<<nodeBlocks, blk, 0, stream>>>(cnt, bsum, rs, cursor, N_NODES);
    scatter_csr<<<edgeGrid, blk, 0, stream>>>(es, ed, cursor, csr, N_EDGES);
    f32_to_f16<<<2048, blk, 0, stream>>>(x, xh, N_NODES * 32);
    prep_wt<<<384, dim3(128), 0, stream>>>(W0, W1, W2, wt0, wt1, wt2);
    prep_pwt<<<128, dim3(64), 0, stream>>>(pW1, pW2, pwt1, pwt2);

    // ================= layer 0 (C=128, H=2) =================
    gemm_mfma<128, 2><<<gemmGrid, blk, 0, stream>>>(xh, wt0, al0, ar0, featb, el, er, N_NODES);
    gat_agg<128, 2><<<aggGrid, blk, 0, stream>>>(rs, csr, el, er, featb, nullptr, hb, N_NODES);
    hipMemsetAsync(bns, 0, 256 * sizeof(float), stream);
    bn_stats<<<256, blk, 0, stream>>>(hb, bns, N_NODES);
    bn_apply<<<(int)((bnPairs + 255) / 256), blk, 0, stream>>>(hb, xh, bns, bn0g, bn0b, bnPairs);

    // ================= layer 1 (C=128, H=2) =================
    gemm_mfma<128, 2><<<gemmGrid, blk, 0, stream>>>(xh, wt1, al1, ar1, featb, el, er, N_NODES);
    gat_agg<128, 2><<<aggGrid, blk, 0, stream>>>(rs, csr, el, er, featb, nullptr, hb, N_NODES);
    hipMemsetAsync(bns, 0, 256 * sizeof(float), stream);
    bn_stats<<<256, blk, 0, stream>>>(hb, bns, N_NODES);
    bn_apply<<<(int)((bnPairs + 255) / 256), blk, 0, stream>>>(hb, xh, bns, bn1g, bn1b, bnPairs);

    // ================= layer 2 (C=64, H=1) =================
    gemm_mfma<64, 1><<<gemmGrid, blk, 0, stream>>>(xh, wt2, al2, ar2, featb, el, er, N_NODES);
    gat_agg<64, 1><<<aggGrid, blk, 0, stream>>>(rs, csr, el, er, featb, b2, hb, N_NODES);

    // ================= predictor (h -> fp16, then MFMA MLP) =================
    f32_to_f16<<<2048, blk, 0, stream>>>(hb, xh, N_NODES * 16);
    predictor<<<3125, blk, 0, stream>>>(xh, ps, pdst, ns, nd,
                                        pwt1, pb1, pwt2, pb2, pW3, pb3, out, 100000);
}

// Round 9
// 449.660 us; speedup vs baseline: 11.2266x; 1.0399x over previous
//
#include <hip/hip_runtime.h>
#include <hip/hip_fp16.h>
#include <cstdint>
#include <cstddef>

#define N_NODES 50000
#define N_EDGES 800000

typedef _Float16 f16x8 __attribute__((ext_vector_type(8)));
typedef float f32x4 __attribute__((ext_vector_type(4)));

// ---------------- f32 -> f16 convert ----------------
__global__ void f32_to_f16(const float* __restrict__ in, __half* __restrict__ outp, int n4)
{
    int i = blockIdx.x * blockDim.x + threadIdx.x;
    int stride = gridDim.x * blockDim.x;
    for (; i < n4; i += stride) {
        float4 v = *reinterpret_cast<const float4*>(in + (size_t)i * 4);
        __half2 a = __floats2half2_rn(v.x, v.y);
        __half2 b = __floats2half2_rn(v.z, v.w);
        uint2 pk;
        pk.x = *reinterpret_cast<unsigned*>(&a);
        pk.y = *reinterpret_cast<unsigned*>(&b);
        *reinterpret_cast<uint2*>(outp + (size_t)i * 4) = pk;
    }
}

// ---------------- W -> Wt[c][k] fp16 pre-transpose (GAT layers) ----------------
__global__ void prep_wt(const float* __restrict__ W0, const float* __restrict__ W1,
                        const float* __restrict__ W2, __half* __restrict__ t0,
                        __half* __restrict__ t1, __half* __restrict__ t2)
{
    int b = blockIdx.x >> 7;
    int k = blockIdx.x & 127;
    int c = threadIdx.x;
    const float* W = (b == 0) ? W0 : (b == 1) ? W1 : W2;
    __half* T = (b == 0) ? t0 : (b == 1) ? t1 : t2;
    int Cb = (b == 2) ? 64 : 128;
    if (c < Cb) T[(size_t)c * 128 + k] = __float2half(W[(size_t)k * Cb + c]);
}

// ---------------- predictor weights -> [c][k] fp16 (64x64 each) ----------------
__global__ void prep_pwt(const float* __restrict__ W1, const float* __restrict__ W2,
                         __half* __restrict__ t1, __half* __restrict__ t2)
{
    int b = blockIdx.x >> 6;
    int k = blockIdx.x & 63;
    int c = threadIdx.x;          // 64 threads
    const float* W = b ? W2 : W1;
    __half* T = b ? t2 : t1;
    T[(size_t)c * 64 + k] = __float2half(W[(size_t)k * 64 + c]);
}

// ---------------- MFMA GEMM (n x 128) @ (128 x C) + fused attn-dot epilogue ----------------
template <int C, int H>
__launch_bounds__(256, 3)
__global__ void gemm_mfma(const __half* __restrict__ Ah, const __half* __restrict__ Wt,
                          const float* __restrict__ al, const float* __restrict__ ar,
                          __half* __restrict__ feat, float* __restrict__ el,
                          float* __restrict__ er, int n)
{
    constexpr int K = 128;
    constexpr int AS = 136;
    constexpr int CT = C / 16;
    __shared__ __half As[64 * AS];
    __shared__ __half Ws[C * AS];

    const int tid = threadIdx.x;
    const int brow = blockIdx.x * 64;

    for (int idx = tid; idx < 64 * 16; idx += 256) {
        int r = idx >> 4, u = idx & 15;
        int gr = brow + r;
        f16x8 v = {0, 0, 0, 0, 0, 0, 0, 0};
        if (gr < n) v = *reinterpret_cast<const f16x8*>(Ah + (size_t)gr * K + u * 8);
        *reinterpret_cast<f16x8*>(&As[r * AS + u * 8]) = v;
    }
    for (int idx = tid; idx < C * 16; idx += 256) {
        int c = idx >> 4, u = idx & 15;
        *reinterpret_cast<f16x8*>(&Ws[c * AS + u * 8]) =
            *reinterpret_cast<const f16x8*>(Wt + (size_t)c * K + u * 8);
    }
    __syncthreads();

    const int w = tid >> 6;
    const int l = tid & 63;
    const int l15 = l & 15;
    const int kg = l >> 4;

    f32x4 acc[CT];
    #pragma unroll
    for (int ct = 0; ct < CT; ++ct) acc[ct] = (f32x4){0.f, 0.f, 0.f, 0.f};

    #pragma unroll
    for (int kt = 0; kt < 4; ++kt) {
        f16x8 a = *reinterpret_cast<const f16x8*>(&As[(w * 16 + l15) * AS + kt * 32 + kg * 8]);
        #pragma unroll
        for (int ct = 0; ct < CT; ++ct) {
            f16x8 b = *reinterpret_cast<const f16x8*>(&Ws[(ct * 16 + l15) * AS + kt * 32 + kg * 8]);
            acc[ct] = __builtin_amdgcn_mfma_f32_16x16x32_f16(a, b, acc[ct], 0, 0, 0);
        }
    }

    const int row0 = w * 16 + kg * 4;
    float pel[4][H], per_[4][H];
    #pragma unroll
    for (int j = 0; j < 4; ++j)
        #pragma unroll
        for (int h = 0; h < H; ++h) { pel[j][h] = 0.f; per_[j][h] = 0.f; }

    #pragma unroll
    for (int ct = 0; ct < CT; ++ct) {
        int col = ct * 16 + l15;
        int head = (H == 2) ? (col >> 6) : 0;
        int lc = col & 63;
        float av = al[head * 64 + lc];
        float rv = ar[head * 64 + lc];
        #pragma unroll
        for (int j = 0; j < 4; ++j) {
            float fv = acc[ct][j];
            int gr = brow + row0 + j;
            if (gr < n) feat[(size_t)gr * C + col] = __float2half(fv);
            pel[j][head] += fv * av;
            per_[j][head] += fv * rv;
        }
    }
    #pragma unroll
    for (int off = 1; off < 16; off <<= 1) {
        #pragma unroll
        for (int j = 0; j < 4; ++j)
            #pragma unroll
            for (int h = 0; h < H; ++h) {
                pel[j][h] += __shfl_xor(pel[j][h], off, 64);
                per_[j][h] += __shfl_xor(per_[j][h], off, 64);
            }
    }
    if (l15 == 0) {
        #pragma unroll
        for (int j = 0; j < 4; ++j) {
            int gr = brow + row0 + j;
            if (gr < n) {
                if constexpr (H == 2) {
                    float2 e0 = make_float2(pel[j][0], pel[j][1]);
                    float2 e1 = make_float2(per_[j][0], per_[j][1]);
                    *reinterpret_cast<float2*>(el + (size_t)gr * 2) = e0;
                    *reinterpret_cast<float2*>(er + (size_t)gr * 2) = e1;
                } else {
                    el[gr] = pel[j][0];
                    er[gr] = per_[j][0];
                }
            }
        }
    }
}

// ---------------- CSR build (by dst), once per launch; 4 edges/thread ILP ----------------
__global__ void hist_dst(const int* __restrict__ dst, int* __restrict__ cnt, int E)
{
    int base = (blockIdx.x * blockDim.x + threadIdx.x) * 4;
    if (base + 3 < E) {
        int4 d = *reinterpret_cast<const int4*>(dst + base);
        atomicAdd(&cnt[d.x], 1);
        atomicAdd(&cnt[d.y], 1);
        atomicAdd(&cnt[d.z], 1);
        atomicAdd(&cnt[d.w], 1);
    } else {
        for (int e = base; e < E; ++e) atomicAdd(&cnt[dst[e]], 1);
    }
}

__global__ void scan_block_sums(const int* __restrict__ cnt, int* __restrict__ bsum, int n)
{
    __shared__ int sh[256];
    int i = blockIdx.x * 256 + threadIdx.x;
    sh[threadIdx.x] = (i < n) ? cnt[i] : 0;
    __syncthreads();
    for (int off = 128; off; off >>= 1) {
        if (threadIdx.x < off) sh[threadIdx.x] += sh[threadIdx.x + off];
        __syncthreads();
    }
    if (threadIdx.x == 0) bsum[blockIdx.x] = sh[0];
}

__global__ void scan_bsum(int* __restrict__ bsum, int nb)
{
    __shared__ int sh[256];
    int t = threadIdx.x;
    sh[t] = (t < nb) ? bsum[t] : 0;
    __syncthreads();
    for (int off = 1; off < 256; off <<= 1) {
        int u = (t >= off) ? sh[t - off] : 0;
        __syncthreads();
        sh[t] += u;
        __syncthreads();
    }
    if (t < nb) bsum[t] = t ? sh[t - 1] : 0;   // exclusive
}

__global__ void scan_final(const int* __restrict__ cnt, const int* __restrict__ bsum,
                           int* __restrict__ rs, int* __restrict__ cursor, int n)
{
    __shared__ int sh[256];
    int t = threadIdx.x;
    int i = blockIdx.x * 256 + t;
    int v = (i < n) ? cnt[i] : 0;
    sh[t] = v;
    __syncthreads();
    for (int off = 1; off < 256; off <<= 1) {
        int u = (t >= off) ? sh[t - off] : 0;
        __syncthreads();
        sh[t] += u;
        __syncthreads();
    }
    int excl = sh[t] - v + bsum[blockIdx.x];
    if (i < n) { rs[i] = excl; cursor[i] = excl; }
    if (i == n - 1) rs[n] = excl + v;
}

__global__ void scatter_csr(const int* __restrict__ src, const int* __restrict__ dst,
                            int* __restrict__ cursor, int* __restrict__ csr, int E)
{
    int base = (blockIdx.x * blockDim.x + threadIdx.x) * 4;
    if (base + 3 < E) {
        int4 d = *reinterpret_cast<const int4*>(dst + base);
        int4 s = *reinterpret_cast<const int4*>(src + base);
        int p0 = atomicAdd(&cursor[d.x], 1);
        int p1 = atomicAdd(&cursor[d.y], 1);
        int p2 = atomicAdd(&cursor[d.z], 1);
        int p3 = atomicAdd(&cursor[d.w], 1);
        csr[p0] = s.x; csr[p1] = s.y; csr[p2] = s.z; csr[p3] = s.w;
    } else {
        for (int e = base; e < E; ++e) {
            int pos = atomicAdd(&cursor[dst[e]], 1);
            csr[pos] = src[e];
        }
    }
}

// ---------------- fused GAT edge-softmax + aggregate, single-pass ----------------
// Softmax shift-invariance: alpha = exp(e)/sum(exp(e)) — no segment max needed
// (scores bounded ~|8| here; f32 exp safe). fp16 feat gather, fp16 output + fused bias.
template <int C, int H>
__launch_bounds__(256)
__global__ void gat_agg(const int* __restrict__ rs, const int* __restrict__ csr,
                        const float* __restrict__ el, const float* __restrict__ er,
                        const __half* __restrict__ feat, const float* __restrict__ bias,
                        __half* __restrict__ outp, int n)
{
    int node = blockIdx.x * 4 + (threadIdx.x >> 6);
    if (node >= n) return;
    int lane = threadIdx.x & 63;
    int start = rs[node], end = rs[node + 1];

    if constexpr (H == 2) {
        const int slot = lane >> 4;     // 4 edge slots
        const int cl = lane & 15;       // channel group (8 ch)
        const int h = cl >> 3;
        const float erh = er[(size_t)node * 2 + h];
        float ssum = 0.f;
        float acc[8];
        #pragma unroll
        for (int u = 0; u < 8; ++u) acc[u] = 0.f;
        for (int j = start + slot; j < end; j += 4) {
            int s = csr[j];
            float v = el[(size_t)s * 2 + h] + erh;
            v = v >= 0.f ? v : 0.2f * v;
            float p = __expf(v);
            ssum += p;
            float4 raw = *reinterpret_cast<const float4*>(feat + (size_t)s * C + cl * 8);
            const __half2* hp = reinterpret_cast<const __half2*>(&raw);
            #pragma unroll
            for (int u = 0; u < 4; ++u) {
                float2 f2 = __half22float2(hp[u]);
                acc[2 * u]     = fmaf(p, f2.x, acc[2 * u]);
                acc[2 * u + 1] = fmaf(p, f2.y, acc[2 * u + 1]);
            }
        }
        #pragma unroll
        for (int off = 16; off <= 32; off <<= 1) {
            ssum += __shfl_xor(ssum, off, 64);
            #pragma unroll
            for (int u = 0; u < 8; ++u) acc[u] += __shfl_xor(acc[u], off, 64);
        }
        if (slot == 0) {
            float r = 1.f / fmaxf(ssum, 1e-9f);
            f16x8 o;
            #pragma unroll
            for (int u = 0; u < 8; ++u) o[u] = (_Float16)(acc[u] * r);
            *reinterpret_cast<f16x8*>(outp + (size_t)node * C + cl * 8) = o;
        }
    } else {
        const int slot = lane >> 3;     // 8 edge slots
        const int cl = lane & 7;        // channel group (8 ch)
        const float er0 = er[node];
        float ssum = 0.f;
        float acc[8];
        #pragma unroll
        for (int u = 0; u < 8; ++u) acc[u] = 0.f;
        for (int j = start + slot; j < end; j += 8) {
            int s = csr[j];
            float v = el[s] + er0;
            v = v >= 0.f ? v : 0.2f * v;
            float p = __expf(v);
            ssum += p;
            float4 raw = *reinterpret_cast<const float4*>(feat + (size_t)s * C + cl * 8);
            const __half2* hp = reinterpret_cast<const __half2*>(&raw);
            #pragma unroll
            for (int u = 0; u < 4; ++u) {
                float2 f2 = __half22float2(hp[u]);
                acc[2 * u]     = fmaf(p, f2.x, acc[2 * u]);
                acc[2 * u + 1] = fmaf(p, f2.y, acc[2 * u + 1]);
            }
        }
        #pragma unroll
        for (int off = 8; off <= 32; off <<= 1) {
            ssum += __shfl_xor(ssum, off, 64);
            #pragma unroll
            for (int u = 0; u < 8; ++u) acc[u] += __shfl_xor(acc[u], off, 64);
        }
        if (slot == 0) {
            float r = 1.f / fmaxf(ssum, 1e-9f);
            f16x8 o;
            #pragma unroll
            for (int u = 0; u < 8; ++u) o[u] = (_Float16)(acc[u] * r + bias[cl * 8 + u]);
            *reinterpret_cast<f16x8*>(outp + (size_t)node * C + cl * 8) = o;
        }
    }
}

// ---------------- BatchNorm stats (C=128), fp16 input ----------------
__global__ void bn_stats(const __half* __restrict__ h, float* __restrict__ sums, int n)
{
    __shared__ float s1[256], s2[256];
    int c = threadIdx.x & 127, half = threadIdx.x >> 7;
    float ls = 0.f, lq = 0.f;
    for (int r = blockIdx.x * 2 + half; r < n; r += gridDim.x * 2) {
        float v = __half2float(h[(size_t)r * 128 + c]);
        ls += v; lq += v * v;
    }
    s1[threadIdx.x] = ls; s2[threadIdx.x] = lq;
    __syncthreads();
    if (threadIdx.x < 128) {
        atomicAdd(&sums[c], s1[threadIdx.x] + s1[threadIdx.x + 128]);
        atomicAdd(&sums[128 + c], s2[threadIdx.x] + s2[threadIdx.x + 128]);
    }
}

// ---------------- BN apply + ReLU, fp16 -> fp16 ----------------
__global__ void bn_apply(const __half* __restrict__ in, __half* __restrict__ outp,
                         const float* __restrict__ sums,
                         const float* __restrict__ g, const float* __restrict__ b,
                         long long npairs)
{
    long long i = (long long)blockIdx.x * blockDim.x + threadIdx.x;
    if (i >= npairs) return;
    int c0 = (int)((i * 2) & 127);
    const float invN = 1.f / (float)N_NODES;
    __half2 v2 = *reinterpret_cast<const __half2*>(in + i * 2);
    float2 v = __half22float2(v2);
    float mean0 = sums[c0] * invN, mean1 = sums[c0 + 1] * invN;
    float var0 = sums[128 + c0] * invN - mean0 * mean0;
    float var1 = sums[128 + c0 + 1] * invN - mean1 * mean1;
    float o0 = fmaxf((v.x - mean0) * rsqrtf(var0 + 1e-5f) * g[c0] + b[c0], 0.f);
    float o1 = fmaxf((v.y - mean1) * rsqrtf(var1 + 1e-5f) * g[c0 + 1] + b[c0 + 1], 0.f);
    *reinterpret_cast<__half2*>(outp + i * 2) = __floats2half2_rn(o0, o1);
}

// ---------------- predictor: MFMA batched MLP, 64 pairs per block ----------------
__launch_bounds__(256, 5)
__global__ void predictor(const __half* __restrict__ h16,
                          const int* __restrict__ ps, const int* __restrict__ pd,
                          const int* __restrict__ ns, const int* __restrict__ nd,
                          const __half* __restrict__ W1t, const float* __restrict__ b1,
                          const __half* __restrict__ W2t, const float* __restrict__ b2,
                          const float* __restrict__ W3, const float* __restrict__ b3,
                          float* __restrict__ out, int P)
{
    constexpr int AS = 72;
    __shared__ __half zt[64 * AS];
    __shared__ __half w1s[64 * AS];
    __shared__ __half w2s[64 * AS];
    const int tid = threadIdx.x;

    for (int idx = tid; idx < 512; idx += 256) {
        int c = idx >> 3, u = idx & 7;
        *reinterpret_cast<f16x8*>(&w1s[c * AS + u * 8]) =
            *reinterpret_cast<const f16x8*>(W1t + (size_t)c * 64 + u * 8);
        *reinterpret_cast<f16x8*>(&w2s[c * AS + u * 8]) =
            *reinterpret_cast<const f16x8*>(W2t + (size_t)c * 64 + u * 8);
    }

    {
        int p = tid >> 2, q = tid & 3;
        int gp = blockIdx.x * 64 + p;
        int s, d;
        if (gp < P) { s = ps[gp]; d = pd[gp]; }
        else        { s = ns[gp - P]; d = nd[gp - P]; }
        const f16x8* hs = reinterpret_cast<const f16x8*>(h16 + (size_t)s * 64 + q * 16);
        const f16x8* hd = reinterpret_cast<const f16x8*>(h16 + (size_t)d * 64 + q * 16);
        #pragma unroll
        for (int u = 0; u < 2; ++u) {
            f16x8 z = hs[u] * hd[u];
            *reinterpret_cast<f16x8*>(&zt[p * AS + q * 16 + u * 8]) = z;
        }
    }
    __syncthreads();

    const int w = tid >> 6;
    const int l = tid & 63;
    const int l15 = l & 15;
    const int kg = l >> 4;
    const int myrow = (w * 16 + l15) * AS;

    f32x4 acc[4];
    {
        f16x8 a0 = *reinterpret_cast<const f16x8*>(&zt[myrow + kg * 8]);
        f16x8 a1 = *reinterpret_cast<const f16x8*>(&zt[myrow + 32 + kg * 8]);
        #pragma unroll
        for (int nt = 0; nt < 4; ++nt) {
            f16x8 b0 = *reinterpret_cast<const f16x8*>(&w1s[(nt * 16 + l15) * AS + kg * 8]);
            f16x8 b1v = *reinterpret_cast<const f16x8*>(&w1s[(nt * 16 + l15) * AS + 32 + kg * 8]);
            acc[nt] = __builtin_amdgcn_mfma_f32_16x16x32_f16(a0, b0, (f32x4){0.f, 0.f, 0.f, 0.f}, 0, 0, 0);
            acc[nt] = __builtin_amdgcn_mfma_f32_16x16x32_f16(a1, b1v, acc[nt], 0, 0, 0);
        }
    }
    {
        #pragma unroll
        for (int nt = 0; nt < 4; ++nt) {
            float bb = b1[nt * 16 + l15];
            #pragma unroll
            for (int j = 0; j < 4; ++j) {
                float v = fmaxf(acc[nt][j] + bb, 0.f);
                zt[(w * 16 + kg * 4 + j) * AS + nt * 16 + l15] = __float2half(v);
            }
        }
    }
    __syncthreads();

    {
        f16x8 a0 = *reinterpret_cast<const f16x8*>(&zt[myrow + kg * 8]);
        f16x8 a1 = *reinterpret_cast<const f16x8*>(&zt[myrow + 32 + kg * 8]);
        #pragma unroll
        for (int nt = 0; nt < 4; ++nt) {
            f16x8 b0 = *reinterpret_cast<const f16x8*>(&w2s[(nt * 16 + l15) * AS + kg * 8]);
            f16x8 b1v = *reinterpret_cast<const f16x8*>(&w2s[(nt * 16 + l15) * AS + 32 + kg * 8]);
            acc[nt] = __builtin_amdgcn_mfma_f32_16x16x32_f16(a0, b0, (f32x4){0.f, 0.f, 0.f, 0.f}, 0, 0, 0);
            acc[nt] = __builtin_amdgcn_mfma_f32_16x16x32_f16(a1, b1v, acc[nt], 0, 0, 0);
        }
    }
    float part[4] = {0.f, 0.f, 0.f, 0.f};
    #pragma unroll
    for (int nt = 0; nt < 4; ++nt) {
        float bb = b2[nt * 16 + l15];
        float wv = W3[nt * 16 + l15];
        #pragma unroll
        for (int j = 0; j < 4; ++j)
            part[j] += fmaxf(acc[nt][j] + bb, 0.f) * wv;
    }
    #pragma unroll
    for (int off = 1; off < 16; off <<= 1) {
        #pragma unroll
        for (int j = 0; j < 4; ++j)
            part[j] += __shfl_xor(part[j], off, 16);
    }
    if (l15 == 0) {
        const float b3v = b3[0];
        int gp0 = blockIdx.x * 64 + w * 16 + kg * 4;
        #pragma unroll
        for (int j = 0; j < 4; ++j)
            out[gp0 + j] = part[j] + b3v;
    }
}

extern "C" void kernel_launch(void* const* d_in, const int* in_sizes, int n_in,
                              void* d_out, int out_size, void* d_ws, size_t ws_size,
                              hipStream_t stream)
{
    const float* x    = (const float*)d_in[0];
    const int* es     = (const int*)d_in[1];
    const int* ed     = (const int*)d_in[2];
    const int* ps     = (const int*)d_in[3];
    const int* pdst   = (const int*)d_in[4];
    const int* ns     = (const int*)d_in[5];
    const int* nd     = (const int*)d_in[6];
    const float* W0   = (const float*)d_in[7];
    const float* al0  = (const float*)d_in[8];
    const float* ar0  = (const float*)d_in[9];
    const float* W1   = (const float*)d_in[11];
    const float* al1  = (const float*)d_in[12];
    const float* ar1  = (const float*)d_in[13];
    const float* W2   = (const float*)d_in[15];
    const float* al2  = (const float*)d_in[16];
    const float* ar2  = (const float*)d_in[17];
    const float* b2   = (const float*)d_in[18];
    const float* bn0g = (const float*)d_in[19];
    const float* bn0b = (const float*)d_in[20];
    const float* bn1g = (const float*)d_in[21];
    const float* bn1b = (const float*)d_in[22];
    const float* pW1  = (const float*)d_in[23];
    const float* pb1  = (const float*)d_in[24];
    const float* pW2  = (const float*)d_in[25];
    const float* pb2  = (const float*)d_in[26];
    const float* pW3  = (const float*)d_in[27];
    const float* pb3  = (const float*)d_in[28];
    float* out = (float*)d_out;

    float* ws = (float*)d_ws;
    size_t off = 0;
    auto alloc = [&](size_t nelem) {
        float* p = ws + off;
        off += (nelem + 63) & ~(size_t)63;
        return p;
    };
    __half* featb = (__half*)alloc((size_t)N_NODES * 64);   // N x 128 halfs
    __half* xh    = (__half*)alloc((size_t)N_NODES * 64);   // fp16 activations (gemm input)
    __half* aggh  = (__half*)alloc((size_t)N_NODES * 64);   // fp16 aggregate output
    __half* wt0  = (__half*)alloc(128 * 64);
    __half* wt1  = (__half*)alloc(128 * 64);
    __half* wt2  = (__half*)alloc(64 * 64);
    __half* pwt1 = (__half*)alloc(64 * 32);
    __half* pwt2 = (__half*)alloc(64 * 32);
    float* el    = alloc((size_t)N_NODES * 2);
    float* er    = alloc((size_t)N_NODES * 2);
    float* bns   = alloc(256);
    int* cnt     = (int*)alloc(N_NODES);
    int* rs      = (int*)alloc(N_NODES + 1);
    int* cursor  = (int*)alloc(N_NODES);
    int* bsum    = (int*)alloc(256);
    int* csr     = (int*)alloc(N_EDGES);

    dim3 blk(256);
    const int gemmGrid = (N_NODES + 63) / 64;
    const int edge4Grid = (N_EDGES / 4 + 255) / 256;
    const int nodeBlocks = (N_NODES + 255) / 256;
    const int aggGrid = (N_NODES + 3) / 4;
    const long long bnPairs = (long long)N_NODES * 64;

    // ================= CSR build + fp16 prep =================
    hipMemsetAsync(cnt, 0, (size_t)N_NODES * sizeof(int), stream);
    hist_dst<<<edge4Grid, blk, 0, stream>>>(ed, cnt, N_EDGES);
    scan_block_sums<<<nodeBlocks, blk, 0, stream>>>(cnt, bsum, N_NODES);
    scan_bsum<<<1, blk, 0, stream>>>(bsum, nodeBlocks);
    scan_final<<<nodeBlocks, blk, 0, stream>>>(cnt, bsum, rs, cursor, N_NODES);
    scatter_csr<<<edge4Grid, blk, 0, stream>>>(es, ed, cursor, csr, N_EDGES);
    f32_to_f16<<<2048, blk, 0, stream>>>(x, xh, N_NODES * 32);
    prep_wt<<<384, dim3(128), 0, stream>>>(W0, W1, W2, wt0, wt1, wt2);
    prep_pwt<<<128, dim3(64), 0, stream>>>(pW1, pW2, pwt1, pwt2);

    // ================= layer 0 (C=128, H=2) =================
    gemm_mfma<128, 2><<<gemmGrid, blk, 0, stream>>>(xh, wt0, al0, ar0, featb, el, er, N_NODES);
    gat_agg<128, 2><<<aggGrid, blk, 0, stream>>>(rs, csr, el, er, featb, nullptr, aggh, N_NODES);
    hipMemsetAsync(bns, 0, 256 * sizeof(float), stream);
    bn_stats<<<256, blk, 0, stream>>>(aggh, bns, N_NODES);
    bn_apply<<<(int)((bnPairs + 255) / 256), blk, 0, stream>>>(aggh, xh, bns, bn0g, bn0b, bnPairs);

    // ================= layer 1 (C=128, H=2) =================
    gemm_mfma<128, 2><<<gemmGrid, blk, 0, stream>>>(xh, wt1, al1, ar1, featb, el, er, N_NODES);
    gat_agg<128, 2><<<aggGrid, blk, 0, stream>>>(rs, csr, el, er, featb, nullptr, aggh, N_NODES);
    hipMemsetAsync(bns, 0, 256 * sizeof(float), stream);
    bn_stats<<<256, blk, 0, stream>>>(aggh, bns, N_NODES);
    bn_apply<<<(int)((bnPairs + 255) / 256), blk, 0, stream>>>(aggh, xh, bns, bn1g, bn1b, bnPairs);

    // ================= layer 2 (C=64, H=1); output fp16 straight into predictor input ====
    gemm_mfma<64, 1><<<gemmGrid, blk, 0, stream>>>(xh, wt2, al2, ar2, featb, el, er, N_NODES);
    gat_agg<64, 1><<<aggGrid, blk, 0, stream>>>(rs, csr, el, er, featb, b2, aggh, N_NODES);

    // ================= predictor =================
    predictor<<<3125, blk, 0, stream>>>(aggh, ps, pdst, ns, nd,
                                        pwt1, pb1, pwt2, pb2, pW3, pb3, out, 100000);
}

// Round 10
// 429.977 us; speedup vs baseline: 11.7406x; 1.0458x over previous
//
#include <hip/hip_runtime.h>
#include <hip/hip_fp16.h>
#include <cstdint>
#include <cstddef>

#define N_NODES 50000
#define N_EDGES 800000

typedef _Float16 f16x8 __attribute__((ext_vector_type(8)));
typedef float f32x4 __attribute__((ext_vector_type(4)));

// ---------------- fat prep kernel: x->f16, zero cnt, zero bns, W transposes ----------------
// block ranges: [0,6250) x convert | [6250,6446) zero cnt | 6446 zero bns[512]
//               [6447,6607) GAT W transposes | [6607,6639) predictor W transposes
__global__ void prep_all(const float* __restrict__ x, __half* __restrict__ xh,
                         int* __restrict__ cnt, float* __restrict__ bns,
                         const float* __restrict__ W0, const float* __restrict__ W1,
                         const float* __restrict__ W2, __half* __restrict__ t0,
                         __half* __restrict__ t1, __half* __restrict__ t2,
                         const float* __restrict__ pW1, const float* __restrict__ pW2,
                         __half* __restrict__ pt1, __half* __restrict__ pt2)
{
    const int b = blockIdx.x;
    const int tid = threadIdx.x;
    if (b < 6250) {
        int i = b * 256 + tid;                 // one float4 per thread, n4 = 1.6M
        if (i < N_NODES * 32) {
            float4 v = *reinterpret_cast<const float4*>(x + (size_t)i * 4);
            __half2 a = __floats2half2_rn(v.x, v.y);
            __half2 c = __floats2half2_rn(v.z, v.w);
            uint2 pk;
            pk.x = *reinterpret_cast<unsigned*>(&a);
            pk.y = *reinterpret_cast<unsigned*>(&c);
            *reinterpret_cast<uint2*>(xh + (size_t)i * 4) = pk;
        }
    } else if (b < 6446) {
        int i = (b - 6250) * 256 + tid;
        if (i < N_NODES) cnt[i] = 0;
    } else if (b == 6446) {
        bns[tid] = 0.f;
        bns[256 + tid] = 0.f;
    } else if (b < 6607) {
        int g = (b - 6447) * 256 + tid;        // 40960 total
        if (g < 16384) {
            int c = g & 127, k = g >> 7;
            t0[(size_t)c * 128 + k] = __float2half(W0[(size_t)k * 128 + c]);
        } else if (g < 32768) {
            int idx = g - 16384;
            int c = idx & 127, k = idx >> 7;
            t1[(size_t)c * 128 + k] = __float2half(W1[(size_t)k * 128 + c]);
        } else if (g < 40960) {
            int idx = g - 32768;
            int c = idx & 63, k = idx >> 6;
            t2[(size_t)c * 128 + k] = __float2half(W2[(size_t)k * 64 + c]);
        }
    } else {
        int g = (b - 6607) * 256 + tid;        // 8192 total
        if (g < 4096) {
            int c = g & 63, k = g >> 6;
            pt1[(size_t)c * 64 + k] = __float2half(pW1[(size_t)k * 64 + c]);
        } else if (g < 8192) {
            int idx = g - 4096;
            int c = idx & 63, k = idx >> 6;
            pt2[(size_t)c * 64 + k] = __float2half(pW2[(size_t)k * 64 + c]);
        }
    }
}

// ---------------- MFMA GEMM (n x 128) @ (128 x C) + optional fused BN+ReLU on input ----
// A fp16 [n][128]; Wt fp16 [C][128]. BN: A' = relu(A*scale[c]+shift[c]) applied in staging.
template <int C, int H, bool BN>
__launch_bounds__(256, 3)
__global__ void gemm_mfma(const __half* __restrict__ Ah, const __half* __restrict__ Wt,
                          const float* __restrict__ al, const float* __restrict__ ar,
                          const float* __restrict__ bns, const float* __restrict__ bng,
                          const float* __restrict__ bnb,
                          __half* __restrict__ feat, float* __restrict__ el,
                          float* __restrict__ er, int n)
{
    constexpr int K = 128;
    constexpr int AS = 136;
    constexpr int CT = C / 16;
    __shared__ __half As[64 * AS];
    __shared__ __half Ws[C * AS];
    __shared__ float sc[128], sh_[128];

    const int tid = threadIdx.x;
    const int brow = blockIdx.x * 64;

    if constexpr (BN) {
        if (tid < 128) {
            const float invN = 1.f / (float)N_NODES;
            float mean = bns[tid] * invN;
            float var = bns[128 + tid] * invN - mean * mean;
            float s = bng[tid] * rsqrtf(var + 1e-5f);
            sc[tid] = s;
            sh_[tid] = bnb[tid] - mean * s;
        }
        __syncthreads();
    }

    for (int idx = tid; idx < 64 * 16; idx += 256) {
        int r = idx >> 4, u = idx & 15;
        int gr = brow + r;
        f16x8 v = {0, 0, 0, 0, 0, 0, 0, 0};
        if (gr < n) v = *reinterpret_cast<const f16x8*>(Ah + (size_t)gr * K + u * 8);
        if constexpr (BN) {
            #pragma unroll
            for (int e = 0; e < 8; ++e) {
                int ch = u * 8 + e;
                float f = (float)v[e] * sc[ch] + sh_[ch];
                v[e] = (_Float16)fmaxf(f, 0.f);
            }
        }
        *reinterpret_cast<f16x8*>(&As[r * AS + u * 8]) = v;
    }
    for (int idx = tid; idx < C * 16; idx += 256) {
        int c = idx >> 4, u = idx & 15;
        *reinterpret_cast<f16x8*>(&Ws[c * AS + u * 8]) =
            *reinterpret_cast<const f16x8*>(Wt + (size_t)c * K + u * 8);
    }
    __syncthreads();

    const int w = tid >> 6;
    const int l = tid & 63;
    const int l15 = l & 15;
    const int kg = l >> 4;

    f32x4 acc[CT];
    #pragma unroll
    for (int ct = 0; ct < CT; ++ct) acc[ct] = (f32x4){0.f, 0.f, 0.f, 0.f};

    #pragma unroll
    for (int kt = 0; kt < 4; ++kt) {
        f16x8 a = *reinterpret_cast<const f16x8*>(&As[(w * 16 + l15) * AS + kt * 32 + kg * 8]);
        #pragma unroll
        for (int ct = 0; ct < CT; ++ct) {
            f16x8 b = *reinterpret_cast<const f16x8*>(&Ws[(ct * 16 + l15) * AS + kt * 32 + kg * 8]);
            acc[ct] = __builtin_amdgcn_mfma_f32_16x16x32_f16(a, b, acc[ct], 0, 0, 0);
        }
    }

    const int row0 = w * 16 + kg * 4;
    float pel[4][H], per_[4][H];
    #pragma unroll
    for (int j = 0; j < 4; ++j)
        #pragma unroll
        for (int h = 0; h < H; ++h) { pel[j][h] = 0.f; per_[j][h] = 0.f; }

    #pragma unroll
    for (int ct = 0; ct < CT; ++ct) {
        int col = ct * 16 + l15;
        int head = (H == 2) ? (col >> 6) : 0;
        int lc = col & 63;
        float av = al[head * 64 + lc];
        float rv = ar[head * 64 + lc];
        #pragma unroll
        for (int j = 0; j < 4; ++j) {
            float fv = acc[ct][j];
            int gr = brow + row0 + j;
            if (gr < n) feat[(size_t)gr * C + col] = __float2half(fv);
            pel[j][head] += fv * av;
            per_[j][head] += fv * rv;
        }
    }
    #pragma unroll
    for (int off = 1; off < 16; off <<= 1) {
        #pragma unroll
        for (int j = 0; j < 4; ++j)
            #pragma unroll
            for (int h = 0; h < H; ++h) {
                pel[j][h] += __shfl_xor(pel[j][h], off, 64);
                per_[j][h] += __shfl_xor(per_[j][h], off, 64);
            }
    }
    if (l15 == 0) {
        #pragma unroll
        for (int j = 0; j < 4; ++j) {
            int gr = brow + row0 + j;
            if (gr < n) {
                if constexpr (H == 2) {
                    float2 e0 = make_float2(pel[j][0], pel[j][1]);
                    float2 e1 = make_float2(per_[j][0], per_[j][1]);
                    *reinterpret_cast<float2*>(el + (size_t)gr * 2) = e0;
                    *reinterpret_cast<float2*>(er + (size_t)gr * 2) = e1;
                } else {
                    el[gr] = pel[j][0];
                    er[gr] = per_[j][0];
                }
            }
        }
    }
}

// ---------------- CSR build (by dst): 1 edge/thread (latency-bound, max threads) ------
__global__ void hist_dst(const int* __restrict__ dst, int* __restrict__ cnt, int E)
{
    int e = blockIdx.x * blockDim.x + threadIdx.x;
    if (e < E) atomicAdd(&cnt[dst[e]], 1);
}

__global__ void scan_block_sums(const int* __restrict__ cnt, int* __restrict__ bsum, int n)
{
    __shared__ int sh[256];
    int i = blockIdx.x * 256 + threadIdx.x;
    sh[threadIdx.x] = (i < n) ? cnt[i] : 0;
    __syncthreads();
    for (int off = 128; off; off >>= 1) {
        if (threadIdx.x < off) sh[threadIdx.x] += sh[threadIdx.x + off];
        __syncthreads();
    }
    if (threadIdx.x == 0) bsum[blockIdx.x] = sh[0];
}

__global__ void scan_bsum(int* __restrict__ bsum, int nb)
{
    __shared__ int sh[256];
    int t = threadIdx.x;
    sh[t] = (t < nb) ? bsum[t] : 0;
    __syncthreads();
    for (int off = 1; off < 256; off <<= 1) {
        int u = (t >= off) ? sh[t - off] : 0;
        __syncthreads();
        sh[t] += u;
        __syncthreads();
    }
    if (t < nb) bsum[t] = t ? sh[t - 1] : 0;   // exclusive
}

__global__ void scan_final(const int* __restrict__ cnt, const int* __restrict__ bsum,
                           int* __restrict__ rs, int* __restrict__ cursor, int n)
{
    __shared__ int sh[256];
    int t = threadIdx.x;
    int i = blockIdx.x * 256 + t;
    int v = (i < n) ? cnt[i] : 0;
    sh[t] = v;
    __syncthreads();
    for (int off = 1; off < 256; off <<= 1) {
        int u = (t >= off) ? sh[t - off] : 0;
        __syncthreads();
        sh[t] += u;
        __syncthreads();
    }
    int excl = sh[t] - v + bsum[blockIdx.x];
    if (i < n) { rs[i] = excl; cursor[i] = excl; }
    if (i == n - 1) rs[n] = excl + v;
}

__global__ void scatter_csr(const int* __restrict__ src, const int* __restrict__ dst,
                            int* __restrict__ cursor, int* __restrict__ csr, int E)
{
    int e = blockIdx.x * blockDim.x + threadIdx.x;
    if (e < E) {
        int d = dst[e];
        int pos = atomicAdd(&cursor[d], 1);
        csr[pos] = src[e];
    }
}

// ---------------- fused GAT edge-softmax + aggregate, single-pass ----------------
template <int C, int H>
__launch_bounds__(256)
__global__ void gat_agg(const int* __restrict__ rs, const int* __restrict__ csr,
                        const float* __restrict__ el, const float* __restrict__ er,
                        const __half* __restrict__ feat, const float* __restrict__ bias,
                        __half* __restrict__ outp, int n)
{
    int node = blockIdx.x * 4 + (threadIdx.x >> 6);
    if (node >= n) return;
    int lane = threadIdx.x & 63;
    int start = rs[node], end = rs[node + 1];

    if constexpr (H == 2) {
        const int slot = lane >> 4;
        const int cl = lane & 15;
        const int h = cl >> 3;
        const float erh = er[(size_t)node * 2 + h];
        float ssum = 0.f;
        float acc[8];
        #pragma unroll
        for (int u = 0; u < 8; ++u) acc[u] = 0.f;
        for (int j = start + slot; j < end; j += 4) {
            int s = csr[j];
            float v = el[(size_t)s * 2 + h] + erh;
            v = v >= 0.f ? v : 0.2f * v;
            float p = __expf(v);
            ssum += p;
            float4 raw = *reinterpret_cast<const float4*>(feat + (size_t)s * C + cl * 8);
            const __half2* hp = reinterpret_cast<const __half2*>(&raw);
            #pragma unroll
            for (int u = 0; u < 4; ++u) {
                float2 f2 = __half22float2(hp[u]);
                acc[2 * u]     = fmaf(p, f2.x, acc[2 * u]);
                acc[2 * u + 1] = fmaf(p, f2.y, acc[2 * u + 1]);
            }
        }
        #pragma unroll
        for (int off = 16; off <= 32; off <<= 1) {
            ssum += __shfl_xor(ssum, off, 64);
            #pragma unroll
            for (int u = 0; u < 8; ++u) acc[u] += __shfl_xor(acc[u], off, 64);
        }
        if (slot == 0) {
            float r = 1.f / fmaxf(ssum, 1e-9f);
            f16x8 o;
            #pragma unroll
            for (int u = 0; u < 8; ++u) o[u] = (_Float16)(acc[u] * r);
            *reinterpret_cast<f16x8*>(outp + (size_t)node * C + cl * 8) = o;
        }
    } else {
        const int slot = lane >> 3;
        const int cl = lane & 7;
        const float er0 = er[node];
        float ssum = 0.f;
        float acc[8];
        #pragma unroll
        for (int u = 0; u < 8; ++u) acc[u] = 0.f;
        for (int j = start + slot; j < end; j += 8) {
            int s = csr[j];
            float v = el[s] + er0;
            v = v >= 0.f ? v : 0.2f * v;
            float p = __expf(v);
            ssum += p;
            float4 raw = *reinterpret_cast<const float4*>(feat + (size_t)s * C + cl * 8);
            const __half2* hp = reinterpret_cast<const __half2*>(&raw);
            #pragma unroll
            for (int u = 0; u < 4; ++u) {
                float2 f2 = __half22float2(hp[u]);
                acc[2 * u]     = fmaf(p, f2.x, acc[2 * u]);
                acc[2 * u + 1] = fmaf(p, f2.y, acc[2 * u + 1]);
            }
        }
        #pragma unroll
        for (int off = 8; off <= 32; off <<= 1) {
            ssum += __shfl_xor(ssum, off, 64);
            #pragma unroll
            for (int u = 0; u < 8; ++u) acc[u] += __shfl_xor(acc[u], off, 64);
        }
        if (slot == 0) {
            float r = 1.f / fmaxf(ssum, 1e-9f);
            f16x8 o;
            #pragma unroll
            for (int u = 0; u < 8; ++u) o[u] = (_Float16)(acc[u] * r + bias[cl * 8 + u]);
            *reinterpret_cast<f16x8*>(outp + (size_t)node * C + cl * 8) = o;
        }
    }
}

// ---------------- BatchNorm stats (C=128), fp16 input ----------------
__global__ void bn_stats(const __half* __restrict__ h, float* __restrict__ sums, int n)
{
    __shared__ float s1[256], s2[256];
    int c = threadIdx.x & 127, half = threadIdx.x >> 7;
    float ls = 0.f, lq = 0.f;
    for (int r = blockIdx.x * 2 + half; r < n; r += gridDim.x * 2) {
        float v = __half2float(h[(size_t)r * 128 + c]);
        ls += v; lq += v * v;
    }
    s1[threadIdx.x] = ls; s2[threadIdx.x] = lq;
    __syncthreads();
    if (threadIdx.x < 128) {
        atomicAdd(&sums[c], s1[threadIdx.x] + s1[threadIdx.x + 128]);
        atomicAdd(&sums[128 + c], s2[threadIdx.x] + s2[threadIdx.x + 128]);
    }
}

// ---------------- predictor: MFMA batched MLP, 64 pairs per block ----------------
__launch_bounds__(256, 5)
__global__ void predictor(const __half* __restrict__ h16,
                          const int* __restrict__ ps, const int* __restrict__ pd,
                          const int* __restrict__ ns, const int* __restrict__ nd,
                          const __half* __restrict__ W1t, const float* __restrict__ b1,
                          const __half* __restrict__ W2t, const float* __restrict__ b2,
                          const float* __restrict__ W3, const float* __restrict__ b3,
                          float* __restrict__ out, int P)
{
    constexpr int AS = 72;
    __shared__ __half zt[64 * AS];
    __shared__ __half w1s[64 * AS];
    __shared__ __half w2s[64 * AS];
    const int tid = threadIdx.x;

    for (int idx = tid; idx < 512; idx += 256) {
        int c = idx >> 3, u = idx & 7;
        *reinterpret_cast<f16x8*>(&w1s[c * AS + u * 8]) =
            *reinterpret_cast<const f16x8*>(W1t + (size_t)c * 64 + u * 8);
        *reinterpret_cast<f16x8*>(&w2s[c * AS + u * 8]) =
            *reinterpret_cast<const f16x8*>(W2t + (size_t)c * 64 + u * 8);
    }

    {
        int p = tid >> 2, q = tid & 3;
        int gp = blockIdx.x * 64 + p;
        int s, d;
        if (gp < P) { s = ps[gp]; d = pd[gp]; }
        else        { s = ns[gp - P]; d = nd[gp - P]; }
        const f16x8* hs = reinterpret_cast<const f16x8*>(h16 + (size_t)s * 64 + q * 16);
        const f16x8* hd = reinterpret_cast<const f16x8*>(h16 + (size_t)d * 64 + q * 16);
        #pragma unroll
        for (int u = 0; u < 2; ++u) {
            f16x8 z = hs[u] * hd[u];
            *reinterpret_cast<f16x8*>(&zt[p * AS + q * 16 + u * 8]) = z;
        }
    }
    __syncthreads();

    const int w = tid >> 6;
    const int l = tid & 63;
    const int l15 = l & 15;
    const int kg = l >> 4;
    const int myrow = (w * 16 + l15) * AS;

    f32x4 acc[4];
    {
        f16x8 a0 = *reinterpret_cast<const f16x8*>(&zt[myrow + kg * 8]);
        f16x8 a1 = *reinterpret_cast<const f16x8*>(&zt[myrow + 32 + kg * 8]);
        #pragma unroll
        for (int nt = 0; nt < 4; ++nt) {
            f16x8 b0 = *reinterpret_cast<const f16x8*>(&w1s[(nt * 16 + l15) * AS + kg * 8]);
            f16x8 b1v = *reinterpret_cast<const f16x8*>(&w1s[(nt * 16 + l15) * AS + 32 + kg * 8]);
            acc[nt] = __builtin_amdgcn_mfma_f32_16x16x32_f16(a0, b0, (f32x4){0.f, 0.f, 0.f, 0.f}, 0, 0, 0);
            acc[nt] = __builtin_amdgcn_mfma_f32_16x16x32_f16(a1, b1v, acc[nt], 0, 0, 0);
        }
    }
    {
        #pragma unroll
        for (int nt = 0; nt < 4; ++nt) {
            float bb = b1[nt * 16 + l15];
            #pragma unroll
            for (int j = 0; j < 4; ++j) {
                float v = fmaxf(acc[nt][j] + bb, 0.f);
                zt[(w * 16 + kg * 4 + j) * AS + nt * 16 + l15] = __float2half(v);
            }
        }
    }
    __syncthreads();

    {
        f16x8 a0 = *reinterpret_cast<const f16x8*>(&zt[myrow + kg * 8]);
        f16x8 a1 = *reinterpret_cast<const f16x8*>(&zt[myrow + 32 + kg * 8]);
        #pragma unroll
        for (int nt = 0; nt < 4; ++nt) {
            f16x8 b0 = *reinterpret_cast<const f16x8*>(&w2s[(nt * 16 + l15) * AS + kg * 8]);
            f16x8 b1v = *reinterpret_cast<const f16x8*>(&w2s[(nt * 16 + l15) * AS + 32 + kg * 8]);
            acc[nt] = __builtin_amdgcn_mfma_f32_16x16x32_f16(a0, b0, (f32x4){0.f, 0.f, 0.f, 0.f}, 0, 0, 0);
            acc[nt] = __builtin_amdgcn_mfma_f32_16x16x32_f16(a1, b1v, acc[nt], 0, 0, 0);
        }
    }
    float part[4] = {0.f, 0.f, 0.f, 0.f};
    #pragma unroll
    for (int nt = 0; nt < 4; ++nt) {
        float bb = b2[nt * 16 + l15];
        float wv = W3[nt * 16 + l15];
        #pragma unroll
        for (int j = 0; j < 4; ++j)
            part[j] += fmaxf(acc[nt][j] + bb, 0.f) * wv;
    }
    #pragma unroll
    for (int off = 1; off < 16; off <<= 1) {
        #pragma unroll
        for (int j = 0; j < 4; ++j)
            part[j] += __shfl_xor(part[j], off, 16);
    }
    if (l15 == 0) {
        const float b3v = b3[0];
        int gp0 = blockIdx.x * 64 + w * 16 + kg * 4;
        #pragma unroll
        for (int j = 0; j < 4; ++j)
            out[gp0 + j] = part[j] + b3v;
    }
}

extern "C" void kernel_launch(void* const* d_in, const int* in_sizes, int n_in,
                              void* d_out, int out_size, void* d_ws, size_t ws_size,
                              hipStream_t stream)
{
    const float* x    = (const float*)d_in[0];
    const int* es     = (const int*)d_in[1];
    const int* ed     = (const int*)d_in[2];
    const int* ps     = (const int*)d_in[3];
    const int* pdst   = (const int*)d_in[4];
    const int* ns     = (const int*)d_in[5];
    const int* nd     = (const int*)d_in[6];
    const float* W0   = (const float*)d_in[7];
    const float* al0  = (const float*)d_in[8];
    const float* ar0  = (const float*)d_in[9];
    const float* W1   = (const float*)d_in[11];
    const float* al1  = (const float*)d_in[12];
    const float* ar1  = (const float*)d_in[13];
    const float* W2   = (const float*)d_in[15];
    const float* al2  = (const float*)d_in[16];
    const float* ar2  = (const float*)d_in[17];
    const float* b2   = (const float*)d_in[18];
    const float* bn0g = (const float*)d_in[19];
    const float* bn0b = (const float*)d_in[20];
    const float* bn1g = (const float*)d_in[21];
    const float* bn1b = (const float*)d_in[22];
    const float* pW1  = (const float*)d_in[23];
    const float* pb1  = (const float*)d_in[24];
    const float* pW2  = (const float*)d_in[25];
    const float* pb2  = (const float*)d_in[26];
    const float* pW3  = (const float*)d_in[27];
    const float* pb3  = (const float*)d_in[28];
    float* out = (float*)d_out;

    float* ws = (float*)d_ws;
    size_t off = 0;
    auto alloc = [&](size_t nelem) {
        float* p = ws + off;
        off += (nelem + 63) & ~(size_t)63;
        return p;
    };
    __half* featb = (__half*)alloc((size_t)N_NODES * 64);   // N x 128 halfs
    __half* xh    = (__half*)alloc((size_t)N_NODES * 64);   // fp16 activations
    __half* aggh  = (__half*)alloc((size_t)N_NODES * 64);   // fp16 aggregate output
    __half* wt0  = (__half*)alloc(128 * 64);
    __half* wt1  = (__half*)alloc(128 * 64);
    __half* wt2  = (__half*)alloc(64 * 64);
    __half* pwt1 = (__half*)alloc(64 * 32);
    __half* pwt2 = (__half*)alloc(64 * 32);
    float* el    = alloc((size_t)N_NODES * 2);
    float* er    = alloc((size_t)N_NODES * 2);
    float* bns   = alloc(512);                               // [0:256)=layer0, [256:512)=layer1
    int* cnt     = (int*)alloc(N_NODES);
    int* rs      = (int*)alloc(N_NODES + 1);
    int* cursor  = (int*)alloc(N_NODES);
    int* bsum    = (int*)alloc(256);
    int* csr     = (int*)alloc(N_EDGES);

    dim3 blk(256);
    const int gemmGrid = (N_NODES + 63) / 64;
    const int edgeGrid = (N_EDGES + 255) / 256;
    const int nodeBlocks = (N_NODES + 255) / 256;
    const int aggGrid = (N_NODES + 3) / 4;

    // ================= prep (1 dispatch) + CSR build =================
    prep_all<<<6639, blk, 0, stream>>>(x, xh, cnt, bns, W0, W1, W2, wt0, wt1, wt2,
                                       pW1, pW2, pwt1, pwt2);
    hist_dst<<<edgeGrid, blk, 0, stream>>>(ed, cnt, N_EDGES);
    scan_block_sums<<<nodeBlocks, blk, 0, stream>>>(cnt, bsum, N_NODES);
    scan_bsum<<<1, blk, 0, stream>>>(bsum, nodeBlocks);
    scan_final<<<nodeBlocks, blk, 0, stream>>>(cnt, bsum, rs, cursor, N_NODES);
    scatter_csr<<<edgeGrid, blk, 0, stream>>>(es, ed, cursor, csr, N_EDGES);

    // ================= layer 0 (C=128, H=2) =================
    gemm_mfma<128, 2, false><<<gemmGrid, blk, 0, stream>>>(xh, wt0, al0, ar0,
        nullptr, nullptr, nullptr, featb, el, er, N_NODES);
    gat_agg<128, 2><<<aggGrid, blk, 0, stream>>>(rs, csr, el, er, featb, nullptr, aggh, N_NODES);
    bn_stats<<<256, blk, 0, stream>>>(aggh, bns, N_NODES);

    // ================= layer 1 (C=128, H=2); BN0 fused into gemm =================
    gemm_mfma<128, 2, true><<<gemmGrid, blk, 0, stream>>>(aggh, wt1, al1, ar1,
        bns, bn0g, bn0b, featb, el, er, N_NODES);
    gat_agg<128, 2><<<aggGrid, blk, 0, stream>>>(rs, csr, el, er, featb, nullptr, aggh, N_NODES);
    bn_stats<<<256, blk, 0, stream>>>(aggh, bns + 256, N_NODES);

    // ================= layer 2 (C=64, H=1); BN1 fused into gemm =================
    gemm_mfma<64, 1, true><<<gemmGrid, blk, 0, stream>>>(aggh, wt2, al2, ar2,
        bns + 256, bn1g, bn1b, featb, el, er, N_NODES);
    gat_agg<64, 1><<<aggGrid, blk, 0, stream>>>(rs, csr, el, er, featb, b2, aggh, N_NODES);

    // ================= predictor =================
    predictor<<<3125, blk, 0, stream>>>(aggh, ps, pdst, ns, nd,
                                        pwt1, pb1, pwt2, pb2, pW3, pb3, out, 100000);
}